// Round 1
// baseline (5542.931 us; speedup 1.0000x reference)
//
#include <hip/hip_runtime.h>
#include <math.h>

#define N_ 4096
#define D_ 256
#define K_ 4
#define TK_ 16
#define E_ (K_ * N_)          // 16384 hyperedges
#define NENT_ (E_ * TK_)      // 262144 incidence entries

// ============================= small kernels =============================

__global__ void scalars_kernel(const float* __restrict__ alpha,
                               const float* __restrict__ rho_raw,
                               float* __restrict__ scal) {
  if (threadIdx.x == 0) {
    float m = alpha[0];
    for (int k = 1; k < K_; ++k) m = fmaxf(m, alpha[k]);
    float e[K_]; float s = 0.f;
    for (int k = 0; k < K_; ++k) { e[k] = expf(alpha[k] - m); s += e[k]; }
    for (int k = 0; k < K_; ++k) scal[k] = e[k] / s;   // w_k
    scal[4] = 1.0f / (1.0f + expf(-rho_raw[0]));       // rho
  }
}

__global__ void dvis_kernel(const float* __restrict__ DvAcc, float* __restrict__ Dvis) {
  int i = blockIdx.x * 256 + threadIdx.x;
  Dvis[i] = 1.0f / sqrtf(DvAcc[i] + 1e-9f);
}

__global__ void ew_scale(const float* __restrict__ M, const float* __restrict__ Dvis,
                         float* __restrict__ U) {
  int i = blockIdx.x * 256 + threadIdx.x;
  U[i] = Dvis[i >> 8] * M[i];
}

// ============================= 64-tile fp32 GEMMs =============================
// C(MxN) = A(MxK) @ B(KxN), row-major. grid=(M/64, N/64), 256 thr, 4x4/thread.
__global__ __launch_bounds__(256) void gemm_nn64(const float* __restrict__ A,
                                                 const float* __restrict__ B,
                                                 float* __restrict__ C,
                                                 int Kdim, int lda, int ldb, int ldc) {
  __shared__ float As[16][68];
  __shared__ float Bs[16][68];
  const int tid = threadIdx.x;
  const int bm = blockIdx.x * 64, bn = blockIdx.y * 64;
  const int lrA = tid >> 2, lcA = (tid & 3) * 4;   // A tile 64x16
  const int rrB = tid >> 4, ccB = (tid & 15) * 4;  // B tile 16x64
  const int tx = tid & 15, ty = tid >> 4;
  const float* Ap = A + (size_t)(bm + lrA) * lda + lcA;
  const float* Bp = B + (size_t)rrB * ldb + bn + ccB;
  float acc[4][4] = {};
  for (int k0 = 0; k0 < Kdim; k0 += 16) {
    float4 av = *(const float4*)(Ap + k0);
    float4 bv = *(const float4*)(Bp + (size_t)k0 * ldb);
    __syncthreads();
    As[lcA + 0][lrA] = av.x; As[lcA + 1][lrA] = av.y;
    As[lcA + 2][lrA] = av.z; As[lcA + 3][lrA] = av.w;
    *(float4*)&Bs[rrB][ccB] = bv;
    __syncthreads();
#pragma unroll
    for (int kk = 0; kk < 16; ++kk) {
      float a[4], b[4];
      *(float4*)a = *(const float4*)&As[kk][ty * 4];
      *(float4*)b = *(const float4*)&Bs[kk][tx * 4];
#pragma unroll
      for (int i = 0; i < 4; ++i)
#pragma unroll
        for (int j = 0; j < 4; ++j) acc[i][j] += a[i] * b[j];
    }
  }
#pragma unroll
  for (int i = 0; i < 4; ++i) {
    int row = bm + ty * 4 + i;
    float4 o; o.x = acc[i][0]; o.y = acc[i][1]; o.z = acc[i][2]; o.w = acc[i][3];
    *(float4*)(C + (size_t)row * ldc + bn + tx * 4) = o;
  }
}

// C(MxN) = A(MxK) @ B(NxK)^T + bias, row-major. grid=(M/64, N/64).
__global__ __launch_bounds__(256) void gemm_nt64_bias(const float* __restrict__ A,
                                                      const float* __restrict__ B,
                                                      const float* __restrict__ bias,
                                                      float* __restrict__ C,
                                                      int Kdim, int lda, int ldb, int ldc) {
  __shared__ float As[16][68];
  __shared__ float Bs[16][68];
  const int tid = threadIdx.x;
  const int bm = blockIdx.x * 64, bn = blockIdx.y * 64;
  const int lr = tid >> 2, lc = (tid & 3) * 4;
  const int tx = tid & 15, ty = tid >> 4;
  const float* Ap = A + (size_t)(bm + lr) * lda + lc;
  const float* Bp = B + (size_t)(bn + lr) * ldb + lc;
  float acc[4][4] = {};
  for (int k0 = 0; k0 < Kdim; k0 += 16) {
    float4 av = *(const float4*)(Ap + k0);
    float4 bv = *(const float4*)(Bp + k0);
    __syncthreads();
    As[lc + 0][lr] = av.x; As[lc + 1][lr] = av.y; As[lc + 2][lr] = av.z; As[lc + 3][lr] = av.w;
    Bs[lc + 0][lr] = bv.x; Bs[lc + 1][lr] = bv.y; Bs[lc + 2][lr] = bv.z; Bs[lc + 3][lr] = bv.w;
    __syncthreads();
#pragma unroll
    for (int kk = 0; kk < 16; ++kk) {
      float a[4], b[4];
      *(float4*)a = *(const float4*)&As[kk][ty * 4];
      *(float4*)b = *(const float4*)&Bs[kk][tx * 4];
#pragma unroll
      for (int i = 0; i < 4; ++i)
#pragma unroll
        for (int j = 0; j < 4; ++j) acc[i][j] += a[i] * b[j];
    }
  }
#pragma unroll
  for (int i = 0; i < 4; ++i) {
    int row = bm + ty * 4 + i;
    float4 o;
    o.x = acc[i][0] + bias[bn + tx * 4 + 0];
    o.y = acc[i][1] + bias[bn + tx * 4 + 1];
    o.z = acc[i][2] + bias[bn + tx * 4 + 2];
    o.w = acc[i][3] + bias[bn + tx * 4 + 3];
    *(float4*)(C + (size_t)row * ldc + bn + tx * 4) = o;
  }
}

// ============================= 128-tile fp32 GEMMs =============================
// scores: C(4096x4096) = A(4096x256) @ B(4096x256)^T * scale. grid (32,32).
__global__ __launch_bounds__(256) void gemm_scores(const float* __restrict__ A,
                                                   const float* __restrict__ B,
                                                   float* __restrict__ C, float scale) {
  __shared__ float As[8][132];
  __shared__ float Bs[8][132];
  const int tid = threadIdx.x;
  const int bm = blockIdx.x * 128, bn = blockIdx.y * 128;
  const int lr = tid >> 1, lc = (tid & 1) * 4;
  const int tx = tid & 15, ty = tid >> 4;
  const float* Ap = A + (size_t)(bm + lr) * D_ + lc;
  const float* Bp = B + (size_t)(bn + lr) * D_ + lc;
  float acc[8][8] = {};
  for (int k0 = 0; k0 < D_; k0 += 8) {
    float4 av = *(const float4*)(Ap + k0);
    float4 bv = *(const float4*)(Bp + k0);
    __syncthreads();
    As[lc + 0][lr] = av.x; As[lc + 1][lr] = av.y; As[lc + 2][lr] = av.z; As[lc + 3][lr] = av.w;
    Bs[lc + 0][lr] = bv.x; Bs[lc + 1][lr] = bv.y; Bs[lc + 2][lr] = bv.z; Bs[lc + 3][lr] = bv.w;
    __syncthreads();
#pragma unroll
    for (int kk = 0; kk < 8; ++kk) {
      float a[8], b[8];
      *(float4*)(a + 0) = *(const float4*)&As[kk][ty * 8];
      *(float4*)(a + 4) = *(const float4*)&As[kk][ty * 8 + 4];
      *(float4*)(b + 0) = *(const float4*)&Bs[kk][tx * 8];
      *(float4*)(b + 4) = *(const float4*)&Bs[kk][tx * 8 + 4];
#pragma unroll
      for (int i = 0; i < 8; ++i)
#pragma unroll
        for (int j = 0; j < 8; ++j) acc[i][j] += a[i] * b[j];
    }
  }
#pragma unroll
  for (int i = 0; i < 8; ++i) {
    int row = bm + ty * 8 + i;
    float4 o0, o1;
    o0.x = acc[i][0] * scale; o0.y = acc[i][1] * scale; o0.z = acc[i][2] * scale; o0.w = acc[i][3] * scale;
    o1.x = acc[i][4] * scale; o1.y = acc[i][5] * scale; o1.z = acc[i][6] * scale; o1.w = acc[i][7] * scale;
    *(float4*)(C + (size_t)row * N_ + bn + tx * 8) = o0;
    *(float4*)(C + (size_t)row * N_ + bn + tx * 8 + 4) = o1;
  }
}

// Zpart[ks] += w_k * H_k @ X ; H = exp(S - rowmax)/rowZ computed on A-load.
// grid (32, 2, SPLITK), K-chunk = 4096/SPLITK.
__global__ __launch_bounds__(256) void gemm_zkern(const float* __restrict__ S,
                                                  const float* __restrict__ rowmax,
                                                  const float* __restrict__ rowZ,
                                                  const float* __restrict__ X,
                                                  float* __restrict__ Zpart,
                                                  const float* __restrict__ scal,
                                                  int kidx, int kchunk) {
  __shared__ float As[8][132];
  __shared__ float Bs[8][132];
  const int tid = threadIdx.x;
  const int bm = blockIdx.x * 128, bn = blockIdx.y * 128;
  const int ks = blockIdx.z;
  const int k0base = ks * kchunk;
  const int lrA = tid >> 1, lcA = (tid & 1) * 4;
  const int rrB = tid >> 5, ccB = (tid & 31) * 4;
  const int tx = tid & 15, ty = tid >> 4;
  const int arow = bm + lrA;
  const float rm = rowmax[arow];
  const float rzinv = 1.0f / rowZ[arow];
  const float wk = scal[kidx];
  const float* Sp = S + (size_t)arow * N_ + k0base + lcA;
  const float* Xp = X + (size_t)(k0base + rrB) * D_ + bn + ccB;
  float acc[8][8] = {};
  for (int k0 = 0; k0 < kchunk; k0 += 8) {
    float4 sv = *(const float4*)(Sp + k0);
    float4 xv = *(const float4*)(Xp + (size_t)k0 * D_);
    float4 av;
    av.x = expf(sv.x - rm) * rzinv; av.y = expf(sv.y - rm) * rzinv;
    av.z = expf(sv.z - rm) * rzinv; av.w = expf(sv.w - rm) * rzinv;
    __syncthreads();
    As[lcA + 0][lrA] = av.x; As[lcA + 1][lrA] = av.y;
    As[lcA + 2][lrA] = av.z; As[lcA + 3][lrA] = av.w;
    *(float4*)&Bs[rrB][ccB] = xv;
    __syncthreads();
#pragma unroll
    for (int kk = 0; kk < 8; ++kk) {
      float a[8], b[8];
      *(float4*)(a + 0) = *(const float4*)&As[kk][ty * 8];
      *(float4*)(a + 4) = *(const float4*)&As[kk][ty * 8 + 4];
      *(float4*)(b + 0) = *(const float4*)&Bs[kk][tx * 8];
      *(float4*)(b + 4) = *(const float4*)&Bs[kk][tx * 8 + 4];
#pragma unroll
      for (int i = 0; i < 8; ++i)
#pragma unroll
        for (int j = 0; j < 8; ++j) acc[i][j] += a[i] * b[j];
    }
  }
  float* Zp = Zpart + (size_t)ks * N_ * D_;
#pragma unroll
  for (int i = 0; i < 8; ++i) {
    int row = bm + ty * 8 + i;
    float* base = Zp + (size_t)row * D_ + bn + tx * 8;
    float4 c0 = *(float4*)base;
    float4 c1 = *(float4*)(base + 4);
    c0.x += wk * acc[i][0]; c0.y += wk * acc[i][1]; c0.z += wk * acc[i][2]; c0.w += wk * acc[i][3];
    c1.x += wk * acc[i][4]; c1.y += wk * acc[i][5]; c1.z += wk * acc[i][6]; c1.w += wk * acc[i][7];
    *(float4*)base = c0;
    *(float4*)(base + 4) = c1;
  }
}

// ======================= per-row stats + top-16 =======================
// One block (256 thr) per row: row max, softmax denom Z, top-16 (val,idx),
// renormalized vals (exactly matching the reference's softmax->topk->renorm).
__global__ __launch_bounds__(256) void rowstats_topk(const float* __restrict__ S,
                                                     float* __restrict__ rowmax,
                                                     float* __restrict__ rowZ,
                                                     float* __restrict__ tkv,
                                                     int* __restrict__ tki) {
  const int row = blockIdx.x, tid = threadIdx.x;
  __shared__ float buf[N_];
  __shared__ float rv[256];
  __shared__ int ri[256];
  __shared__ float stk[TK_];
  __shared__ int itk[TK_];
  __shared__ float sden;
  const float4* Sp = (const float4*)(S + (size_t)row * N_);
  float lmax = -3.4e38f;
#pragma unroll
  for (int it = 0; it < 4; ++it) {
    float4 v = Sp[tid + it * 256];
    ((float4*)buf)[tid + it * 256] = v;
    lmax = fmaxf(lmax, fmaxf(fmaxf(v.x, v.y), fmaxf(v.z, v.w)));
  }
  rv[tid] = lmax;
  __syncthreads();
  for (int s = 128; s; s >>= 1) { if (tid < s) rv[tid] = fmaxf(rv[tid], rv[tid + s]); __syncthreads(); }
  const float M = rv[0];
  __syncthreads();
  float ls = 0.f;
  for (int i = tid; i < N_; i += 256) ls += expf(buf[i] - M);
  rv[tid] = ls;
  __syncthreads();
  for (int s = 128; s; s >>= 1) { if (tid < s) rv[tid] += rv[tid + s]; __syncthreads(); }
  const float Z = rv[0];
  if (tid == 0) { rowmax[row] = M; rowZ[row] = Z; }
  __syncthreads();
  // top-16: 16 x (scan + wave-shuffle argmax, tie -> smaller index like jax top_k)
  for (int t = 0; t < TK_; ++t) {
    float bmv = -3.4e38f; int bi = 0x7fffffff;
    for (int i = tid; i < N_; i += 256) { float v = buf[i]; if (v > bmv) { bmv = v; bi = i; } }
#pragma unroll
    for (int off = 32; off; off >>= 1) {
      float ov = __shfl_xor(bmv, off);
      int oi = __shfl_xor(bi, off);
      if (ov > bmv || (ov == bmv && oi < bi)) { bmv = ov; bi = oi; }
    }
    const int wid = tid >> 6, lane = tid & 63;
    if (lane == 0) { rv[wid] = bmv; ri[wid] = bi; }
    __syncthreads();
    if (tid == 0) {
      float b0 = rv[0]; int i0 = ri[0];
      for (int wv = 1; wv < 4; ++wv)
        if (rv[wv] > b0 || (rv[wv] == b0 && ri[wv] < i0)) { b0 = rv[wv]; i0 = ri[wv]; }
      stk[t] = b0; itk[t] = i0; buf[i0] = -3.4e38f;
    }
    __syncthreads();
  }
  // renorm: softval = exp(s-M)/Z ; vals = softval / (sum16 + 1e-9)
  if (tid < TK_) rv[tid] = expf(stk[tid] - M) / Z;
  __syncthreads();
  if (tid == 0) { float s = 0.f; for (int t = 0; t < TK_; ++t) s += rv[t]; sden = s + 1e-9f; }
  __syncthreads();
  if (tid < TK_) {
    tkv[(size_t)row * TK_ + tid] = rv[tid] / sden;
    tki[(size_t)row * TK_ + tid] = itk[tid];
  }
}

// ======================= hypergraph build =======================
__global__ void edge_scan(const float* __restrict__ tkv, const int* __restrict__ tki,
                          float* __restrict__ DvAcc, int* __restrict__ cnt,
                          float* __restrict__ invDe) {
  int e = blockIdx.x * 256 + threadIdx.x;
  float s = 0.f;
#pragma unroll
  for (int q = 0; q < TK_; ++q) s += tkv[(size_t)e * TK_ + q];
  invDe[e] = 1.0f / (s + 1e-9f);
#pragma unroll
  for (int q = 0; q < TK_; ++q) {
    int m = tki[(size_t)e * TK_ + q];
    atomicAdd(&DvAcc[m], tkv[(size_t)e * TK_ + q]);
    atomicAdd(&cnt[m], 1);
  }
}

__global__ __launch_bounds__(1024) void scan_offsets(const int* __restrict__ cnt,
                                                     int* __restrict__ off,
                                                     int* __restrict__ cur) {
  __shared__ int part[1024];
  const int t = threadIdx.x;
  const int b = t * 4;
  int c0 = cnt[b], c1 = cnt[b + 1], c2 = cnt[b + 2], c3 = cnt[b + 3];
  part[t] = c0 + c1 + c2 + c3;
  __syncthreads();
  for (int o = 1; o < 1024; o <<= 1) {
    int v = part[t] + ((t >= o) ? part[t - o] : 0);
    __syncthreads();
    part[t] = v;
    __syncthreads();
  }
  int ex = (t == 0) ? 0 : part[t - 1];
  off[b] = ex; off[b + 1] = ex + c0; off[b + 2] = ex + c0 + c1; off[b + 3] = ex + c0 + c1 + c2;
  cur[b] = off[b]; cur[b + 1] = off[b + 1]; cur[b + 2] = off[b + 2]; cur[b + 3] = off[b + 3];
  if (t == 1023) off[N_] = part[1023];
}

__global__ void edge_fill(const float* __restrict__ tkv, const int* __restrict__ tki,
                          int* __restrict__ cur, int* __restrict__ ince,
                          float* __restrict__ incv) {
  int e = blockIdx.x * 256 + threadIdx.x;
#pragma unroll
  for (int q = 0; q < TK_; ++q) {
    int m = tki[(size_t)e * TK_ + q];
    int pos = atomicAdd(&cur[m], 1);
    ince[pos] = e;
    incv[pos] = tkv[(size_t)e * TK_ + q];
  }
}

// ======================= power iteration (single block) =======================
__global__ __launch_bounds__(1024) void power_iter(const float* __restrict__ v0,
                                                   const float* __restrict__ Dvis,
                                                   const float* __restrict__ invDe,
                                                   const float* __restrict__ tkv,
                                                   const int* __restrict__ tki,
                                                   const int* __restrict__ off,
                                                   const int* __restrict__ ince,
                                                   const float* __restrict__ incv,
                                                   float* __restrict__ vb,
                                                   float* __restrict__ tb,
                                                   float* __restrict__ ye,
                                                   float* __restrict__ scal) {
  const int t = threadIdx.x;
  __shared__ float red[1024];
  float ls = 0.f;
  for (int i = t; i < N_; i += 1024) { float x = v0[i]; ls += x * x; }
  red[t] = ls;
  __syncthreads();
  for (int s = 512; s; s >>= 1) { if (t < s) red[t] += red[t + s]; __syncthreads(); }
  float inv = 1.0f / (sqrtf(red[0]) + 1e-9f);
  __syncthreads();
  for (int i = t; i < N_; i += 1024) vb[i] = v0[i] * inv;
  for (int it = 0; it < 6; ++it) {
    __syncthreads();
    for (int i = t; i < N_; i += 1024) tb[i] = Dvis[i] * vb[i];
    __syncthreads();
    for (int e = t; e < E_; e += 1024) {
      float a = 0.f;
      const float* tv = tkv + (size_t)e * TK_;
      const int* ti = tki + (size_t)e * TK_;
#pragma unroll
      for (int q = 0; q < TK_; ++q) a += tv[q] * tb[ti[q]];
      ye[e] = a * invDe[e];
    }
    __syncthreads();
    for (int m = t; m < N_; m += 1024) {
      float z = 0.f;
      int j0 = off[m], j1 = off[m + 1];
      for (int j = j0; j < j1; ++j) z += incv[j] * ye[ince[j]];
      tb[m] = vb[m] - Dvis[m] * z;   // L v
    }
    __syncthreads();
    if (it < 5) {
      ls = 0.f;
      for (int i = t; i < N_; i += 1024) { float x = tb[i]; ls += x * x; }
      red[t] = ls;
      __syncthreads();
      for (int s = 512; s; s >>= 1) { if (t < s) red[t] += red[t + s]; __syncthreads(); }
      inv = 1.0f / (sqrtf(red[0]) + 1e-9f);
      __syncthreads();
      for (int i = t; i < N_; i += 1024) vb[i] = tb[i] * inv;
    } else {
      ls = 0.f;
      for (int i = t; i < N_; i += 1024) ls += vb[i] * tb[i];
      red[t] = ls;
      __syncthreads();
      for (int s = 512; s; s >>= 1) { if (t < s) red[t] += red[t + s]; __syncthreads(); }
      if (t == 0) scal[5] = fmaxf(red[0], 1e-3f);
    }
  }
}

// ======================= Chebyshev sparse applies =======================
// Ye[e,d] = invDe[e] * sum_t val_t * U[idx_t, d]
__global__ __launch_bounds__(256) void ye_mat(const float* __restrict__ U,
                                              const float* __restrict__ tkv,
                                              const int* __restrict__ tki,
                                              const float* __restrict__ invDe,
                                              float* __restrict__ Ye) {
  const int e = blockIdx.x, d = threadIdx.x;
  __shared__ float sv[TK_];
  __shared__ int si[TK_];
  if (d < TK_) { sv[d] = tkv[(size_t)e * TK_ + d]; si[d] = tki[(size_t)e * TK_ + d]; }
  __syncthreads();
  float a = 0.f;
#pragma unroll
  for (int q = 0; q < TK_; ++q) a += sv[q] * U[(size_t)si[q] * D_ + d];
  Ye[(size_t)e * D_ + d] = a * invDe[e];
}

// Z = B Ye per node; combine:
//  mode 1 (T1 = Lt X):      out = (2/lam - 1)*M - (2/lam)*Dvis*Z
//  mode 2 (T2 = 2 Lt T1-X): out = (4/lam - 2)*M - (4/lam)*Dvis*Z - G
__global__ __launch_bounds__(256) void bgather_combine(const float* __restrict__ Ye,
                                                       const int* __restrict__ off,
                                                       const int* __restrict__ ince,
                                                       const float* __restrict__ incv,
                                                       const float* __restrict__ Dvis,
                                                       const float* __restrict__ Mx,
                                                       const float* __restrict__ G,
                                                       const float* __restrict__ scal,
                                                       float* __restrict__ out, int mode) {
  const int m = blockIdx.x, d = threadIdx.x;
  const int j0 = off[m], j1 = off[m + 1];
  float z = 0.f;
  for (int j = j0; j < j1; ++j) z += incv[j] * Ye[(size_t)ince[j] * D_ + d];
  const float lam = scal[5];
  const float c = 2.0f / lam;
  const size_t idx = (size_t)m * D_ + d;
  const float zz = Dvis[m] * z;
  float r;
  if (mode == 1) r = (c - 1.0f) * Mx[idx] - c * zz;
  else           r = (2.0f * c - 2.0f) * Mx[idx] - 2.0f * c * zz - G[idx];
  out[idx] = r;
}

// cheb combine + ELU + residual blend
__global__ void mix_kernel(const float* __restrict__ X, const float* __restrict__ T1,
                           const float* __restrict__ T2, const float* __restrict__ theta,
                           const float* __restrict__ Zpart, int splitk,
                           const float* __restrict__ scal, float* __restrict__ Zmix) {
  const int i = blockIdx.x * 256 + threadIdx.x;
  const int d = i & (D_ - 1);
  float cheb = X[i] * theta[d] + T1[i] * theta[D_ + d] + T2[i] * theta[2 * D_ + d];
  float zs = cheb > 0.f ? cheb : expm1f(cheb);
  float zk = 0.f;
  for (int s = 0; s < splitk; ++s) zk += Zpart[(size_t)s * N_ * D_ + i];
  const float rho = scal[4];
  Zmix[i] = rho * zs + (1.0f - rho) * zk;
}

// ============================= launcher =============================

extern "C" void kernel_launch(void* const* d_in, const int* in_sizes, int n_in,
                              void* d_out, int out_size, void* d_ws, size_t ws_size,
                              hipStream_t stream) {
  const float* X       = (const float*)d_in[0];
  const float* L_k     = (const float*)d_in[1];
  const float* alpha   = (const float*)d_in[2];
  const float* theta   = (const float*)d_in[3];
  const float* rho_raw = (const float*)d_in[4];
  const float* proj_w  = (const float*)d_in[5];
  const float* proj_b  = (const float*)d_in[6];
  const float* v0      = (const float*)d_in[7];
  float* out = (float*)d_out;

  char* w = (char*)d_ws;
  size_t o = 0;
  auto alloc = [&](size_t bytes) -> char* {
    char* p = w + o; o += (bytes + 255) & ~(size_t)255; return p;
  };
  float* XL    = (float*)alloc((size_t)N_ * D_ * 4);
  float* S     = (float*)alloc((size_t)N_ * N_ * 4);
  float* rowmax= (float*)alloc(N_ * 4);
  float* rowZ  = (float*)alloc(N_ * 4);
  float* tkv   = (float*)alloc((size_t)NENT_ * 4);
  int*   tki   = (int*)  alloc((size_t)NENT_ * 4);
  float* invDe = (float*)alloc(E_ * 4);
  float* DvAcc = (float*)alloc(N_ * 4);
  float* Dvis  = (float*)alloc(N_ * 4);
  int*   cnt   = (int*)  alloc(N_ * 4);
  int*   off   = (int*)  alloc((N_ + 1) * 4);
  int*   cur   = (int*)  alloc(N_ * 4);
  int*   ince  = (int*)  alloc((size_t)NENT_ * 4);
  float* incv  = (float*)alloc((size_t)NENT_ * 4);
  float* vb    = (float*)alloc(N_ * 4);
  float* tb    = (float*)alloc(N_ * 4);
  float* yev   = (float*)alloc(E_ * 4);
  float* scal  = (float*)alloc(256);
  int SPLITK = 8;
  while (SPLITK > 1 && o + (size_t)SPLITK * N_ * D_ * 4 > ws_size) SPLITK >>= 1;
  float* Zpart = (float*)alloc((size_t)SPLITK * N_ * D_ * 4);
  const int kchunk = N_ / SPLITK;
  // phase-2 temporaries alias into S (dead after the k-loop): 32MB <= 64MB
  float* U    = S;
  float* Ye   = S + (size_t)N_ * D_;
  float* T1   = Ye + (size_t)E_ * D_;
  float* T2   = T1 + (size_t)N_ * D_;
  float* Zmix = T2 + (size_t)N_ * D_;

  scalars_kernel<<<1, 64, 0, stream>>>(alpha, rho_raw, scal);
  hipMemsetAsync(Zpart, 0, (size_t)SPLITK * N_ * D_ * 4, stream);
  hipMemsetAsync(DvAcc, 0, N_ * 4, stream);
  hipMemsetAsync(cnt, 0, N_ * 4, stream);

  for (int k = 0; k < K_; ++k) {
    gemm_nn64<<<dim3(N_ / 64, D_ / 64), 256, 0, stream>>>(
        X, L_k + (size_t)k * D_ * D_, XL, D_, D_, D_, D_);
    gemm_scores<<<dim3(N_ / 128, N_ / 128), 256, 0, stream>>>(
        XL, X, S, 1.0f / 16.0f);  // 1/sqrt(256)
    rowstats_topk<<<N_, 256, 0, stream>>>(
        S, rowmax, rowZ, tkv + (size_t)k * N_ * TK_, tki + (size_t)k * N_ * TK_);
    gemm_zkern<<<dim3(N_ / 128, D_ / 128, SPLITK), 256, 0, stream>>>(
        S, rowmax, rowZ, X, Zpart, scal, k, kchunk);
  }

  edge_scan<<<E_ / 256, 256, 0, stream>>>(tkv, tki, DvAcc, cnt, invDe);
  dvis_kernel<<<N_ / 256, 256, 0, stream>>>(DvAcc, Dvis);
  scan_offsets<<<1, 1024, 0, stream>>>(cnt, off, cur);
  edge_fill<<<E_ / 256, 256, 0, stream>>>(tkv, tki, cur, ince, incv);

  power_iter<<<1, 1024, 0, stream>>>(v0, Dvis, invDe, tkv, tki, off, ince, incv,
                                     vb, tb, yev, scal);

  // T1 = Lt @ X
  ew_scale<<<N_ * D_ / 256, 256, 0, stream>>>(X, Dvis, U);
  ye_mat<<<E_, 256, 0, stream>>>(U, tkv, tki, invDe, Ye);
  bgather_combine<<<N_, 256, 0, stream>>>(Ye, off, ince, incv, Dvis, X, X, scal, T1, 1);
  // T2 = 2*Lt @ T1 - X
  ew_scale<<<N_ * D_ / 256, 256, 0, stream>>>(T1, Dvis, U);
  ye_mat<<<E_, 256, 0, stream>>>(U, tkv, tki, invDe, Ye);
  bgather_combine<<<N_, 256, 0, stream>>>(Ye, off, ince, incv, Dvis, T1, X, scal, T2, 2);

  mix_kernel<<<N_ * D_ / 256, 256, 0, stream>>>(X, T1, T2, theta, Zpart, SPLITK, scal, Zmix);

  gemm_nt64_bias<<<dim3(N_ / 64, D_ / 64), 256, 0, stream>>>(
      Zmix, proj_w, proj_b, out, D_, D_, D_, D_);
}

// Round 2
// 1900.899 us; speedup vs baseline: 2.9160x; 2.9160x over previous
//
#include <hip/hip_runtime.h>
#include <math.h>

#define N_ 4096
#define D_ 256
#define K_ 4
#define TK_ 16
#define E_ (K_ * N_)          // 16384 hyperedges
#define NENT_ (E_ * TK_)      // 262144 incidence entries

// ============================= small kernels =============================

__global__ void scalars_kernel(const float* __restrict__ alpha,
                               const float* __restrict__ rho_raw,
                               float* __restrict__ scal) {
  if (threadIdx.x == 0) {
    float m = alpha[0];
    for (int k = 1; k < K_; ++k) m = fmaxf(m, alpha[k]);
    float e[K_]; float s = 0.f;
    for (int k = 0; k < K_; ++k) { e[k] = expf(alpha[k] - m); s += e[k]; }
    for (int k = 0; k < K_; ++k) scal[k] = e[k] / s;   // w_k
    scal[4] = 1.0f / (1.0f + expf(-rho_raw[0]));       // rho
  }
}

__global__ void dvis_kernel(const float* __restrict__ DvAcc, float* __restrict__ Dvis) {
  int i = blockIdx.x * 256 + threadIdx.x;
  Dvis[i] = 1.0f / sqrtf(DvAcc[i] + 1e-9f);
}

__global__ void ew_scale(const float* __restrict__ M, const float* __restrict__ Dvis,
                         float* __restrict__ U) {
  int i = blockIdx.x * 256 + threadIdx.x;
  U[i] = Dvis[i >> 8] * M[i];
}

// ============================= 64-tile fp32 GEMMs =============================
// C(MxN) = A(MxK) @ B(KxN), row-major. grid=(M/64, N/64), 256 thr, 4x4/thread.
__global__ __launch_bounds__(256) void gemm_nn64(const float* __restrict__ A,
                                                 const float* __restrict__ B,
                                                 float* __restrict__ C,
                                                 int Kdim, int lda, int ldb, int ldc) {
  __shared__ float As[16][68];
  __shared__ float Bs[16][68];
  const int tid = threadIdx.x;
  const int bm = blockIdx.x * 64, bn = blockIdx.y * 64;
  const int lrA = tid >> 2, lcA = (tid & 3) * 4;   // A tile 64x16
  const int rrB = tid >> 4, ccB = (tid & 15) * 4;  // B tile 16x64
  const int tx = tid & 15, ty = tid >> 4;
  const float* Ap = A + (size_t)(bm + lrA) * lda + lcA;
  const float* Bp = B + (size_t)rrB * ldb + bn + ccB;
  float acc[4][4] = {};
  for (int k0 = 0; k0 < Kdim; k0 += 16) {
    float4 av = *(const float4*)(Ap + k0);
    float4 bv = *(const float4*)(Bp + (size_t)k0 * ldb);
    __syncthreads();
    As[lcA + 0][lrA] = av.x; As[lcA + 1][lrA] = av.y;
    As[lcA + 2][lrA] = av.z; As[lcA + 3][lrA] = av.w;
    *(float4*)&Bs[rrB][ccB] = bv;
    __syncthreads();
#pragma unroll
    for (int kk = 0; kk < 16; ++kk) {
      float a[4], b[4];
      *(float4*)a = *(const float4*)&As[kk][ty * 4];
      *(float4*)b = *(const float4*)&Bs[kk][tx * 4];
#pragma unroll
      for (int i = 0; i < 4; ++i)
#pragma unroll
        for (int j = 0; j < 4; ++j) acc[i][j] += a[i] * b[j];
    }
  }
#pragma unroll
  for (int i = 0; i < 4; ++i) {
    int row = bm + ty * 4 + i;
    float4 o; o.x = acc[i][0]; o.y = acc[i][1]; o.z = acc[i][2]; o.w = acc[i][3];
    *(float4*)(C + (size_t)row * ldc + bn + tx * 4) = o;
  }
}

// C(MxN) = A(MxK) @ B(NxK)^T + bias, row-major. grid=(M/64, N/64).
__global__ __launch_bounds__(256) void gemm_nt64_bias(const float* __restrict__ A,
                                                      const float* __restrict__ B,
                                                      const float* __restrict__ bias,
                                                      float* __restrict__ C,
                                                      int Kdim, int lda, int ldb, int ldc) {
  __shared__ float As[16][68];
  __shared__ float Bs[16][68];
  const int tid = threadIdx.x;
  const int bm = blockIdx.x * 64, bn = blockIdx.y * 64;
  const int lr = tid >> 2, lc = (tid & 3) * 4;
  const int tx = tid & 15, ty = tid >> 4;
  const float* Ap = A + (size_t)(bm + lr) * lda + lc;
  const float* Bp = B + (size_t)(bn + lr) * ldb + lc;
  float acc[4][4] = {};
  for (int k0 = 0; k0 < Kdim; k0 += 16) {
    float4 av = *(const float4*)(Ap + k0);
    float4 bv = *(const float4*)(Bp + k0);
    __syncthreads();
    As[lc + 0][lr] = av.x; As[lc + 1][lr] = av.y; As[lc + 2][lr] = av.z; As[lc + 3][lr] = av.w;
    Bs[lc + 0][lr] = bv.x; Bs[lc + 1][lr] = bv.y; Bs[lc + 2][lr] = bv.z; Bs[lc + 3][lr] = bv.w;
    __syncthreads();
#pragma unroll
    for (int kk = 0; kk < 16; ++kk) {
      float a[4], b[4];
      *(float4*)a = *(const float4*)&As[kk][ty * 4];
      *(float4*)b = *(const float4*)&Bs[kk][tx * 4];
#pragma unroll
      for (int i = 0; i < 4; ++i)
#pragma unroll
        for (int j = 0; j < 4; ++j) acc[i][j] += a[i] * b[j];
    }
  }
#pragma unroll
  for (int i = 0; i < 4; ++i) {
    int row = bm + ty * 4 + i;
    float4 o;
    o.x = acc[i][0] + bias[bn + tx * 4 + 0];
    o.y = acc[i][1] + bias[bn + tx * 4 + 1];
    o.z = acc[i][2] + bias[bn + tx * 4 + 2];
    o.w = acc[i][3] + bias[bn + tx * 4 + 3];
    *(float4*)(C + (size_t)row * ldc + bn + tx * 4) = o;
  }
}

// ============================= 128-tile fp32 GEMMs =============================
// scores: C(4096x4096) = A(4096x256) @ B(4096x256)^T * scale. grid (32,32).
__global__ __launch_bounds__(256) void gemm_scores(const float* __restrict__ A,
                                                   const float* __restrict__ B,
                                                   float* __restrict__ C, float scale) {
  __shared__ float As[8][132];
  __shared__ float Bs[8][132];
  const int tid = threadIdx.x;
  const int bm = blockIdx.x * 128, bn = blockIdx.y * 128;
  const int lr = tid >> 1, lc = (tid & 1) * 4;
  const int tx = tid & 15, ty = tid >> 4;
  const float* Ap = A + (size_t)(bm + lr) * D_ + lc;
  const float* Bp = B + (size_t)(bn + lr) * D_ + lc;
  float acc[8][8] = {};
  for (int k0 = 0; k0 < D_; k0 += 8) {
    float4 av = *(const float4*)(Ap + k0);
    float4 bv = *(const float4*)(Bp + k0);
    __syncthreads();
    As[lc + 0][lr] = av.x; As[lc + 1][lr] = av.y; As[lc + 2][lr] = av.z; As[lc + 3][lr] = av.w;
    Bs[lc + 0][lr] = bv.x; Bs[lc + 1][lr] = bv.y; Bs[lc + 2][lr] = bv.z; Bs[lc + 3][lr] = bv.w;
    __syncthreads();
#pragma unroll
    for (int kk = 0; kk < 8; ++kk) {
      float a[8], b[8];
      *(float4*)(a + 0) = *(const float4*)&As[kk][ty * 8];
      *(float4*)(a + 4) = *(const float4*)&As[kk][ty * 8 + 4];
      *(float4*)(b + 0) = *(const float4*)&Bs[kk][tx * 8];
      *(float4*)(b + 4) = *(const float4*)&Bs[kk][tx * 8 + 4];
#pragma unroll
      for (int i = 0; i < 8; ++i)
#pragma unroll
        for (int j = 0; j < 8; ++j) acc[i][j] += a[i] * b[j];
    }
  }
#pragma unroll
  for (int i = 0; i < 8; ++i) {
    int row = bm + ty * 8 + i;
    float4 o0, o1;
    o0.x = acc[i][0] * scale; o0.y = acc[i][1] * scale; o0.z = acc[i][2] * scale; o0.w = acc[i][3] * scale;
    o1.x = acc[i][4] * scale; o1.y = acc[i][5] * scale; o1.z = acc[i][6] * scale; o1.w = acc[i][7] * scale;
    *(float4*)(C + (size_t)row * N_ + bn + tx * 8) = o0;
    *(float4*)(C + (size_t)row * N_ + bn + tx * 8 + 4) = o1;
  }
}

// Zpart[ks] += w_k * H_k @ X ; H = exp(S - rowmax)/rowZ computed on A-load.
// grid (32, 2, SPLITK), K-chunk = 4096/SPLITK.
__global__ __launch_bounds__(256) void gemm_zkern(const float* __restrict__ S,
                                                  const float* __restrict__ rowmax,
                                                  const float* __restrict__ rowZ,
                                                  const float* __restrict__ X,
                                                  float* __restrict__ Zpart,
                                                  const float* __restrict__ scal,
                                                  int kidx, int kchunk) {
  __shared__ float As[8][132];
  __shared__ float Bs[8][132];
  const int tid = threadIdx.x;
  const int bm = blockIdx.x * 128, bn = blockIdx.y * 128;
  const int ks = blockIdx.z;
  const int k0base = ks * kchunk;
  const int lrA = tid >> 1, lcA = (tid & 1) * 4;
  const int rrB = tid >> 5, ccB = (tid & 31) * 4;
  const int tx = tid & 15, ty = tid >> 4;
  const int arow = bm + lrA;
  const float rm = rowmax[arow];
  const float rzinv = 1.0f / rowZ[arow];
  const float wk = scal[kidx];
  const float* Sp = S + (size_t)arow * N_ + k0base + lcA;
  const float* Xp = X + (size_t)(k0base + rrB) * D_ + bn + ccB;
  float acc[8][8] = {};
  for (int k0 = 0; k0 < kchunk; k0 += 8) {
    float4 sv = *(const float4*)(Sp + k0);
    float4 xv = *(const float4*)(Xp + (size_t)k0 * D_);
    float4 av;
    av.x = expf(sv.x - rm) * rzinv; av.y = expf(sv.y - rm) * rzinv;
    av.z = expf(sv.z - rm) * rzinv; av.w = expf(sv.w - rm) * rzinv;
    __syncthreads();
    As[lcA + 0][lrA] = av.x; As[lcA + 1][lrA] = av.y;
    As[lcA + 2][lrA] = av.z; As[lcA + 3][lrA] = av.w;
    *(float4*)&Bs[rrB][ccB] = xv;
    __syncthreads();
#pragma unroll
    for (int kk = 0; kk < 8; ++kk) {
      float a[8], b[8];
      *(float4*)(a + 0) = *(const float4*)&As[kk][ty * 8];
      *(float4*)(a + 4) = *(const float4*)&As[kk][ty * 8 + 4];
      *(float4*)(b + 0) = *(const float4*)&Bs[kk][tx * 8];
      *(float4*)(b + 4) = *(const float4*)&Bs[kk][tx * 8 + 4];
#pragma unroll
      for (int i = 0; i < 8; ++i)
#pragma unroll
        for (int j = 0; j < 8; ++j) acc[i][j] += a[i] * b[j];
    }
  }
  float* Zp = Zpart + (size_t)ks * N_ * D_;
#pragma unroll
  for (int i = 0; i < 8; ++i) {
    int row = bm + ty * 8 + i;
    float* base = Zp + (size_t)row * D_ + bn + tx * 8;
    float4 c0 = *(float4*)base;
    float4 c1 = *(float4*)(base + 4);
    c0.x += wk * acc[i][0]; c0.y += wk * acc[i][1]; c0.z += wk * acc[i][2]; c0.w += wk * acc[i][3];
    c1.x += wk * acc[i][4]; c1.y += wk * acc[i][5]; c1.z += wk * acc[i][6]; c1.w += wk * acc[i][7];
    *(float4*)base = c0;
    *(float4*)(base + 4) = c1;
  }
}

// ======================= per-row stats + top-16 =======================
__global__ __launch_bounds__(256) void rowstats_topk(const float* __restrict__ S,
                                                     float* __restrict__ rowmax,
                                                     float* __restrict__ rowZ,
                                                     float* __restrict__ tkv,
                                                     int* __restrict__ tki) {
  const int row = blockIdx.x, tid = threadIdx.x;
  __shared__ float buf[N_];
  __shared__ float rv[256];
  __shared__ int ri[256];
  __shared__ float stk[TK_];
  __shared__ int itk[TK_];
  __shared__ float sden;
  const float4* Sp = (const float4*)(S + (size_t)row * N_);
  float lmax = -3.4e38f;
#pragma unroll
  for (int it = 0; it < 4; ++it) {
    float4 v = Sp[tid + it * 256];
    ((float4*)buf)[tid + it * 256] = v;
    lmax = fmaxf(lmax, fmaxf(fmaxf(v.x, v.y), fmaxf(v.z, v.w)));
  }
  rv[tid] = lmax;
  __syncthreads();
  for (int s = 128; s; s >>= 1) { if (tid < s) rv[tid] = fmaxf(rv[tid], rv[tid + s]); __syncthreads(); }
  const float M = rv[0];
  __syncthreads();
  float ls = 0.f;
  for (int i = tid; i < N_; i += 256) ls += expf(buf[i] - M);
  rv[tid] = ls;
  __syncthreads();
  for (int s = 128; s; s >>= 1) { if (tid < s) rv[tid] += rv[tid + s]; __syncthreads(); }
  const float Z = rv[0];
  if (tid == 0) { rowmax[row] = M; rowZ[row] = Z; }
  __syncthreads();
  for (int t = 0; t < TK_; ++t) {
    float bmv = -3.4e38f; int bi = 0x7fffffff;
    for (int i = tid; i < N_; i += 256) { float v = buf[i]; if (v > bmv) { bmv = v; bi = i; } }
#pragma unroll
    for (int off = 32; off; off >>= 1) {
      float ov = __shfl_xor(bmv, off);
      int oi = __shfl_xor(bi, off);
      if (ov > bmv || (ov == bmv && oi < bi)) { bmv = ov; bi = oi; }
    }
    const int wid = tid >> 6, lane = tid & 63;
    if (lane == 0) { rv[wid] = bmv; ri[wid] = bi; }
    __syncthreads();
    if (tid == 0) {
      float b0 = rv[0]; int i0 = ri[0];
      for (int wv = 1; wv < 4; ++wv)
        if (rv[wv] > b0 || (rv[wv] == b0 && ri[wv] < i0)) { b0 = rv[wv]; i0 = ri[wv]; }
      stk[t] = b0; itk[t] = i0; buf[i0] = -3.4e38f;
    }
    __syncthreads();
  }
  if (tid < TK_) rv[tid] = expf(stk[tid] - M) / Z;
  __syncthreads();
  if (tid == 0) { float s = 0.f; for (int t = 0; t < TK_; ++t) s += rv[t]; sden = s + 1e-9f; }
  __syncthreads();
  if (tid < TK_) {
    tkv[(size_t)row * TK_ + tid] = rv[tid] / sden;
    tki[(size_t)row * TK_ + tid] = itk[tid];
  }
}

// ======================= hypergraph build =======================
__global__ void edge_scan(const float* __restrict__ tkv, const int* __restrict__ tki,
                          float* __restrict__ DvAcc, int* __restrict__ cnt,
                          float* __restrict__ invDe) {
  int e = blockIdx.x * 256 + threadIdx.x;
  float s = 0.f;
#pragma unroll
  for (int q = 0; q < TK_; ++q) s += tkv[(size_t)e * TK_ + q];
  invDe[e] = 1.0f / (s + 1e-9f);
#pragma unroll
  for (int q = 0; q < TK_; ++q) {
    int m = tki[(size_t)e * TK_ + q];
    atomicAdd(&DvAcc[m], tkv[(size_t)e * TK_ + q]);
    atomicAdd(&cnt[m], 1);
  }
}

__global__ __launch_bounds__(1024) void scan_offsets(const int* __restrict__ cnt,
                                                     int* __restrict__ off,
                                                     int* __restrict__ cur) {
  __shared__ int part[1024];
  const int t = threadIdx.x;
  const int b = t * 4;
  int c0 = cnt[b], c1 = cnt[b + 1], c2 = cnt[b + 2], c3 = cnt[b + 3];
  part[t] = c0 + c1 + c2 + c3;
  __syncthreads();
  for (int o = 1; o < 1024; o <<= 1) {
    int v = part[t] + ((t >= o) ? part[t - o] : 0);
    __syncthreads();
    part[t] = v;
    __syncthreads();
  }
  int ex = (t == 0) ? 0 : part[t - 1];
  off[b] = ex; off[b + 1] = ex + c0; off[b + 2] = ex + c0 + c1; off[b + 3] = ex + c0 + c1 + c2;
  cur[b] = off[b]; cur[b + 1] = off[b + 1]; cur[b + 2] = off[b + 2]; cur[b + 3] = off[b + 3];
  if (t == 1023) off[N_] = part[1023];
}

__global__ void edge_fill(const float* __restrict__ tkv, const int* __restrict__ tki,
                          int* __restrict__ cur, int* __restrict__ ince,
                          float* __restrict__ incv) {
  int e = blockIdx.x * 256 + threadIdx.x;
#pragma unroll
  for (int q = 0; q < TK_; ++q) {
    int m = tki[(size_t)e * TK_ + q];
    int pos = atomicAdd(&cur[m], 1);
    ince[pos] = e;
    incv[pos] = tkv[(size_t)e * TK_ + q];
  }
}

// ======================= power iteration (multi-kernel, unnormalized) ==========
// Direction-only power iteration: skip per-step normalization (L is linear;
// ||L||<=2 so 5 steps grow <=32x, fp32-safe), fold it into the final Rayleigh
// quotient lam = (v' L v)/(v' v). Removes all grid-wide syncs between matvecs.

__global__ void pi_init(const float* __restrict__ v0, const float* __restrict__ Dvis,
                        float* __restrict__ v, float* __restrict__ u) {
  int i = blockIdx.x * 256 + threadIdx.x;
  float x = v0[i];
  v[i] = x; u[i] = Dvis[i] * x;
}

// ye[e] = invDe[e] * sum_q tkv[e,q] * u[tki[e,q]]
__global__ void pi_ye(const float* __restrict__ u, const float* __restrict__ tkv,
                      const int* __restrict__ tki, const float* __restrict__ invDe,
                      float* __restrict__ ye) {
  int e = blockIdx.x * 256 + threadIdx.x;
  const float* tv = tkv + (size_t)e * TK_;
  const int* ti = tki + (size_t)e * TK_;
  float a = 0.f;
#pragma unroll
  for (int q = 0; q < TK_; ++q) a += tv[q] * u[ti[q]];
  ye[e] = a * invDe[e];
}

// vn[m] = v[m] - Dvis[m] * sum_j incv[j]*ye[ince[j]] ; un = Dvis*vn
__global__ void pi_step(const float* __restrict__ v, const float* __restrict__ ye,
                        const int* __restrict__ off, const int* __restrict__ ince,
                        const float* __restrict__ incv, const float* __restrict__ Dvis,
                        float* __restrict__ vn, float* __restrict__ un) {
  int m = blockIdx.x * 256 + threadIdx.x;
  float z = 0.f;
  int j0 = off[m], j1 = off[m + 1];
  for (int j = j0; j < j1; ++j) z += incv[j] * ye[ince[j]];
  float wv = v[m] - Dvis[m] * z;
  vn[m] = wv; un[m] = Dvis[m] * wv;
}

// final matvec + per-block partial dots (v.Lv, v.v)
__global__ __launch_bounds__(256) void pi_final(const float* __restrict__ v,
                                                const float* __restrict__ ye,
                                                const int* __restrict__ off,
                                                const int* __restrict__ ince,
                                                const float* __restrict__ incv,
                                                const float* __restrict__ Dvis,
                                                float* __restrict__ partial) {
  __shared__ float r1[256], r2[256];
  int m = blockIdx.x * 256 + threadIdx.x;
  float z = 0.f;
  int j0 = off[m], j1 = off[m + 1];
  for (int j = j0; j < j1; ++j) z += incv[j] * ye[ince[j]];
  float wv = v[m] - Dvis[m] * z;
  r1[threadIdx.x] = v[m] * wv;
  r2[threadIdx.x] = v[m] * v[m];
  __syncthreads();
  for (int s = 128; s; s >>= 1) {
    if (threadIdx.x < s) { r1[threadIdx.x] += r1[threadIdx.x + s]; r2[threadIdx.x] += r2[threadIdx.x + s]; }
    __syncthreads();
  }
  if (threadIdx.x == 0) { partial[blockIdx.x * 2] = r1[0]; partial[blockIdx.x * 2 + 1] = r2[0]; }
}

__global__ void pi_lam(const float* __restrict__ partial, float* __restrict__ scal) {
  if (threadIdx.x == 0) {
    float s1 = 0.f, s2 = 0.f;
    for (int b = 0; b < N_ / 256; ++b) { s1 += partial[2 * b]; s2 += partial[2 * b + 1]; }
    scal[5] = fmaxf(s1 / s2, 1e-3f);
  }
}

// ======================= Chebyshev sparse applies =======================
__global__ __launch_bounds__(256) void ye_mat(const float* __restrict__ U,
                                              const float* __restrict__ tkv,
                                              const int* __restrict__ tki,
                                              const float* __restrict__ invDe,
                                              float* __restrict__ Ye) {
  const int e = blockIdx.x, d = threadIdx.x;
  __shared__ float sv[TK_];
  __shared__ int si[TK_];
  if (d < TK_) { sv[d] = tkv[(size_t)e * TK_ + d]; si[d] = tki[(size_t)e * TK_ + d]; }
  __syncthreads();
  float a = 0.f;
#pragma unroll
  for (int q = 0; q < TK_; ++q) a += sv[q] * U[(size_t)si[q] * D_ + d];
  Ye[(size_t)e * D_ + d] = a * invDe[e];
}

__global__ __launch_bounds__(256) void bgather_combine(const float* __restrict__ Ye,
                                                       const int* __restrict__ off,
                                                       const int* __restrict__ ince,
                                                       const float* __restrict__ incv,
                                                       const float* __restrict__ Dvis,
                                                       const float* __restrict__ Mx,
                                                       const float* __restrict__ G,
                                                       const float* __restrict__ scal,
                                                       float* __restrict__ out, int mode) {
  const int m = blockIdx.x, d = threadIdx.x;
  const int j0 = off[m], j1 = off[m + 1];
  float z = 0.f;
  for (int j = j0; j < j1; ++j) z += incv[j] * Ye[(size_t)ince[j] * D_ + d];
  const float lam = scal[5];
  const float c = 2.0f / lam;
  const size_t idx = (size_t)m * D_ + d;
  const float zz = Dvis[m] * z;
  float r;
  if (mode == 1) r = (c - 1.0f) * Mx[idx] - c * zz;
  else           r = (2.0f * c - 2.0f) * Mx[idx] - 2.0f * c * zz - G[idx];
  out[idx] = r;
}

// cheb combine + ELU + residual blend
__global__ void mix_kernel(const float* __restrict__ X, const float* __restrict__ T1,
                           const float* __restrict__ T2, const float* __restrict__ theta,
                           const float* __restrict__ Zpart, int splitk,
                           const float* __restrict__ scal, float* __restrict__ Zmix) {
  const int i = blockIdx.x * 256 + threadIdx.x;
  const int d = i & (D_ - 1);
  float cheb = X[i] * theta[d] + T1[i] * theta[D_ + d] + T2[i] * theta[2 * D_ + d];
  float zs = cheb > 0.f ? cheb : expm1f(cheb);
  float zk = 0.f;
  for (int s = 0; s < splitk; ++s) zk += Zpart[(size_t)s * N_ * D_ + i];
  const float rho = scal[4];
  Zmix[i] = rho * zs + (1.0f - rho) * zk;
}

// ============================= launcher =============================

extern "C" void kernel_launch(void* const* d_in, const int* in_sizes, int n_in,
                              void* d_out, int out_size, void* d_ws, size_t ws_size,
                              hipStream_t stream) {
  const float* X       = (const float*)d_in[0];
  const float* L_k     = (const float*)d_in[1];
  const float* alpha   = (const float*)d_in[2];
  const float* theta   = (const float*)d_in[3];
  const float* rho_raw = (const float*)d_in[4];
  const float* proj_w  = (const float*)d_in[5];
  const float* proj_b  = (const float*)d_in[6];
  const float* v0      = (const float*)d_in[7];
  float* out = (float*)d_out;

  char* w = (char*)d_ws;
  size_t o = 0;
  auto alloc = [&](size_t bytes) -> char* {
    char* p = w + o; o += (bytes + 255) & ~(size_t)255; return p;
  };
  float* XL    = (float*)alloc((size_t)N_ * D_ * 4);
  float* S     = (float*)alloc((size_t)N_ * N_ * 4);
  float* rowmax= (float*)alloc(N_ * 4);
  float* rowZ  = (float*)alloc(N_ * 4);
  float* tkv   = (float*)alloc((size_t)NENT_ * 4);
  int*   tki   = (int*)  alloc((size_t)NENT_ * 4);
  float* invDe = (float*)alloc(E_ * 4);
  float* DvAcc = (float*)alloc(N_ * 4);
  float* Dvis  = (float*)alloc(N_ * 4);
  int*   cnt   = (int*)  alloc(N_ * 4);
  int*   off   = (int*)  alloc((N_ + 1) * 4);
  int*   cur   = (int*)  alloc(N_ * 4);
  int*   ince  = (int*)  alloc((size_t)NENT_ * 4);
  float* incv  = (float*)alloc((size_t)NENT_ * 4);
  float* va    = (float*)alloc(N_ * 4);
  float* ua    = (float*)alloc(N_ * 4);
  float* vbuf  = (float*)alloc(N_ * 4);
  float* ubuf  = (float*)alloc(N_ * 4);
  float* yev   = (float*)alloc(E_ * 4);
  float* part  = (float*)alloc((N_ / 256) * 2 * 4);
  float* scal  = (float*)alloc(256);
  int SPLITK = 8;
  while (SPLITK > 1 && o + (size_t)SPLITK * N_ * D_ * 4 > ws_size) SPLITK >>= 1;
  float* Zpart = (float*)alloc((size_t)SPLITK * N_ * D_ * 4);
  const int kchunk = N_ / SPLITK;
  // phase-2 temporaries alias into S (dead after the k-loop): 32MB <= 64MB
  float* U    = S;
  float* Ye   = S + (size_t)N_ * D_;
  float* T1   = Ye + (size_t)E_ * D_;
  float* T2   = T1 + (size_t)N_ * D_;
  float* Zmix = T2 + (size_t)N_ * D_;

  scalars_kernel<<<1, 64, 0, stream>>>(alpha, rho_raw, scal);
  hipMemsetAsync(Zpart, 0, (size_t)SPLITK * N_ * D_ * 4, stream);
  hipMemsetAsync(DvAcc, 0, N_ * 4, stream);
  hipMemsetAsync(cnt, 0, N_ * 4, stream);

  for (int k = 0; k < K_; ++k) {
    gemm_nn64<<<dim3(N_ / 64, D_ / 64), 256, 0, stream>>>(
        X, L_k + (size_t)k * D_ * D_, XL, D_, D_, D_, D_);
    gemm_scores<<<dim3(N_ / 128, N_ / 128), 256, 0, stream>>>(
        XL, X, S, 1.0f / 16.0f);  // 1/sqrt(256)
    rowstats_topk<<<N_, 256, 0, stream>>>(
        S, rowmax, rowZ, tkv + (size_t)k * N_ * TK_, tki + (size_t)k * N_ * TK_);
    gemm_zkern<<<dim3(N_ / 128, D_ / 128, SPLITK), 256, 0, stream>>>(
        S, rowmax, rowZ, X, Zpart, scal, k, kchunk);
  }

  edge_scan<<<E_ / 256, 256, 0, stream>>>(tkv, tki, DvAcc, cnt, invDe);
  dvis_kernel<<<N_ / 256, 256, 0, stream>>>(DvAcc, Dvis);
  scan_offsets<<<1, 1024, 0, stream>>>(cnt, off, cur);
  edge_fill<<<E_ / 256, 256, 0, stream>>>(tkv, tki, cur, ince, incv);

  // power iteration: 5 unnormalized matvecs + Rayleigh quotient
  pi_init<<<N_ / 256, 256, 0, stream>>>(v0, Dvis, va, ua);
  float* vc = va; float* uc = ua; float* vn = vbuf; float* un = ubuf;
  for (int it = 0; it < 5; ++it) {
    pi_ye<<<E_ / 256, 256, 0, stream>>>(uc, tkv, tki, invDe, yev);
    pi_step<<<N_ / 256, 256, 0, stream>>>(vc, yev, off, ince, incv, Dvis, vn, un);
    float* tv = vc; vc = vn; vn = tv;
    float* tu = uc; uc = un; un = tu;
  }
  pi_ye<<<E_ / 256, 256, 0, stream>>>(uc, tkv, tki, invDe, yev);
  pi_final<<<N_ / 256, 256, 0, stream>>>(vc, yev, off, ince, incv, Dvis, part);
  pi_lam<<<1, 64, 0, stream>>>(part, scal);

  // T1 = Lt @ X
  ew_scale<<<N_ * D_ / 256, 256, 0, stream>>>(X, Dvis, U);
  ye_mat<<<E_, 256, 0, stream>>>(U, tkv, tki, invDe, Ye);
  bgather_combine<<<N_, 256, 0, stream>>>(Ye, off, ince, incv, Dvis, X, X, scal, T1, 1);
  // T2 = 2*Lt @ T1 - X
  ew_scale<<<N_ * D_ / 256, 256, 0, stream>>>(T1, Dvis, U);
  ye_mat<<<E_, 256, 0, stream>>>(U, tkv, tki, invDe, Ye);
  bgather_combine<<<N_, 256, 0, stream>>>(Ye, off, ince, incv, Dvis, T1, X, scal, T2, 2);

  mix_kernel<<<N_ * D_ / 256, 256, 0, stream>>>(X, T1, T2, theta, Zpart, SPLITK, scal, Zmix);

  gemm_nt64_bias<<<dim3(N_ / 64, D_ / 64), 256, 0, stream>>>(
      Zmix, proj_w, proj_b, out, D_, D_, D_, D_);
}

// Round 3
// 1764.958 us; speedup vs baseline: 3.1405x; 1.0770x over previous
//
#include <hip/hip_runtime.h>
#include <math.h>

#define N_ 4096
#define D_ 256
#define K_ 4
#define TK_ 16
#define E_ (K_ * N_)          // 16384 hyperedges
#define NENT_ (E_ * TK_)      // 262144 incidence entries

typedef unsigned short u16;
typedef unsigned int u32;
typedef __attribute__((ext_vector_type(8))) short bf16x8;
typedef __attribute__((ext_vector_type(4))) float f32x4;

__device__ __forceinline__ u16 bf16_rne(float x) {
  u32 u = __float_as_uint(x);
  u32 r = u + 0x7FFFu + ((u >> 16) & 1u);
  return (u16)(r >> 16);
}

// ============================= small kernels =============================

__global__ void scalars_kernel(const float* __restrict__ alpha,
                               const float* __restrict__ rho_raw,
                               float* __restrict__ scal) {
  if (threadIdx.x == 0) {
    float m = alpha[0];
    for (int k = 1; k < K_; ++k) m = fmaxf(m, alpha[k]);
    float e[K_]; float s = 0.f;
    for (int k = 0; k < K_; ++k) { e[k] = expf(alpha[k] - m); s += e[k]; }
    for (int k = 0; k < K_; ++k) scal[k] = e[k] / s;   // w_k
    scal[4] = 1.0f / (1.0f + expf(-rho_raw[0]));       // rho
  }
}

__global__ void dvis_kernel(const float* __restrict__ DvAcc, float* __restrict__ Dvis) {
  int i = blockIdx.x * 256 + threadIdx.x;
  Dvis[i] = 1.0f / sqrtf(DvAcc[i] + 1e-9f);
}

__global__ void ew_scale(const float* __restrict__ M, const float* __restrict__ Dvis,
                         float* __restrict__ U) {
  int i = blockIdx.x * 256 + threadIdx.x;
  U[i] = Dvis[i >> 8] * M[i];
}

// fp32 -> (hi, lo) bf16 split, 4 elems/thread
__global__ void cvt_split4(const float* __restrict__ in, u16* __restrict__ hi,
                           u16* __restrict__ lo) {
  int i = (blockIdx.x * 256 + threadIdx.x) * 4;
  float4 v = *(const float4*)(in + i);
  u16 h0 = bf16_rne(v.x), h1 = bf16_rne(v.y), h2 = bf16_rne(v.z), h3 = bf16_rne(v.w);
  float f0 = __uint_as_float((u32)h0 << 16), f1 = __uint_as_float((u32)h1 << 16);
  float f2 = __uint_as_float((u32)h2 << 16), f3 = __uint_as_float((u32)h3 << 16);
  u16 l0 = bf16_rne(v.x - f0), l1 = bf16_rne(v.y - f1);
  u16 l2 = bf16_rne(v.z - f2), l3 = bf16_rne(v.w - f3);
  *(uint2*)(hi + i) = make_uint2((u32)h0 | ((u32)h1 << 16), (u32)h2 | ((u32)h3 << 16));
  *(uint2*)(lo + i) = make_uint2((u32)l0 | ((u32)l1 << 16), (u32)l2 | ((u32)l3 << 16));
}

// X [N][D] fp32 -> XhT/XlT [D][N] bf16 (transposed split). grid (D/32, N/32), 256 thr.
__global__ __launch_bounds__(256) void transpose_split(const float* __restrict__ X,
                                                       u16* __restrict__ ht,
                                                       u16* __restrict__ lt) {
  __shared__ float tile[32][33];
  const int tx = threadIdx.x & 31, ty = threadIdx.x >> 5;  // 32x8
  const int d0 = blockIdx.x * 32, n0 = blockIdx.y * 32;
#pragma unroll
  for (int q = 0; q < 4; ++q)
    tile[ty + q * 8][tx] = X[(size_t)(n0 + ty + q * 8) * D_ + d0 + tx];
  __syncthreads();
#pragma unroll
  for (int q = 0; q < 4; ++q) {
    int dd = ty + q * 8;
    float v = tile[tx][dd];               // = X[n0+tx][d0+dd]
    u16 h = bf16_rne(v);
    float hf = __uint_as_float((u32)h << 16);
    u16 l = bf16_rne(v - hf);
    ht[(size_t)(d0 + dd) * N_ + n0 + tx] = h;
    lt[(size_t)(d0 + dd) * N_ + n0 + tx] = l;
  }
}

// ============================= 64-tile fp32 GEMMs =============================
// C(MxN) = A(MxK) @ B(KxN), row-major. grid=(M/64, N/64), 256 thr, 4x4/thread.
__global__ __launch_bounds__(256) void gemm_nn64(const float* __restrict__ A,
                                                 const float* __restrict__ B,
                                                 float* __restrict__ C,
                                                 int Kdim, int lda, int ldb, int ldc) {
  __shared__ float As[16][68];
  __shared__ float Bs[16][68];
  const int tid = threadIdx.x;
  const int bm = blockIdx.x * 64, bn = blockIdx.y * 64;
  const int lrA = tid >> 2, lcA = (tid & 3) * 4;
  const int rrB = tid >> 4, ccB = (tid & 15) * 4;
  const int tx = tid & 15, ty = tid >> 4;
  const float* Ap = A + (size_t)(bm + lrA) * lda + lcA;
  const float* Bp = B + (size_t)rrB * ldb + bn + ccB;
  float acc[4][4] = {};
  for (int k0 = 0; k0 < Kdim; k0 += 16) {
    float4 av = *(const float4*)(Ap + k0);
    float4 bv = *(const float4*)(Bp + (size_t)k0 * ldb);
    __syncthreads();
    As[lcA + 0][lrA] = av.x; As[lcA + 1][lrA] = av.y;
    As[lcA + 2][lrA] = av.z; As[lcA + 3][lrA] = av.w;
    *(float4*)&Bs[rrB][ccB] = bv;
    __syncthreads();
#pragma unroll
    for (int kk = 0; kk < 16; ++kk) {
      float a[4], b[4];
      *(float4*)a = *(const float4*)&As[kk][ty * 4];
      *(float4*)b = *(const float4*)&Bs[kk][tx * 4];
#pragma unroll
      for (int i = 0; i < 4; ++i)
#pragma unroll
        for (int j = 0; j < 4; ++j) acc[i][j] += a[i] * b[j];
    }
  }
#pragma unroll
  for (int i = 0; i < 4; ++i) {
    int row = bm + ty * 4 + i;
    float4 o; o.x = acc[i][0]; o.y = acc[i][1]; o.z = acc[i][2]; o.w = acc[i][3];
    *(float4*)(C + (size_t)row * ldc + bn + tx * 4) = o;
  }
}

// C(MxN) = A(MxK) @ B(NxK)^T + bias, row-major. grid=(M/64, N/64).
__global__ __launch_bounds__(256) void gemm_nt64_bias(const float* __restrict__ A,
                                                      const float* __restrict__ B,
                                                      const float* __restrict__ bias,
                                                      float* __restrict__ C,
                                                      int Kdim, int lda, int ldb, int ldc) {
  __shared__ float As[16][68];
  __shared__ float Bs[16][68];
  const int tid = threadIdx.x;
  const int bm = blockIdx.x * 64, bn = blockIdx.y * 64;
  const int lr = tid >> 2, lc = (tid & 3) * 4;
  const int tx = tid & 15, ty = tid >> 4;
  const float* Ap = A + (size_t)(bm + lr) * lda + lc;
  const float* Bp = B + (size_t)(bn + lr) * ldb + lc;
  float acc[4][4] = {};
  for (int k0 = 0; k0 < Kdim; k0 += 16) {
    float4 av = *(const float4*)(Ap + k0);
    float4 bv = *(const float4*)(Bp + k0);
    __syncthreads();
    As[lc + 0][lr] = av.x; As[lc + 1][lr] = av.y; As[lc + 2][lr] = av.z; As[lc + 3][lr] = av.w;
    Bs[lc + 0][lr] = bv.x; Bs[lc + 1][lr] = bv.y; Bs[lc + 2][lr] = bv.z; Bs[lc + 3][lr] = bv.w;
    __syncthreads();
#pragma unroll
    for (int kk = 0; kk < 16; ++kk) {
      float a[4], b[4];
      *(float4*)a = *(const float4*)&As[kk][ty * 4];
      *(float4*)b = *(const float4*)&Bs[kk][tx * 4];
#pragma unroll
      for (int i = 0; i < 4; ++i)
#pragma unroll
        for (int j = 0; j < 4; ++j) acc[i][j] += a[i] * b[j];
    }
  }
#pragma unroll
  for (int i = 0; i < 4; ++i) {
    int row = bm + ty * 4 + i;
    float4 o;
    o.x = acc[i][0] + bias[bn + tx * 4 + 0];
    o.y = acc[i][1] + bias[bn + tx * 4 + 1];
    o.z = acc[i][2] + bias[bn + tx * 4 + 2];
    o.w = acc[i][3] + bias[bn + tx * 4 + 3];
    *(float4*)(C + (size_t)row * ldc + bn + tx * 4) = o;
  }
}

// ===================== MFMA bf16-split GEMMs (3-pass hi/lo) =====================
// LDS tiles [128 rows][64 bf16] = 16 KB each, XOR-swizzled: byte ^= (row&7)<<4
// so ds_read_b128 of 16 rows x same 16B column spreads across banks (2-way max).

// S(4096x4096) = (Ah+Al)(Bh+Bl)^T * scale; A=XL split [N][256], B=X split [N][256].
__global__ __launch_bounds__(256) void scores_mfma(const u16* __restrict__ Ahg,
                                                   const u16* __restrict__ Alg,
                                                   const u16* __restrict__ Bhg,
                                                   const u16* __restrict__ Blg,
                                                   float* __restrict__ C, float scale) {
  __shared__ u16 LAh[128][64], LAl[128][64], LBh[128][64], LBl[128][64];
  const int tid = threadIdx.x;
  const int bm = blockIdx.x * 128, bn = blockIdx.y * 128;
  const int w = tid >> 6, l = tid & 63;
  const int wr = (w >> 1) * 64, wc = (w & 1) * 64;
  const int srow = tid >> 3, scol = (tid & 7) * 8;   // staging: 32 rows/round, 8x8 bf16 cols
  f32x4 acc[4][4];
#pragma unroll
  for (int i = 0; i < 4; ++i)
#pragma unroll
    for (int j = 0; j < 4; ++j) { acc[i][j][0] = 0.f; acc[i][j][1] = 0.f; acc[i][j][2] = 0.f; acc[i][j][3] = 0.f; }

  for (int c = 0; c < 4; ++c) {
    const int k0 = c * 64;
    uint4 ah[4], al[4], bh[4], bl[4];
#pragma unroll
    for (int ii = 0; ii < 4; ++ii) {
      int r = srow + ii * 32;
      ah[ii] = *(const uint4*)(Ahg + (size_t)(bm + r) * D_ + k0 + scol);
      al[ii] = *(const uint4*)(Alg + (size_t)(bm + r) * D_ + k0 + scol);
      bh[ii] = *(const uint4*)(Bhg + (size_t)(bn + r) * D_ + k0 + scol);
      bl[ii] = *(const uint4*)(Blg + (size_t)(bn + r) * D_ + k0 + scol);
    }
    __syncthreads();
#pragma unroll
    for (int ii = 0; ii < 4; ++ii) {
      int r = srow + ii * 32;
      int off = r * 128 + ((scol * 2) ^ ((r & 7) << 4));
      *(uint4*)((char*)LAh + off) = ah[ii];
      *(uint4*)((char*)LAl + off) = al[ii];
      *(uint4*)((char*)LBh + off) = bh[ii];
      *(uint4*)((char*)LBl + off) = bl[ii];
    }
    __syncthreads();
#pragma unroll
    for (int kk = 0; kk < 2; ++kk) {
      const int kb = kk * 64 + ((l >> 4) << 4);   // byte offset of this lane's 8 bf16
      bf16x8 fbh[4], fbl[4];
#pragma unroll
      for (int j = 0; j < 4; ++j) {
        int rb = wc + j * 16 + (l & 15);
        int ob = rb * 128 + (kb ^ ((rb & 7) << 4));
        fbh[j] = *(const bf16x8*)((const char*)LBh + ob);
        fbl[j] = *(const bf16x8*)((const char*)LBl + ob);
      }
#pragma unroll
      for (int i = 0; i < 4; ++i) {
        int ra = wr + i * 16 + (l & 15);
        int oa = ra * 128 + (kb ^ ((ra & 7) << 4));
        bf16x8 fah = *(const bf16x8*)((const char*)LAh + oa);
        bf16x8 fal = *(const bf16x8*)((const char*)LAl + oa);
#pragma unroll
        for (int j = 0; j < 4; ++j) {
          acc[i][j] = __builtin_amdgcn_mfma_f32_16x16x32_bf16(fah, fbh[j], acc[i][j], 0, 0, 0);
          acc[i][j] = __builtin_amdgcn_mfma_f32_16x16x32_bf16(fah, fbl[j], acc[i][j], 0, 0, 0);
          acc[i][j] = __builtin_amdgcn_mfma_f32_16x16x32_bf16(fal, fbh[j], acc[i][j], 0, 0, 0);
        }
      }
    }
  }
  const int cr = (l >> 4) * 4, cc = l & 15;
#pragma unroll
  for (int i = 0; i < 4; ++i)
#pragma unroll
    for (int r = 0; r < 4; ++r) {
      size_t base = (size_t)(bm + wr + i * 16 + cr + r) * N_ + bn + wc + cc;
#pragma unroll
      for (int j = 0; j < 4; ++j) C[base + j * 16] = acc[i][j][r] * scale;
    }
}

// Zpart[kz] += (w_k/rowZ[m]) * exp(S-rowmax) @ X ; A staged from S with exp+split,
// B from pre-transposed XhT/XlT [256][4096]. grid (32, 2, SPLITK).
__global__ __launch_bounds__(256) void zkern_mfma(const float* __restrict__ S,
                                                  const float* __restrict__ rowmax,
                                                  const float* __restrict__ rowZ,
                                                  const u16* __restrict__ BhT,
                                                  const u16* __restrict__ BlT,
                                                  float* __restrict__ Zpart,
                                                  const float* __restrict__ scal,
                                                  int kidx, int kchunk) {
  __shared__ u16 LAh[128][64], LAl[128][64], LBh[128][64], LBl[128][64];
  const int tid = threadIdx.x;
  const int bm = blockIdx.x * 128, bn = blockIdx.y * 128;
  const int kz = blockIdx.z;
  const int w = tid >> 6, l = tid & 63;
  const int wr = (w >> 1) * 64, wc = (w & 1) * 64;
  const int arow = tid >> 4, acol = (tid & 15) * 4;  // S staging: 16 rows/round, 16x4 cols
  const int brow = tid >> 3, bcol = (tid & 7) * 8;   // BT staging
  f32x4 acc[4][4];
#pragma unroll
  for (int i = 0; i < 4; ++i)
#pragma unroll
    for (int j = 0; j < 4; ++j) { acc[i][j][0] = 0.f; acc[i][j][1] = 0.f; acc[i][j][2] = 0.f; acc[i][j][3] = 0.f; }

  const int nchunk = kchunk >> 6;
  for (int c = 0; c < nchunk; ++c) {
    const int k0 = kz * kchunk + c * 64;
    uint2 eh[8], el[8];
#pragma unroll
    for (int ii = 0; ii < 8; ++ii) {
      int r = arow + ii * 16;
      float rm = rowmax[bm + r];
      float4 s = *(const float4*)(S + (size_t)(bm + r) * N_ + k0 + acol);
      float e0 = expf(s.x - rm), e1 = expf(s.y - rm), e2 = expf(s.z - rm), e3 = expf(s.w - rm);
      u16 h0 = bf16_rne(e0), h1 = bf16_rne(e1), h2 = bf16_rne(e2), h3 = bf16_rne(e3);
      u16 l0 = bf16_rne(e0 - __uint_as_float((u32)h0 << 16));
      u16 l1 = bf16_rne(e1 - __uint_as_float((u32)h1 << 16));
      u16 l2 = bf16_rne(e2 - __uint_as_float((u32)h2 << 16));
      u16 l3 = bf16_rne(e3 - __uint_as_float((u32)h3 << 16));
      eh[ii] = make_uint2((u32)h0 | ((u32)h1 << 16), (u32)h2 | ((u32)h3 << 16));
      el[ii] = make_uint2((u32)l0 | ((u32)l1 << 16), (u32)l2 | ((u32)l3 << 16));
    }
    uint4 bh[4], bl[4];
#pragma unroll
    for (int ii = 0; ii < 4; ++ii) {
      int r = brow + ii * 32;
      bh[ii] = *(const uint4*)(BhT + (size_t)(bn + r) * N_ + k0 + bcol);
      bl[ii] = *(const uint4*)(BlT + (size_t)(bn + r) * N_ + k0 + bcol);
    }
    __syncthreads();
#pragma unroll
    for (int ii = 0; ii < 8; ++ii) {
      int r = arow + ii * 16;
      int off = r * 128 + (((tid & 15) * 8) ^ ((r & 7) << 4));
      *(uint2*)((char*)LAh + off) = eh[ii];
      *(uint2*)((char*)LAl + off) = el[ii];
    }
#pragma unroll
    for (int ii = 0; ii < 4; ++ii) {
      int r = brow + ii * 32;
      int off = r * 128 + ((bcol * 2) ^ ((r & 7) << 4));
      *(uint4*)((char*)LBh + off) = bh[ii];
      *(uint4*)((char*)LBl + off) = bl[ii];
    }
    __syncthreads();
#pragma unroll
    for (int kk = 0; kk < 2; ++kk) {
      const int kb = kk * 64 + ((l >> 4) << 4);
      bf16x8 fbh[4], fbl[4];
#pragma unroll
      for (int j = 0; j < 4; ++j) {
        int rb = wc + j * 16 + (l & 15);
        int ob = rb * 128 + (kb ^ ((rb & 7) << 4));
        fbh[j] = *(const bf16x8*)((const char*)LBh + ob);
        fbl[j] = *(const bf16x8*)((const char*)LBl + ob);
      }
#pragma unroll
      for (int i = 0; i < 4; ++i) {
        int ra = wr + i * 16 + (l & 15);
        int oa = ra * 128 + (kb ^ ((ra & 7) << 4));
        bf16x8 fah = *(const bf16x8*)((const char*)LAh + oa);
        bf16x8 fal = *(const bf16x8*)((const char*)LAl + oa);
#pragma unroll
        for (int j = 0; j < 4; ++j) {
          acc[i][j] = __builtin_amdgcn_mfma_f32_16x16x32_bf16(fah, fbh[j], acc[i][j], 0, 0, 0);
          acc[i][j] = __builtin_amdgcn_mfma_f32_16x16x32_bf16(fah, fbl[j], acc[i][j], 0, 0, 0);
          acc[i][j] = __builtin_amdgcn_mfma_f32_16x16x32_bf16(fal, fbh[j], acc[i][j], 0, 0, 0);
        }
      }
    }
  }
  const float wk = scal[kidx];
  float* Zp = Zpart + (size_t)kz * N_ * D_;
  const int cr = (l >> 4) * 4, cc = l & 15;
#pragma unroll
  for (int i = 0; i < 4; ++i)
#pragma unroll
    for (int r = 0; r < 4; ++r) {
      int row = bm + wr + i * 16 + cr + r;
      float sc = wk / rowZ[row];
      size_t base = (size_t)row * D_ + bn + wc + cc;
#pragma unroll
      for (int j = 0; j < 4; ++j) Zp[base + j * 16] += sc * acc[i][j][r];
    }
}

// ======================= per-row stats + top-16 (register-resident) ============
__global__ __launch_bounds__(256) void rowstats_topk(const float* __restrict__ S,
                                                     float* __restrict__ rowmax,
                                                     float* __restrict__ rowZ,
                                                     float* __restrict__ tkv,
                                                     int* __restrict__ tki) {
  const int row = blockIdx.x, tid = threadIdx.x;
  const int wid = tid >> 6, lane = tid & 63;
  __shared__ float rv[4];
  __shared__ int ri[4];
  __shared__ float stk[TK_];
  __shared__ int itk[TK_];
  __shared__ float tv16[TK_];
  __shared__ float mzs[3];
  __shared__ int sgi;
  const float4* Sp = (const float4*)(S + (size_t)row * N_);
  float r[16];
  float lmax = -3.4e38f;
#pragma unroll
  for (int it = 0; it < 4; ++it) {
    float4 v = Sp[tid + it * 256];
    r[it * 4 + 0] = v.x; r[it * 4 + 1] = v.y; r[it * 4 + 2] = v.z; r[it * 4 + 3] = v.w;
    lmax = fmaxf(lmax, fmaxf(fmaxf(v.x, v.y), fmaxf(v.z, v.w)));
  }
#pragma unroll
  for (int off = 32; off; off >>= 1) lmax = fmaxf(lmax, __shfl_xor(lmax, off));
  if (lane == 0) rv[wid] = lmax;
  __syncthreads();
  if (tid == 0) mzs[0] = fmaxf(fmaxf(rv[0], rv[1]), fmaxf(rv[2], rv[3]));
  __syncthreads();
  const float M = mzs[0];
  float ls = 0.f;
#pragma unroll
  for (int j = 0; j < 16; ++j) ls += expf(r[j] - M);
#pragma unroll
  for (int off = 32; off; off >>= 1) ls += __shfl_xor(ls, off);
  if (lane == 0) rv[wid] = ls;
  __syncthreads();
  if (tid == 0) {
    float z = rv[0] + rv[1] + rv[2] + rv[3];
    mzs[1] = z; rowmax[row] = M; rowZ[row] = z;
  }
  __syncthreads();
  const float Z = mzs[1];
  // element gi = 4*tid + 1024*(j>>2) + (j&3): ascending j => ascending gi
  unsigned mask = 0;
  for (int t = 0; t < TK_; ++t) {
    float bmv = -3.4e38f; int bj = -1;
#pragma unroll
    for (int j = 0; j < 16; ++j) {
      float v = (mask & (1u << j)) ? -3.4e38f : r[j];
      if (v > bmv) { bmv = v; bj = j; }
    }
    int gi = bj < 0 ? 0x7fffffff : 4 * tid + ((bj >> 2) << 10) + (bj & 3);
#pragma unroll
    for (int off = 32; off; off >>= 1) {
      float ov = __shfl_xor(bmv, off);
      int og = __shfl_xor(gi, off);
      if (ov > bmv || (ov == bmv && og < gi)) { bmv = ov; gi = og; }
    }
    if (lane == 0) { rv[wid] = bmv; ri[wid] = gi; }
    __syncthreads();
    if (tid == 0) {
      float b0 = rv[0]; int g0 = ri[0];
      for (int q = 1; q < 4; ++q)
        if (rv[q] > b0 || (rv[q] == b0 && ri[q] < g0)) { b0 = rv[q]; g0 = ri[q]; }
      stk[t] = b0; itk[t] = g0; sgi = g0;
    }
    __syncthreads();
    int g = sgi;
    if (((g >> 2) & 255) == tid) mask |= 1u << (((g >> 10) << 2) | (g & 3));
  }
  if (tid < TK_) tv16[tid] = expf(stk[tid] - M) / Z;
  __syncthreads();
  if (tid == 0) { float s = 0.f; for (int q = 0; q < TK_; ++q) s += tv16[q]; mzs[2] = s + 1e-9f; }
  __syncthreads();
  if (tid < TK_) {
    tkv[(size_t)row * TK_ + tid] = tv16[tid] / mzs[2];
    tki[(size_t)row * TK_ + tid] = itk[tid];
  }
}

// ======================= hypergraph build =======================
__global__ void edge_scan(const float* __restrict__ tkv, const int* __restrict__ tki,
                          float* __restrict__ DvAcc, int* __restrict__ cnt,
                          float* __restrict__ invDe) {
  int e = blockIdx.x * 256 + threadIdx.x;
  float s = 0.f;
#pragma unroll
  for (int q = 0; q < TK_; ++q) s += tkv[(size_t)e * TK_ + q];
  invDe[e] = 1.0f / (s + 1e-9f);
#pragma unroll
  for (int q = 0; q < TK_; ++q) {
    int m = tki[(size_t)e * TK_ + q];
    atomicAdd(&DvAcc[m], tkv[(size_t)e * TK_ + q]);
    atomicAdd(&cnt[m], 1);
  }
}

__global__ __launch_bounds__(1024) void scan_offsets(const int* __restrict__ cnt,
                                                     int* __restrict__ off,
                                                     int* __restrict__ cur) {
  __shared__ int part[1024];
  const int t = threadIdx.x;
  const int b = t * 4;
  int c0 = cnt[b], c1 = cnt[b + 1], c2 = cnt[b + 2], c3 = cnt[b + 3];
  part[t] = c0 + c1 + c2 + c3;
  __syncthreads();
  for (int o = 1; o < 1024; o <<= 1) {
    int v = part[t] + ((t >= o) ? part[t - o] : 0);
    __syncthreads();
    part[t] = v;
    __syncthreads();
  }
  int ex = (t == 0) ? 0 : part[t - 1];
  off[b] = ex; off[b + 1] = ex + c0; off[b + 2] = ex + c0 + c1; off[b + 3] = ex + c0 + c1 + c2;
  cur[b] = off[b]; cur[b + 1] = off[b + 1]; cur[b + 2] = off[b + 2]; cur[b + 3] = off[b + 3];
  if (t == 1023) off[N_] = part[1023];
}

__global__ void edge_fill(const float* __restrict__ tkv, const int* __restrict__ tki,
                          int* __restrict__ cur, int* __restrict__ ince,
                          float* __restrict__ incv) {
  int e = blockIdx.x * 256 + threadIdx.x;
#pragma unroll
  for (int q = 0; q < TK_; ++q) {
    int m = tki[(size_t)e * TK_ + q];
    int pos = atomicAdd(&cur[m], 1);
    ince[pos] = e;
    incv[pos] = tkv[(size_t)e * TK_ + q];
  }
}

// ======================= power iteration (multi-kernel, unnormalized) ==========
__global__ void pi_init(const float* __restrict__ v0, const float* __restrict__ Dvis,
                        float* __restrict__ v, float* __restrict__ u) {
  int i = blockIdx.x * 256 + threadIdx.x;
  float x = v0[i];
  v[i] = x; u[i] = Dvis[i] * x;
}

__global__ void pi_ye(const float* __restrict__ u, const float* __restrict__ tkv,
                      const int* __restrict__ tki, const float* __restrict__ invDe,
                      float* __restrict__ ye) {
  int e = blockIdx.x * 256 + threadIdx.x;
  const float* tv = tkv + (size_t)e * TK_;
  const int* ti = tki + (size_t)e * TK_;
  float a = 0.f;
#pragma unroll
  for (int q = 0; q < TK_; ++q) a += tv[q] * u[ti[q]];
  ye[e] = a * invDe[e];
}

__global__ void pi_step(const float* __restrict__ v, const float* __restrict__ ye,
                        const int* __restrict__ off, const int* __restrict__ ince,
                        const float* __restrict__ incv, const float* __restrict__ Dvis,
                        float* __restrict__ vn, float* __restrict__ un) {
  int m = blockIdx.x * 256 + threadIdx.x;
  float z = 0.f;
  int j0 = off[m], j1 = off[m + 1];
  for (int j = j0; j < j1; ++j) z += incv[j] * ye[ince[j]];
  float wv = v[m] - Dvis[m] * z;
  vn[m] = wv; un[m] = Dvis[m] * wv;
}

__global__ __launch_bounds__(256) void pi_final(const float* __restrict__ v,
                                                const float* __restrict__ ye,
                                                const int* __restrict__ off,
                                                const int* __restrict__ ince,
                                                const float* __restrict__ incv,
                                                const float* __restrict__ Dvis,
                                                float* __restrict__ partial) {
  __shared__ float r1[256], r2[256];
  int m = blockIdx.x * 256 + threadIdx.x;
  float z = 0.f;
  int j0 = off[m], j1 = off[m + 1];
  for (int j = j0; j < j1; ++j) z += incv[j] * ye[ince[j]];
  float wv = v[m] - Dvis[m] * z;
  r1[threadIdx.x] = v[m] * wv;
  r2[threadIdx.x] = v[m] * v[m];
  __syncthreads();
  for (int s = 128; s; s >>= 1) {
    if (threadIdx.x < s) { r1[threadIdx.x] += r1[threadIdx.x + s]; r2[threadIdx.x] += r2[threadIdx.x + s]; }
    __syncthreads();
  }
  if (threadIdx.x == 0) { partial[blockIdx.x * 2] = r1[0]; partial[blockIdx.x * 2 + 1] = r2[0]; }
}

__global__ void pi_lam(const float* __restrict__ partial, float* __restrict__ scal) {
  if (threadIdx.x == 0) {
    float s1 = 0.f, s2 = 0.f;
    for (int b = 0; b < N_ / 256; ++b) { s1 += partial[2 * b]; s2 += partial[2 * b + 1]; }
    scal[5] = fmaxf(s1 / s2, 1e-3f);
  }
}

// ======================= Chebyshev sparse applies =======================
__global__ __launch_bounds__(256) void ye_mat(const float* __restrict__ U,
                                              const float* __restrict__ tkv,
                                              const int* __restrict__ tki,
                                              const float* __restrict__ invDe,
                                              float* __restrict__ Ye) {
  const int e = blockIdx.x, d = threadIdx.x;
  __shared__ float sv[TK_];
  __shared__ int si[TK_];
  if (d < TK_) { sv[d] = tkv[(size_t)e * TK_ + d]; si[d] = tki[(size_t)e * TK_ + d]; }
  __syncthreads();
  float a = 0.f;
#pragma unroll
  for (int q = 0; q < TK_; ++q) a += sv[q] * U[(size_t)si[q] * D_ + d];
  Ye[(size_t)e * D_ + d] = a * invDe[e];
}

__global__ __launch_bounds__(256) void bgather_combine(const float* __restrict__ Ye,
                                                       const int* __restrict__ off,
                                                       const int* __restrict__ ince,
                                                       const float* __restrict__ incv,
                                                       const float* __restrict__ Dvis,
                                                       const float* __restrict__ Mx,
                                                       const float* __restrict__ G,
                                                       const float* __restrict__ scal,
                                                       float* __restrict__ out, int mode) {
  const int m = blockIdx.x, d = threadIdx.x;
  const int j0 = off[m], j1 = off[m + 1];
  float z = 0.f;
  for (int j = j0; j < j1; ++j) z += incv[j] * Ye[(size_t)ince[j] * D_ + d];
  const float lam = scal[5];
  const float c = 2.0f / lam;
  const size_t idx = (size_t)m * D_ + d;
  const float zz = Dvis[m] * z;
  float r;
  if (mode == 1) r = (c - 1.0f) * Mx[idx] - c * zz;
  else           r = (2.0f * c - 2.0f) * Mx[idx] - 2.0f * c * zz - G[idx];
  out[idx] = r;
}

__global__ void mix_kernel(const float* __restrict__ X, const float* __restrict__ T1,
                           const float* __restrict__ T2, const float* __restrict__ theta,
                           const float* __restrict__ Zpart, int splitk,
                           const float* __restrict__ scal, float* __restrict__ Zmix) {
  const int i = blockIdx.x * 256 + threadIdx.x;
  const int d = i & (D_ - 1);
  float cheb = X[i] * theta[d] + T1[i] * theta[D_ + d] + T2[i] * theta[2 * D_ + d];
  float zs = cheb > 0.f ? cheb : expm1f(cheb);
  float zk = 0.f;
  for (int s = 0; s < splitk; ++s) zk += Zpart[(size_t)s * N_ * D_ + i];
  const float rho = scal[4];
  Zmix[i] = rho * zs + (1.0f - rho) * zk;
}

// ============================= launcher =============================

extern "C" void kernel_launch(void* const* d_in, const int* in_sizes, int n_in,
                              void* d_out, int out_size, void* d_ws, size_t ws_size,
                              hipStream_t stream) {
  const float* X       = (const float*)d_in[0];
  const float* L_k     = (const float*)d_in[1];
  const float* alpha   = (const float*)d_in[2];
  const float* theta   = (const float*)d_in[3];
  const float* rho_raw = (const float*)d_in[4];
  const float* proj_w  = (const float*)d_in[5];
  const float* proj_b  = (const float*)d_in[6];
  const float* v0      = (const float*)d_in[7];
  float* out = (float*)d_out;

  char* w = (char*)d_ws;
  size_t o = 0;
  auto alloc = [&](size_t bytes) -> char* {
    char* p = w + o; o += (bytes + 255) & ~(size_t)255; return p;
  };
  float* XL    = (float*)alloc((size_t)N_ * D_ * 4);
  float* S     = (float*)alloc((size_t)N_ * N_ * 4);
  u16*   Xh    = (u16*)  alloc((size_t)N_ * D_ * 2);
  u16*   Xl    = (u16*)  alloc((size_t)N_ * D_ * 2);
  u16*   XhT   = (u16*)  alloc((size_t)D_ * N_ * 2);
  u16*   XlT   = (u16*)  alloc((size_t)D_ * N_ * 2);
  u16*   XLh   = (u16*)  alloc((size_t)N_ * D_ * 2);
  u16*   XLl   = (u16*)  alloc((size_t)N_ * D_ * 2);
  float* rowmax= (float*)alloc(N_ * 4);
  float* rowZ  = (float*)alloc(N_ * 4);
  float* tkv   = (float*)alloc((size_t)NENT_ * 4);
  int*   tki   = (int*)  alloc((size_t)NENT_ * 4);
  float* invDe = (float*)alloc(E_ * 4);
  float* DvAcc = (float*)alloc(N_ * 4);
  float* Dvis  = (float*)alloc(N_ * 4);
  int*   cnt   = (int*)  alloc(N_ * 4);
  int*   off   = (int*)  alloc((N_ + 1) * 4);
  int*   cur   = (int*)  alloc(N_ * 4);
  int*   ince  = (int*)  alloc((size_t)NENT_ * 4);
  float* incv  = (float*)alloc((size_t)NENT_ * 4);
  float* va    = (float*)alloc(N_ * 4);
  float* ua    = (float*)alloc(N_ * 4);
  float* vbuf  = (float*)alloc(N_ * 4);
  float* ubuf  = (float*)alloc(N_ * 4);
  float* yev   = (float*)alloc(E_ * 4);
  float* part  = (float*)alloc((N_ / 256) * 2 * 4);
  float* scal  = (float*)alloc(256);
  int SPLITK = 8;
  while (SPLITK > 1 && o + (size_t)SPLITK * N_ * D_ * 4 > ws_size) SPLITK >>= 1;
  float* Zpart = (float*)alloc((size_t)SPLITK * N_ * D_ * 4);
  const int kchunk = N_ / SPLITK;
  // phase-2 temporaries alias into S (dead after the k-loop)
  float* U    = S;
  float* Ye   = S + (size_t)N_ * D_;
  float* T1   = Ye + (size_t)E_ * D_;
  float* T2   = T1 + (size_t)N_ * D_;
  float* Zmix = T2 + (size_t)N_ * D_;

  scalars_kernel<<<1, 64, 0, stream>>>(alpha, rho_raw, scal);
  hipMemsetAsync(Zpart, 0, (size_t)SPLITK * N_ * D_ * 4, stream);
  hipMemsetAsync(DvAcc, 0, N_ * 4, stream);
  hipMemsetAsync(cnt, 0, N_ * 4, stream);

  // one-time bf16 splits of X (row-major and transposed)
  cvt_split4<<<(N_ * D_ / 4) / 256, 256, 0, stream>>>(X, Xh, Xl);
  transpose_split<<<dim3(D_ / 32, N_ / 32), 256, 0, stream>>>(X, XhT, XlT);

  for (int k = 0; k < K_; ++k) {
    gemm_nn64<<<dim3(N_ / 64, D_ / 64), 256, 0, stream>>>(
        X, L_k + (size_t)k * D_ * D_, XL, D_, D_, D_, D_);
    cvt_split4<<<(N_ * D_ / 4) / 256, 256, 0, stream>>>(XL, XLh, XLl);
    scores_mfma<<<dim3(N_ / 128, N_ / 128), 256, 0, stream>>>(
        XLh, XLl, Xh, Xl, S, 1.0f / 16.0f);  // 1/sqrt(256)
    rowstats_topk<<<N_, 256, 0, stream>>>(
        S, rowmax, rowZ, tkv + (size_t)k * N_ * TK_, tki + (size_t)k * N_ * TK_);
    zkern_mfma<<<dim3(N_ / 128, D_ / 128, SPLITK), 256, 0, stream>>>(
        S, rowmax, rowZ, XhT, XlT, Zpart, scal, k, kchunk);
  }

  edge_scan<<<E_ / 256, 256, 0, stream>>>(tkv, tki, DvAcc, cnt, invDe);
  dvis_kernel<<<N_ / 256, 256, 0, stream>>>(DvAcc, Dvis);
  scan_offsets<<<1, 1024, 0, stream>>>(cnt, off, cur);
  edge_fill<<<E_ / 256, 256, 0, stream>>>(tkv, tki, cur, ince, incv);

  pi_init<<<N_ / 256, 256, 0, stream>>>(v0, Dvis, va, ua);
  float* vc = va; float* uc = ua; float* vn = vbuf; float* un = ubuf;
  for (int it = 0; it < 5; ++it) {
    pi_ye<<<E_ / 256, 256, 0, stream>>>(uc, tkv, tki, invDe, yev);
    pi_step<<<N_ / 256, 256, 0, stream>>>(vc, yev, off, ince, incv, Dvis, vn, un);
    float* tv = vc; vc = vn; vn = tv;
    float* tu = uc; uc = un; un = tu;
  }
  pi_ye<<<E_ / 256, 256, 0, stream>>>(uc, tkv, tki, invDe, yev);
  pi_final<<<N_ / 256, 256, 0, stream>>>(vc, yev, off, ince, incv, Dvis, part);
  pi_lam<<<1, 64, 0, stream>>>(part, scal);

  // T1 = Lt @ X
  ew_scale<<<N_ * D_ / 256, 256, 0, stream>>>(X, Dvis, U);
  ye_mat<<<E_, 256, 0, stream>>>(U, tkv, tki, invDe, Ye);
  bgather_combine<<<N_, 256, 0, stream>>>(Ye, off, ince, incv, Dvis, X, X, scal, T1, 1);
  // T2 = 2*Lt @ T1 - X
  ew_scale<<<N_ * D_ / 256, 256, 0, stream>>>(T1, Dvis, U);
  ye_mat<<<E_, 256, 0, stream>>>(U, tkv, tki, invDe, Ye);
  bgather_combine<<<N_, 256, 0, stream>>>(Ye, off, ince, incv, Dvis, T1, X, scal, T2, 2);

  mix_kernel<<<N_ * D_ / 256, 256, 0, stream>>>(X, T1, T2, theta, Zpart, SPLITK, scal, Zmix);

  gemm_nt64_bias<<<dim3(N_ / 64, D_ / 64), 256, 0, stream>>>(
      Zmix, proj_w, proj_b, out, D_, D_, D_, D_);
}

// Round 4
// 1649.974 us; speedup vs baseline: 3.3594x; 1.0697x over previous
//
#include <hip/hip_runtime.h>
#include <math.h>

#define N_ 4096
#define D_ 256
#define K_ 4
#define TK_ 16
#define E_ (K_ * N_)          // 16384 hyperedges
#define NENT_ (E_ * TK_)      // 262144 incidence entries

typedef unsigned short u16;
typedef unsigned int u32;
typedef __attribute__((ext_vector_type(8))) short bf16x8;
typedef __attribute__((ext_vector_type(4))) float f32x4;

__device__ __forceinline__ u16 bf16_rne(float x) {
  u32 u = __float_as_uint(x);
  u32 r = u + 0x7FFFu + ((u >> 16) & 1u);
  return (u16)(r >> 16);
}

// ============================= small kernels =============================

__global__ void scalars_kernel(const float* __restrict__ alpha,
                               const float* __restrict__ rho_raw,
                               float* __restrict__ scal) {
  if (threadIdx.x == 0) {
    float m = alpha[0];
    for (int k = 1; k < K_; ++k) m = fmaxf(m, alpha[k]);
    float e[K_]; float s = 0.f;
    for (int k = 0; k < K_; ++k) { e[k] = expf(alpha[k] - m); s += e[k]; }
    for (int k = 0; k < K_; ++k) scal[k] = e[k] / s;   // w_k
    scal[4] = 1.0f / (1.0f + expf(-rho_raw[0]));       // rho
  }
}

__global__ void dvis_kernel(const float* __restrict__ DvAcc, float* __restrict__ Dvis) {
  int i = blockIdx.x * 256 + threadIdx.x;
  Dvis[i] = 1.0f / sqrtf(DvAcc[i] + 1e-9f);
}

__global__ void ew_scale(const float* __restrict__ M, const float* __restrict__ Dvis,
                         float* __restrict__ U) {
  int i = blockIdx.x * 256 + threadIdx.x;
  U[i] = Dvis[i >> 8] * M[i];
}

// fp32 -> (hi, lo) bf16 split, 4 elems/thread (used for X row-major)
__global__ void cvt_split4(const float* __restrict__ in, u16* __restrict__ hi,
                           u16* __restrict__ lo) {
  int i = (blockIdx.x * 256 + threadIdx.x) * 4;
  float4 v = *(const float4*)(in + i);
  u16 h0 = bf16_rne(v.x), h1 = bf16_rne(v.y), h2 = bf16_rne(v.z), h3 = bf16_rne(v.w);
  float f0 = __uint_as_float((u32)h0 << 16), f1 = __uint_as_float((u32)h1 << 16);
  float f2 = __uint_as_float((u32)h2 << 16), f3 = __uint_as_float((u32)h3 << 16);
  u16 l0 = bf16_rne(v.x - f0), l1 = bf16_rne(v.y - f1);
  u16 l2 = bf16_rne(v.z - f2), l3 = bf16_rne(v.w - f3);
  *(uint2*)(hi + i) = make_uint2((u32)h0 | ((u32)h1 << 16), (u32)h2 | ((u32)h3 << 16));
  *(uint2*)(lo + i) = make_uint2((u32)l0 | ((u32)l1 << 16), (u32)l2 | ((u32)l3 << 16));
}

// X [N][D] fp32 -> XhT/XlT [D][N] bf16 (transposed split). grid (D/32, N/32), 256 thr.
__global__ __launch_bounds__(256) void transpose_split(const float* __restrict__ X,
                                                       u16* __restrict__ ht,
                                                       u16* __restrict__ lt) {
  __shared__ float tile[32][33];
  const int tx = threadIdx.x & 31, ty = threadIdx.x >> 5;  // 32x8
  const int d0 = blockIdx.x * 32, n0 = blockIdx.y * 32;
#pragma unroll
  for (int q = 0; q < 4; ++q)
    tile[ty + q * 8][tx] = X[(size_t)(n0 + ty + q * 8) * D_ + d0 + tx];
  __syncthreads();
#pragma unroll
  for (int q = 0; q < 4; ++q) {
    int dd = ty + q * 8;
    float v = tile[tx][dd];               // = X[n0+tx][d0+dd]
    u16 h = bf16_rne(v);
    float hf = __uint_as_float((u32)h << 16);
    u16 l = bf16_rne(v - hf);
    ht[(size_t)(d0 + dd) * N_ + n0 + tx] = h;
    lt[(size_t)(d0 + dd) * N_ + n0 + tx] = l;
  }
}

// ============================= 64-tile fp32 GEMMs =============================
// XL = X @ L_k, epilogue writes bf16 hi/lo split directly. grid=(N/64, D/64).
__global__ __launch_bounds__(256) void gemm_nn64_split(const float* __restrict__ A,
                                                       const float* __restrict__ B,
                                                       u16* __restrict__ Ch,
                                                       u16* __restrict__ Cl,
                                                       int Kdim, int lda, int ldb, int ldc) {
  __shared__ float As[16][68];
  __shared__ float Bs[16][68];
  const int tid = threadIdx.x;
  const int bm = blockIdx.x * 64, bn = blockIdx.y * 64;
  const int lrA = tid >> 2, lcA = (tid & 3) * 4;
  const int rrB = tid >> 4, ccB = (tid & 15) * 4;
  const int tx = tid & 15, ty = tid >> 4;
  const float* Ap = A + (size_t)(bm + lrA) * lda + lcA;
  const float* Bp = B + (size_t)rrB * ldb + bn + ccB;
  float acc[4][4] = {};
  for (int k0 = 0; k0 < Kdim; k0 += 16) {
    float4 av = *(const float4*)(Ap + k0);
    float4 bv = *(const float4*)(Bp + (size_t)k0 * ldb);
    __syncthreads();
    As[lcA + 0][lrA] = av.x; As[lcA + 1][lrA] = av.y;
    As[lcA + 2][lrA] = av.z; As[lcA + 3][lrA] = av.w;
    *(float4*)&Bs[rrB][ccB] = bv;
    __syncthreads();
#pragma unroll
    for (int kk = 0; kk < 16; ++kk) {
      float a[4], b[4];
      *(float4*)a = *(const float4*)&As[kk][ty * 4];
      *(float4*)b = *(const float4*)&Bs[kk][tx * 4];
#pragma unroll
      for (int i = 0; i < 4; ++i)
#pragma unroll
        for (int j = 0; j < 4; ++j) acc[i][j] += a[i] * b[j];
    }
  }
#pragma unroll
  for (int i = 0; i < 4; ++i) {
    int row = bm + ty * 4 + i;
    u16 h[4], lo[4];
#pragma unroll
    for (int j = 0; j < 4; ++j) {
      h[j] = bf16_rne(acc[i][j]);
      lo[j] = bf16_rne(acc[i][j] - __uint_as_float((u32)h[j] << 16));
    }
    size_t base = (size_t)row * ldc + bn + tx * 4;
    *(uint2*)(Ch + base) = make_uint2((u32)h[0] | ((u32)h[1] << 16), (u32)h[2] | ((u32)h[3] << 16));
    *(uint2*)(Cl + base) = make_uint2((u32)lo[0] | ((u32)lo[1] << 16), (u32)lo[2] | ((u32)lo[3] << 16));
  }
}

// C(MxN) = A(MxK) @ B(NxK)^T + bias, row-major. grid=(M/64, N/64).
__global__ __launch_bounds__(256) void gemm_nt64_bias(const float* __restrict__ A,
                                                      const float* __restrict__ B,
                                                      const float* __restrict__ bias,
                                                      float* __restrict__ C,
                                                      int Kdim, int lda, int ldb, int ldc) {
  __shared__ float As[16][68];
  __shared__ float Bs[16][68];
  const int tid = threadIdx.x;
  const int bm = blockIdx.x * 64, bn = blockIdx.y * 64;
  const int lr = tid >> 2, lc = (tid & 3) * 4;
  const int tx = tid & 15, ty = tid >> 4;
  const float* Ap = A + (size_t)(bm + lr) * lda + lc;
  const float* Bp = B + (size_t)(bn + lr) * ldb + lc;
  float acc[4][4] = {};
  for (int k0 = 0; k0 < Kdim; k0 += 16) {
    float4 av = *(const float4*)(Ap + k0);
    float4 bv = *(const float4*)(Bp + k0);
    __syncthreads();
    As[lc + 0][lr] = av.x; As[lc + 1][lr] = av.y; As[lc + 2][lr] = av.z; As[lc + 3][lr] = av.w;
    Bs[lc + 0][lr] = bv.x; Bs[lc + 1][lr] = bv.y; Bs[lc + 2][lr] = bv.z; Bs[lc + 3][lr] = bv.w;
    __syncthreads();
#pragma unroll
    for (int kk = 0; kk < 16; ++kk) {
      float a[4], b[4];
      *(float4*)a = *(const float4*)&As[kk][ty * 4];
      *(float4*)b = *(const float4*)&Bs[kk][tx * 4];
#pragma unroll
      for (int i = 0; i < 4; ++i)
#pragma unroll
        for (int j = 0; j < 4; ++j) acc[i][j] += a[i] * b[j];
    }
  }
#pragma unroll
  for (int i = 0; i < 4; ++i) {
    int row = bm + ty * 4 + i;
    float4 o;
    o.x = acc[i][0] + bias[bn + tx * 4 + 0];
    o.y = acc[i][1] + bias[bn + tx * 4 + 1];
    o.z = acc[i][2] + bias[bn + tx * 4 + 2];
    o.w = acc[i][3] + bias[bn + tx * 4 + 3];
    *(float4*)(C + (size_t)row * ldc + bn + tx * 4) = o;
  }
}

// ===================== MFMA bf16-split GEMMs (3-pass hi/lo) =====================
// LDS tiles [128 rows][64 bf16] = 16 KB each, XOR-swizzled: byte ^= (row&7)<<4.

// S(4096x4096) = (Ah+Al)(Bh+Bl)^T * scale; LDS-staged coalesced epilogue.
__global__ __launch_bounds__(256) void scores_mfma(const u16* __restrict__ Ahg,
                                                   const u16* __restrict__ Alg,
                                                   const u16* __restrict__ Bhg,
                                                   const u16* __restrict__ Blg,
                                                   float* __restrict__ C, float scale) {
  __shared__ char smem[65536];
  char* pAh = smem;
  char* pAl = smem + 16384;
  char* pBh = smem + 32768;
  char* pBl = smem + 49152;
  const int tid = threadIdx.x;
  const int bm = blockIdx.x * 128, bn = blockIdx.y * 128;
  const int w = tid >> 6, l = tid & 63;
  const int wr = (w >> 1) * 64, wc = (w & 1) * 64;
  const int srow = tid >> 3, scol = (tid & 7) * 8;
  f32x4 acc[4][4];
#pragma unroll
  for (int i = 0; i < 4; ++i)
#pragma unroll
    for (int j = 0; j < 4; ++j) { acc[i][j][0] = 0.f; acc[i][j][1] = 0.f; acc[i][j][2] = 0.f; acc[i][j][3] = 0.f; }

  for (int c = 0; c < 4; ++c) {
    const int k0 = c * 64;
    uint4 ah[4], al[4], bh[4], bl[4];
#pragma unroll
    for (int ii = 0; ii < 4; ++ii) {
      int r = srow + ii * 32;
      ah[ii] = *(const uint4*)(Ahg + (size_t)(bm + r) * D_ + k0 + scol);
      al[ii] = *(const uint4*)(Alg + (size_t)(bm + r) * D_ + k0 + scol);
      bh[ii] = *(const uint4*)(Bhg + (size_t)(bn + r) * D_ + k0 + scol);
      bl[ii] = *(const uint4*)(Blg + (size_t)(bn + r) * D_ + k0 + scol);
    }
    __syncthreads();
#pragma unroll
    for (int ii = 0; ii < 4; ++ii) {
      int r = srow + ii * 32;
      int off = r * 128 + ((scol * 2) ^ ((r & 7) << 4));
      *(uint4*)(pAh + off) = ah[ii];
      *(uint4*)(pAl + off) = al[ii];
      *(uint4*)(pBh + off) = bh[ii];
      *(uint4*)(pBl + off) = bl[ii];
    }
    __syncthreads();
#pragma unroll
    for (int kk = 0; kk < 2; ++kk) {
      const int kb = kk * 64 + ((l >> 4) << 4);
      bf16x8 fbh[4], fbl[4];
#pragma unroll
      for (int j = 0; j < 4; ++j) {
        int rb = wc + j * 16 + (l & 15);
        int ob = rb * 128 + (kb ^ ((rb & 7) << 4));
        fbh[j] = *(const bf16x8*)(pBh + ob);
        fbl[j] = *(const bf16x8*)(pBl + ob);
      }
#pragma unroll
      for (int i = 0; i < 4; ++i) {
        int ra = wr + i * 16 + (l & 15);
        int oa = ra * 128 + (kb ^ ((ra & 7) << 4));
        bf16x8 fah = *(const bf16x8*)(pAh + oa);
        bf16x8 fal = *(const bf16x8*)(pAl + oa);
#pragma unroll
        for (int j = 0; j < 4; ++j) {
          acc[i][j] = __builtin_amdgcn_mfma_f32_16x16x32_bf16(fah, fbh[j], acc[i][j], 0, 0, 0);
          acc[i][j] = __builtin_amdgcn_mfma_f32_16x16x32_bf16(fah, fbl[j], acc[i][j], 0, 0, 0);
          acc[i][j] = __builtin_amdgcn_mfma_f32_16x16x32_bf16(fal, fbh[j], acc[i][j], 0, 0, 0);
        }
      }
    }
  }
  // LDS-staged epilogue: swizzled scatter into 128x128 f32, coalesced read-out.
  __syncthreads();
  float* Cs = (float*)smem;
  const int cr = (l >> 4) * 4, cc = l & 15;
#pragma unroll
  for (int i = 0; i < 4; ++i)
#pragma unroll
    for (int r = 0; r < 4; ++r) {
      int rl = wr + i * 16 + cr + r;
      int sw = ((rl >> 2) & 3) << 4;
#pragma unroll
      for (int j = 0; j < 4; ++j) {
        int cl = wc + j * 16 + cc;
        Cs[rl * 128 + (cl ^ sw)] = acc[i][j][r] * scale;
      }
    }
  __syncthreads();
#pragma unroll
  for (int ii = 0; ii < 16; ++ii) {
    int rl = ii * 8 + (tid >> 5);
    int c4 = (tid & 31) * 4;
    float4 v = *(float4*)&Cs[rl * 128 + (c4 ^ (((rl >> 2) & 3) << 4))];
    *(float4*)(C + (size_t)(bm + rl) * N_ + bn + c4) = v;
  }
}

// Zpart[kz] += (w_k/rowZ[m]) * exp(S-rowmax) @ X ; A staged from S with exp+split,
// B from pre-transposed XhT/XlT [256][4096]. grid (32, 2, SPLITK).
__global__ __launch_bounds__(256) void zkern_mfma(const float* __restrict__ S,
                                                  const float* __restrict__ rowmax,
                                                  const float* __restrict__ rowZ,
                                                  const u16* __restrict__ BhT,
                                                  const u16* __restrict__ BlT,
                                                  float* __restrict__ Zpart,
                                                  const float* __restrict__ scal,
                                                  int kidx, int kchunk) {
  __shared__ u16 LAh[128][64], LAl[128][64], LBh[128][64], LBl[128][64];
  const int tid = threadIdx.x;
  const int bm = blockIdx.x * 128, bn = blockIdx.y * 128;
  const int kz = blockIdx.z;
  const int w = tid >> 6, l = tid & 63;
  const int wr = (w >> 1) * 64, wc = (w & 1) * 64;
  const int arow = tid >> 4, acol = (tid & 15) * 4;
  const int brow = tid >> 3, bcol = (tid & 7) * 8;
  f32x4 acc[4][4];
#pragma unroll
  for (int i = 0; i < 4; ++i)
#pragma unroll
    for (int j = 0; j < 4; ++j) { acc[i][j][0] = 0.f; acc[i][j][1] = 0.f; acc[i][j][2] = 0.f; acc[i][j][3] = 0.f; }

  const int nchunk = kchunk >> 6;
  for (int c = 0; c < nchunk; ++c) {
    const int k0 = kz * kchunk + c * 64;
    uint2 eh[8], el[8];
#pragma unroll
    for (int ii = 0; ii < 8; ++ii) {
      int r = arow + ii * 16;
      float rm = rowmax[bm + r];
      float4 s = *(const float4*)(S + (size_t)(bm + r) * N_ + k0 + acol);
      float e0 = expf(s.x - rm), e1 = expf(s.y - rm), e2 = expf(s.z - rm), e3 = expf(s.w - rm);
      u16 h0 = bf16_rne(e0), h1 = bf16_rne(e1), h2 = bf16_rne(e2), h3 = bf16_rne(e3);
      u16 l0 = bf16_rne(e0 - __uint_as_float((u32)h0 << 16));
      u16 l1 = bf16_rne(e1 - __uint_as_float((u32)h1 << 16));
      u16 l2 = bf16_rne(e2 - __uint_as_float((u32)h2 << 16));
      u16 l3 = bf16_rne(e3 - __uint_as_float((u32)h3 << 16));
      eh[ii] = make_uint2((u32)h0 | ((u32)h1 << 16), (u32)h2 | ((u32)h3 << 16));
      el[ii] = make_uint2((u32)l0 | ((u32)l1 << 16), (u32)l2 | ((u32)l3 << 16));
    }
    uint4 bh[4], bl[4];
#pragma unroll
    for (int ii = 0; ii < 4; ++ii) {
      int r = brow + ii * 32;
      bh[ii] = *(const uint4*)(BhT + (size_t)(bn + r) * N_ + k0 + bcol);
      bl[ii] = *(const uint4*)(BlT + (size_t)(bn + r) * N_ + k0 + bcol);
    }
    __syncthreads();
#pragma unroll
    for (int ii = 0; ii < 8; ++ii) {
      int r = arow + ii * 16;
      int off = r * 128 + (((tid & 15) * 8) ^ ((r & 7) << 4));
      *(uint2*)((char*)LAh + off) = eh[ii];
      *(uint2*)((char*)LAl + off) = el[ii];
    }
#pragma unroll
    for (int ii = 0; ii < 4; ++ii) {
      int r = brow + ii * 32;
      int off = r * 128 + ((bcol * 2) ^ ((r & 7) << 4));
      *(uint4*)((char*)LBh + off) = bh[ii];
      *(uint4*)((char*)LBl + off) = bl[ii];
    }
    __syncthreads();
#pragma unroll
    for (int kk = 0; kk < 2; ++kk) {
      const int kb = kk * 64 + ((l >> 4) << 4);
      bf16x8 fbh[4], fbl[4];
#pragma unroll
      for (int j = 0; j < 4; ++j) {
        int rb = wc + j * 16 + (l & 15);
        int ob = rb * 128 + (kb ^ ((rb & 7) << 4));
        fbh[j] = *(const bf16x8*)((const char*)LBh + ob);
        fbl[j] = *(const bf16x8*)((const char*)LBl + ob);
      }
#pragma unroll
      for (int i = 0; i < 4; ++i) {
        int ra = wr + i * 16 + (l & 15);
        int oa = ra * 128 + (kb ^ ((ra & 7) << 4));
        bf16x8 fah = *(const bf16x8*)((const char*)LAh + oa);
        bf16x8 fal = *(const bf16x8*)((const char*)LAl + oa);
#pragma unroll
        for (int j = 0; j < 4; ++j) {
          acc[i][j] = __builtin_amdgcn_mfma_f32_16x16x32_bf16(fah, fbh[j], acc[i][j], 0, 0, 0);
          acc[i][j] = __builtin_amdgcn_mfma_f32_16x16x32_bf16(fah, fbl[j], acc[i][j], 0, 0, 0);
          acc[i][j] = __builtin_amdgcn_mfma_f32_16x16x32_bf16(fal, fbh[j], acc[i][j], 0, 0, 0);
        }
      }
    }
  }
  const float wk = scal[kidx];
  float* Zp = Zpart + (size_t)kz * N_ * D_;
  const int cr = (l >> 4) * 4, cc = l & 15;
#pragma unroll
  for (int i = 0; i < 4; ++i)
#pragma unroll
    for (int r = 0; r < 4; ++r) {
      int row = bm + wr + i * 16 + cr + r;
      float sc = wk / rowZ[row];
      size_t base = (size_t)row * D_ + bn + wc + cc;
#pragma unroll
      for (int j = 0; j < 4; ++j) Zp[base + j * 16] += sc * acc[i][j][r];
    }
}

// ======================= per-row stats + histogram top-16 =======================
// One block (256 thr) per row. Row held in 16 regs/thread. M and Z via shuffle
// reductions; top-16 via 1024-bin histogram select over monotonic float keys,
// then (val desc, idx asc) pick over <=256 candidates. Same selection semantics
// as jax.lax.top_k (stable ties).
__global__ __launch_bounds__(256) void rowstats_topk(const float* __restrict__ S,
                                                     float* __restrict__ rowmax,
                                                     float* __restrict__ rowZ,
                                                     float* __restrict__ tkv,
                                                     int* __restrict__ tki) {
  const int row = blockIdx.x, tid = threadIdx.x;
  const int wid = tid >> 6, lane = tid & 63;
  __shared__ int hist[1024];
  __shared__ int P[256];
  __shared__ float cval[256];
  __shared__ int cgi[256];
  __shared__ int ccnt;
  __shared__ int binlo_s;
  __shared__ float rv[4];
  __shared__ float stk[TK_];
  __shared__ int itk[TK_];
  __shared__ float tv16[TK_];
  __shared__ float mzs[3];

  hist[tid] = 0; hist[tid + 256] = 0; hist[tid + 512] = 0; hist[tid + 768] = 0;
  if (tid == 0) ccnt = 0;

  const float4* Sp = (const float4*)(S + (size_t)row * N_);
  float r[16];
  float lmax = -3.4e38f;
#pragma unroll
  for (int it = 0; it < 4; ++it) {
    float4 v = Sp[tid + it * 256];
    r[it * 4 + 0] = v.x; r[it * 4 + 1] = v.y; r[it * 4 + 2] = v.z; r[it * 4 + 3] = v.w;
    lmax = fmaxf(lmax, fmaxf(fmaxf(v.x, v.y), fmaxf(v.z, v.w)));
  }
#pragma unroll
  for (int off = 32; off; off >>= 1) lmax = fmaxf(lmax, __shfl_xor(lmax, off));
  if (lane == 0) rv[wid] = lmax;
  __syncthreads();
  if (tid == 0) mzs[0] = fmaxf(fmaxf(rv[0], rv[1]), fmaxf(rv[2], rv[3]));
  __syncthreads();
  const float M = mzs[0];
  float ls = 0.f;
#pragma unroll
  for (int j = 0; j < 16; ++j) ls += expf(r[j] - M);
#pragma unroll
  for (int off = 32; off; off >>= 1) ls += __shfl_xor(ls, off);
  if (lane == 0) rv[wid] = ls;
  __syncthreads();
  if (tid == 0) {
    float z = rv[0] + rv[1] + rv[2] + rv[3];
    mzs[1] = z; rowmax[row] = M; rowZ[row] = z;
  }
  __syncthreads();
  const float Z = mzs[1];

  // histogram over monotonic keys (bin = top 10 bits)
#pragma unroll
  for (int j = 0; j < 16; ++j) {
    u32 u = __float_as_uint(r[j]);
    u32 key = (u >> 31) ? ~u : (u | 0x80000000u);
    atomicAdd(&hist[key >> 22], 1);
  }
  __syncthreads();
  // suffix scan: find largest bin b* with suffix(b*) >= 16
  const int b0 = tid * 4;
  const int h0 = hist[b0], h1 = hist[b0 + 1], h2 = hist[b0 + 2], h3 = hist[b0 + 3];
  P[tid] = h0 + h1 + h2 + h3;
  __syncthreads();
  for (int o = 1; o < 256; o <<= 1) {
    int v = P[tid] + ((tid + o < 256) ? P[tid + o] : 0);
    __syncthreads();
    P[tid] = v;
    __syncthreads();
  }
  {
    int above = (tid < 255) ? P[tid + 1] : 0;   // elems in bins >= b0+4
    int s3 = above + h3, s2 = s3 + h2, s1 = s2 + h1, s0 = s1 + h0;
    if (s3 >= TK_ && above < TK_) binlo_s = b0 + 3;
    else if (s2 >= TK_ && s3 < TK_) binlo_s = b0 + 2;
    else if (s1 >= TK_ && s2 < TK_) binlo_s = b0 + 1;
    else if (s0 >= TK_ && s1 < TK_) binlo_s = b0;
  }
  __syncthreads();
  const u32 kmin = (u32)binlo_s << 22;
#pragma unroll
  for (int j = 0; j < 16; ++j) {
    u32 u = __float_as_uint(r[j]);
    u32 key = (u >> 31) ? ~u : (u | 0x80000000u);
    if (key >= kmin) {
      int p = atomicAdd(&ccnt, 1);
      if (p < 256) {
        cval[p] = r[j];
        cgi[p] = 4 * tid + ((j >> 2) << 10) + (j & 3);
      }
    }
  }
  __syncthreads();
  const int nc = min(ccnt, 256);
  // 16 picks over candidates, (val desc, idx asc)
  for (int t = 0; t < TK_; ++t) {
    if (tid < 64) {
      float bv = -3.4e38f; int bg = 0x7fffffff, bp = -1;
      for (int p = tid; p < nc; p += 64) {
        float v = cval[p]; int g = cgi[p];
        if (v > bv || (v == bv && g < bg)) { bv = v; bg = g; bp = p; }
      }
#pragma unroll
      for (int off = 32; off; off >>= 1) {
        float ov = __shfl_xor(bv, off);
        int og = __shfl_xor(bg, off);
        int op = __shfl_xor(bp, off);
        if (ov > bv || (ov == bv && og < bg)) { bv = ov; bg = og; bp = op; }
      }
      if (tid == 0) { stk[t] = bv; itk[t] = bg; cval[bp] = -3.4e38f; }
    }
    __syncthreads();
  }
  if (tid < TK_) tv16[tid] = expf(stk[tid] - M) / Z;
  __syncthreads();
  if (tid == 0) { float s = 0.f; for (int q = 0; q < TK_; ++q) s += tv16[q]; mzs[2] = s + 1e-9f; }
  __syncthreads();
  if (tid < TK_) {
    tkv[(size_t)row * TK_ + tid] = tv16[tid] / mzs[2];
    tki[(size_t)row * TK_ + tid] = itk[tid];
  }
}

// ======================= hypergraph build =======================
__global__ void edge_scan(const float* __restrict__ tkv, const int* __restrict__ tki,
                          float* __restrict__ DvAcc, int* __restrict__ cnt,
                          float* __restrict__ invDe) {
  int e = blockIdx.x * 256 + threadIdx.x;
  float s = 0.f;
#pragma unroll
  for (int q = 0; q < TK_; ++q) s += tkv[(size_t)e * TK_ + q];
  invDe[e] = 1.0f / (s + 1e-9f);
#pragma unroll
  for (int q = 0; q < TK_; ++q) {
    int m = tki[(size_t)e * TK_ + q];
    atomicAdd(&DvAcc[m], tkv[(size_t)e * TK_ + q]);
    atomicAdd(&cnt[m], 1);
  }
}

__global__ __launch_bounds__(1024) void scan_offsets(const int* __restrict__ cnt,
                                                     int* __restrict__ off,
                                                     int* __restrict__ cur) {
  __shared__ int part[1024];
  const int t = threadIdx.x;
  const int b = t * 4;
  int c0 = cnt[b], c1 = cnt[b + 1], c2 = cnt[b + 2], c3 = cnt[b + 3];
  part[t] = c0 + c1 + c2 + c3;
  __syncthreads();
  for (int o = 1; o < 1024; o <<= 1) {
    int v = part[t] + ((t >= o) ? part[t - o] : 0);
    __syncthreads();
    part[t] = v;
    __syncthreads();
  }
  int ex = (t == 0) ? 0 : part[t - 1];
  off[b] = ex; off[b + 1] = ex + c0; off[b + 2] = ex + c0 + c1; off[b + 3] = ex + c0 + c1 + c2;
  cur[b] = off[b]; cur[b + 1] = off[b + 1]; cur[b + 2] = off[b + 2]; cur[b + 3] = off[b + 3];
  if (t == 1023) off[N_] = part[1023];
}

__global__ void edge_fill(const float* __restrict__ tkv, const int* __restrict__ tki,
                          int* __restrict__ cur, int* __restrict__ ince,
                          float* __restrict__ incv) {
  int e = blockIdx.x * 256 + threadIdx.x;
#pragma unroll
  for (int q = 0; q < TK_; ++q) {
    int m = tki[(size_t)e * TK_ + q];
    int pos = atomicAdd(&cur[m], 1);
    ince[pos] = e;
    incv[pos] = tkv[(size_t)e * TK_ + q];
  }
}

// ======================= power iteration (multi-kernel, unnormalized) ==========
__global__ void pi_init(const float* __restrict__ v0, const float* __restrict__ Dvis,
                        float* __restrict__ v, float* __restrict__ u) {
  int i = blockIdx.x * 256 + threadIdx.x;
  float x = v0[i];
  v[i] = x; u[i] = Dvis[i] * x;
}

__global__ void pi_ye(const float* __restrict__ u, const float* __restrict__ tkv,
                      const int* __restrict__ tki, const float* __restrict__ invDe,
                      float* __restrict__ ye) {
  int e = blockIdx.x * 256 + threadIdx.x;
  const float* tv = tkv + (size_t)e * TK_;
  const int* ti = tki + (size_t)e * TK_;
  float a = 0.f;
#pragma unroll
  for (int q = 0; q < TK_; ++q) a += tv[q] * u[ti[q]];
  ye[e] = a * invDe[e];
}

__global__ void pi_step(const float* __restrict__ v, const float* __restrict__ ye,
                        const int* __restrict__ off, const int* __restrict__ ince,
                        const float* __restrict__ incv, const float* __restrict__ Dvis,
                        float* __restrict__ vn, float* __restrict__ un) {
  int m = blockIdx.x * 256 + threadIdx.x;
  float z = 0.f;
  int j0 = off[m], j1 = off[m + 1];
  for (int j = j0; j < j1; ++j) z += incv[j] * ye[ince[j]];
  float wv = v[m] - Dvis[m] * z;
  vn[m] = wv; un[m] = Dvis[m] * wv;
}

__global__ __launch_bounds__(256) void pi_final(const float* __restrict__ v,
                                                const float* __restrict__ ye,
                                                const int* __restrict__ off,
                                                const int* __restrict__ ince,
                                                const float* __restrict__ incv,
                                                const float* __restrict__ Dvis,
                                                float* __restrict__ partial) {
  __shared__ float r1[256], r2[256];
  int m = blockIdx.x * 256 + threadIdx.x;
  float z = 0.f;
  int j0 = off[m], j1 = off[m + 1];
  for (int j = j0; j < j1; ++j) z += incv[j] * ye[ince[j]];
  float wv = v[m] - Dvis[m] * z;
  r1[threadIdx.x] = v[m] * wv;
  r2[threadIdx.x] = v[m] * v[m];
  __syncthreads();
  for (int s = 128; s; s >>= 1) {
    if (threadIdx.x < s) { r1[threadIdx.x] += r1[threadIdx.x + s]; r2[threadIdx.x] += r2[threadIdx.x + s]; }
    __syncthreads();
  }
  if (threadIdx.x == 0) { partial[blockIdx.x * 2] = r1[0]; partial[blockIdx.x * 2 + 1] = r2[0]; }
}

__global__ void pi_lam(const float* __restrict__ partial, float* __restrict__ scal) {
  if (threadIdx.x == 0) {
    float s1 = 0.f, s2 = 0.f;
    for (int b = 0; b < N_ / 256; ++b) { s1 += partial[2 * b]; s2 += partial[2 * b + 1]; }
    scal[5] = fmaxf(s1 / s2, 1e-3f);
  }
}

// ======================= Chebyshev sparse applies =======================
__global__ __launch_bounds__(256) void ye_mat(const float* __restrict__ U,
                                              const float* __restrict__ tkv,
                                              const int* __restrict__ tki,
                                              const float* __restrict__ invDe,
                                              float* __restrict__ Ye) {
  const int e = blockIdx.x, d = threadIdx.x;
  __shared__ float sv[TK_];
  __shared__ int si[TK_];
  if (d < TK_) { sv[d] = tkv[(size_t)e * TK_ + d]; si[d] = tki[(size_t)e * TK_ + d]; }
  __syncthreads();
  float a = 0.f;
#pragma unroll
  for (int q = 0; q < TK_; ++q) a += sv[q] * U[(size_t)si[q] * D_ + d];
  Ye[(size_t)e * D_ + d] = a * invDe[e];
}

__global__ __launch_bounds__(256) void bgather_combine(const float* __restrict__ Ye,
                                                       const int* __restrict__ off,
                                                       const int* __restrict__ ince,
                                                       const float* __restrict__ incv,
                                                       const float* __restrict__ Dvis,
                                                       const float* __restrict__ Mx,
                                                       const float* __restrict__ G,
                                                       const float* __restrict__ scal,
                                                       float* __restrict__ out, int mode) {
  const int m = blockIdx.x, d = threadIdx.x;
  const int j0 = off[m], j1 = off[m + 1];
  float z = 0.f;
  for (int j = j0; j < j1; ++j) z += incv[j] * Ye[(size_t)ince[j] * D_ + d];
  const float lam = scal[5];
  const float c = 2.0f / lam;
  const size_t idx = (size_t)m * D_ + d;
  const float zz = Dvis[m] * z;
  float r;
  if (mode == 1) r = (c - 1.0f) * Mx[idx] - c * zz;
  else           r = (2.0f * c - 2.0f) * Mx[idx] - 2.0f * c * zz - G[idx];
  out[idx] = r;
}

__global__ void mix_kernel(const float* __restrict__ X, const float* __restrict__ T1,
                           const float* __restrict__ T2, const float* __restrict__ theta,
                           const float* __restrict__ Zpart, int splitk,
                           const float* __restrict__ scal, float* __restrict__ Zmix) {
  const int i = blockIdx.x * 256 + threadIdx.x;
  const int d = i & (D_ - 1);
  float cheb = X[i] * theta[d] + T1[i] * theta[D_ + d] + T2[i] * theta[2 * D_ + d];
  float zs = cheb > 0.f ? cheb : expm1f(cheb);
  float zk = 0.f;
  for (int s = 0; s < splitk; ++s) zk += Zpart[(size_t)s * N_ * D_ + i];
  const float rho = scal[4];
  Zmix[i] = rho * zs + (1.0f - rho) * zk;
}

// ============================= launcher =============================

extern "C" void kernel_launch(void* const* d_in, const int* in_sizes, int n_in,
                              void* d_out, int out_size, void* d_ws, size_t ws_size,
                              hipStream_t stream) {
  const float* X       = (const float*)d_in[0];
  const float* L_k     = (const float*)d_in[1];
  const float* alpha   = (const float*)d_in[2];
  const float* theta   = (const float*)d_in[3];
  const float* rho_raw = (const float*)d_in[4];
  const float* proj_w  = (const float*)d_in[5];
  const float* proj_b  = (const float*)d_in[6];
  const float* v0      = (const float*)d_in[7];
  float* out = (float*)d_out;

  char* w = (char*)d_ws;
  size_t o = 0;
  auto alloc = [&](size_t bytes) -> char* {
    char* p = w + o; o += (bytes + 255) & ~(size_t)255; return p;
  };
  float* S     = (float*)alloc((size_t)N_ * N_ * 4);
  u16*   Xh    = (u16*)  alloc((size_t)N_ * D_ * 2);
  u16*   Xl    = (u16*)  alloc((size_t)N_ * D_ * 2);
  u16*   XhT   = (u16*)  alloc((size_t)D_ * N_ * 2);
  u16*   XlT   = (u16*)  alloc((size_t)D_ * N_ * 2);
  u16*   XLh   = (u16*)  alloc((size_t)N_ * D_ * 2);
  u16*   XLl   = (u16*)  alloc((size_t)N_ * D_ * 2);
  float* rowmax= (float*)alloc(N_ * 4);
  float* rowZ  = (float*)alloc(N_ * 4);
  float* tkv   = (float*)alloc((size_t)NENT_ * 4);
  int*   tki   = (int*)  alloc((size_t)NENT_ * 4);
  float* invDe = (float*)alloc(E_ * 4);
  float* DvAcc = (float*)alloc(N_ * 4);
  float* Dvis  = (float*)alloc(N_ * 4);
  int*   cnt   = (int*)  alloc(N_ * 4);
  int*   off   = (int*)  alloc((N_ + 1) * 4);
  int*   cur   = (int*)  alloc(N_ * 4);
  int*   ince  = (int*)  alloc((size_t)NENT_ * 4);
  float* incv  = (float*)alloc((size_t)NENT_ * 4);
  float* va    = (float*)alloc(N_ * 4);
  float* ua    = (float*)alloc(N_ * 4);
  float* vbuf  = (float*)alloc(N_ * 4);
  float* ubuf  = (float*)alloc(N_ * 4);
  float* yev   = (float*)alloc(E_ * 4);
  float* part  = (float*)alloc((N_ / 256) * 2 * 4);
  float* scal  = (float*)alloc(256);
  int SPLITK = 8;
  while (SPLITK > 1 && o + (size_t)SPLITK * N_ * D_ * 4 > ws_size) SPLITK >>= 1;
  float* Zpart = (float*)alloc((size_t)SPLITK * N_ * D_ * 4);
  const int kchunk = N_ / SPLITK;
  // phase-2 temporaries alias into S (dead after the k-loop)
  float* U    = S;
  float* Ye   = S + (size_t)N_ * D_;
  float* T1   = Ye + (size_t)E_ * D_;
  float* T2   = T1 + (size_t)N_ * D_;
  float* Zmix = T2 + (size_t)N_ * D_;

  scalars_kernel<<<1, 64, 0, stream>>>(alpha, rho_raw, scal);
  hipMemsetAsync(Zpart, 0, (size_t)SPLITK * N_ * D_ * 4, stream);
  hipMemsetAsync(DvAcc, 0, N_ * 4, stream);
  hipMemsetAsync(cnt, 0, N_ * 4, stream);

  // one-time bf16 splits of X (row-major and transposed)
  cvt_split4<<<(N_ * D_ / 4) / 256, 256, 0, stream>>>(X, Xh, Xl);
  transpose_split<<<dim3(D_ / 32, N_ / 32), 256, 0, stream>>>(X, XhT, XlT);

  for (int k = 0; k < K_; ++k) {
    gemm_nn64_split<<<dim3(N_ / 64, D_ / 64), 256, 0, stream>>>(
        X, L_k + (size_t)k * D_ * D_, XLh, XLl, D_, D_, D_, D_);
    scores_mfma<<<dim3(N_ / 128, N_ / 128), 256, 0, stream>>>(
        XLh, XLl, Xh, Xl, S, 1.0f / 16.0f);  // 1/sqrt(256)
    rowstats_topk<<<N_, 256, 0, stream>>>(
        S, rowmax, rowZ, tkv + (size_t)k * N_ * TK_, tki + (size_t)k * N_ * TK_);
    zkern_mfma<<<dim3(N_ / 128, D_ / 128, SPLITK), 256, 0, stream>>>(
        S, rowmax, rowZ, XhT, XlT, Zpart, scal, k, kchunk);
  }

  edge_scan<<<E_ / 256, 256, 0, stream>>>(tkv, tki, DvAcc, cnt, invDe);
  dvis_kernel<<<N_ / 256, 256, 0, stream>>>(DvAcc, Dvis);
  scan_offsets<<<1, 1024, 0, stream>>>(cnt, off, cur);
  edge_fill<<<E_ / 256, 256, 0, stream>>>(tkv, tki, cur, ince, incv);

  pi_init<<<N_ / 256, 256, 0, stream>>>(v0, Dvis, va, ua);
  float* vc = va; float* uc = ua; float* vn = vbuf; float* un = ubuf;
  for (int it = 0; it < 5; ++it) {
    pi_ye<<<E_ / 256, 256, 0, stream>>>(uc, tkv, tki, invDe, yev);
    pi_step<<<N_ / 256, 256, 0, stream>>>(vc, yev, off, ince, incv, Dvis, vn, un);
    float* tv = vc; vc = vn; vn = tv;
    float* tu = uc; uc = un; un = tu;
  }
  pi_ye<<<E_ / 256, 256, 0, stream>>>(uc, tkv, tki, invDe, yev);
  pi_final<<<N_ / 256, 256, 0, stream>>>(vc, yev, off, ince, incv, Dvis, part);
  pi_lam<<<1, 64, 0, stream>>>(part, scal);

  // T1 = Lt @ X
  ew_scale<<<N_ * D_ / 256, 256, 0, stream>>>(X, Dvis, U);
  ye_mat<<<E_, 256, 0, stream>>>(U, tkv, tki, invDe, Ye);
  bgather_combine<<<N_, 256, 0, stream>>>(Ye, off, ince, incv, Dvis, X, X, scal, T1, 1);
  // T2 = 2*Lt @ T1 - X
  ew_scale<<<N_ * D_ / 256, 256, 0, stream>>>(T1, Dvis, U);
  ye_mat<<<E_, 256, 0, stream>>>(U, tkv, tki, invDe, Ye);
  bgather_combine<<<N_, 256, 0, stream>>>(Ye, off, ince, incv, Dvis, T1, X, scal, T2, 2);

  mix_kernel<<<N_ * D_ / 256, 256, 0, stream>>>(X, T1, T2, theta, Zpart, SPLITK, scal, Zmix);

  gemm_nt64_bias<<<dim3(N_ / 64, D_ / 64), 256, 0, stream>>>(
      Zmix, proj_w, proj_b, out, D_, D_, D_, D_);
}

// Round 5
// 1448.783 us; speedup vs baseline: 3.8259x; 1.1389x over previous
//
#include <hip/hip_runtime.h>
#include <math.h>

#define N_ 4096
#define D_ 256
#define K_ 4
#define TK_ 16
#define E_ (K_ * N_)          // 16384 hyperedges
#define NENT_ (E_ * TK_)      // 262144 incidence entries

typedef unsigned short u16;
typedef unsigned int u32;
typedef __attribute__((ext_vector_type(8))) short bf16x8;
typedef __attribute__((ext_vector_type(4))) float f32x4;

__device__ __forceinline__ u16 bf16_rne(float x) {
  u32 u = __float_as_uint(x);
  u32 r = u + 0x7FFFu + ((u >> 16) & 1u);
  return (u16)(r >> 16);
}

// ============================= small kernels =============================

__global__ void scalars_kernel(const float* __restrict__ alpha,
                               const float* __restrict__ rho_raw,
                               float* __restrict__ scal) {
  if (threadIdx.x == 0) {
    float m = alpha[0];
    for (int k = 1; k < K_; ++k) m = fmaxf(m, alpha[k]);
    float e[K_]; float s = 0.f;
    for (int k = 0; k < K_; ++k) { e[k] = expf(alpha[k] - m); s += e[k]; }
    for (int k = 0; k < K_; ++k) scal[k] = e[k] / s;   // w_k
    scal[4] = 1.0f / (1.0f + expf(-rho_raw[0]));       // rho
  }
}

__global__ void dvis_kernel(const float* __restrict__ DvAcc, float* __restrict__ Dvis) {
  int i = blockIdx.x * 256 + threadIdx.x;
  Dvis[i] = 1.0f / sqrtf(DvAcc[i] + 1e-9f);
}

__global__ void ew_scale(const float* __restrict__ M, const float* __restrict__ Dvis,
                         float* __restrict__ U) {
  int i = blockIdx.x * 256 + threadIdx.x;
  U[i] = Dvis[i >> 8] * M[i];
}

// fp32 -> (hi, lo) bf16 split, 4 elems/thread (used for X row-major)
__global__ void cvt_split4(const float* __restrict__ in, u16* __restrict__ hi,
                           u16* __restrict__ lo) {
  int i = (blockIdx.x * 256 + threadIdx.x) * 4;
  float4 v = *(const float4*)(in + i);
  u16 h0 = bf16_rne(v.x), h1 = bf16_rne(v.y), h2 = bf16_rne(v.z), h3 = bf16_rne(v.w);
  float f0 = __uint_as_float((u32)h0 << 16), f1 = __uint_as_float((u32)h1 << 16);
  float f2 = __uint_as_float((u32)h2 << 16), f3 = __uint_as_float((u32)h3 << 16);
  u16 l0 = bf16_rne(v.x - f0), l1 = bf16_rne(v.y - f1);
  u16 l2 = bf16_rne(v.z - f2), l3 = bf16_rne(v.w - f3);
  *(uint2*)(hi + i) = make_uint2((u32)h0 | ((u32)h1 << 16), (u32)h2 | ((u32)h3 << 16));
  *(uint2*)(lo + i) = make_uint2((u32)l0 | ((u32)l1 << 16), (u32)l2 | ((u32)l3 << 16));
}

// X [N][D] fp32 -> XhT/XlT [D][N] bf16 (transposed split). grid (D/32, N/32), 256 thr.
__global__ __launch_bounds__(256) void transpose_split(const float* __restrict__ X,
                                                       u16* __restrict__ ht,
                                                       u16* __restrict__ lt) {
  __shared__ float tile[32][33];
  const int tx = threadIdx.x & 31, ty = threadIdx.x >> 5;  // 32x8
  const int d0 = blockIdx.x * 32, n0 = blockIdx.y * 32;
#pragma unroll
  for (int q = 0; q < 4; ++q)
    tile[ty + q * 8][tx] = X[(size_t)(n0 + ty + q * 8) * D_ + d0 + tx];
  __syncthreads();
#pragma unroll
  for (int q = 0; q < 4; ++q) {
    int dd = ty + q * 8;
    float v = tile[tx][dd];               // = X[n0+tx][d0+dd]
    u16 h = bf16_rne(v);
    float hf = __uint_as_float((u32)h << 16);
    u16 l = bf16_rne(v - hf);
    ht[(size_t)(d0 + dd) * N_ + n0 + tx] = h;
    lt[(size_t)(d0 + dd) * N_ + n0 + tx] = l;
  }
}

// ============================= 64-tile fp32 GEMMs =============================
// XL = X @ L_k, epilogue writes bf16 hi/lo split directly. grid=(N/64, D/64).
__global__ __launch_bounds__(256) void gemm_nn64_split(const float* __restrict__ A,
                                                       const float* __restrict__ B,
                                                       u16* __restrict__ Ch,
                                                       u16* __restrict__ Cl,
                                                       int Kdim, int lda, int ldb, int ldc) {
  __shared__ float As[16][68];
  __shared__ float Bs[16][68];
  const int tid = threadIdx.x;
  const int bm = blockIdx.x * 64, bn = blockIdx.y * 64;
  const int lrA = tid >> 2, lcA = (tid & 3) * 4;
  const int rrB = tid >> 4, ccB = (tid & 15) * 4;
  const int tx = tid & 15, ty = tid >> 4;
  const float* Ap = A + (size_t)(bm + lrA) * lda + lcA;
  const float* Bp = B + (size_t)rrB * ldb + bn + ccB;
  float acc[4][4] = {};
  for (int k0 = 0; k0 < Kdim; k0 += 16) {
    float4 av = *(const float4*)(Ap + k0);
    float4 bv = *(const float4*)(Bp + (size_t)k0 * ldb);
    __syncthreads();
    As[lcA + 0][lrA] = av.x; As[lcA + 1][lrA] = av.y;
    As[lcA + 2][lrA] = av.z; As[lcA + 3][lrA] = av.w;
    *(float4*)&Bs[rrB][ccB] = bv;
    __syncthreads();
#pragma unroll
    for (int kk = 0; kk < 16; ++kk) {
      float a[4], b[4];
      *(float4*)a = *(const float4*)&As[kk][ty * 4];
      *(float4*)b = *(const float4*)&Bs[kk][tx * 4];
#pragma unroll
      for (int i = 0; i < 4; ++i)
#pragma unroll
        for (int j = 0; j < 4; ++j) acc[i][j] += a[i] * b[j];
    }
  }
#pragma unroll
  for (int i = 0; i < 4; ++i) {
    int row = bm + ty * 4 + i;
    u16 h[4], lo[4];
#pragma unroll
    for (int j = 0; j < 4; ++j) {
      h[j] = bf16_rne(acc[i][j]);
      lo[j] = bf16_rne(acc[i][j] - __uint_as_float((u32)h[j] << 16));
    }
    size_t base = (size_t)row * ldc + bn + tx * 4;
    *(uint2*)(Ch + base) = make_uint2((u32)h[0] | ((u32)h[1] << 16), (u32)h[2] | ((u32)h[3] << 16));
    *(uint2*)(Cl + base) = make_uint2((u32)lo[0] | ((u32)lo[1] << 16), (u32)lo[2] | ((u32)lo[3] << 16));
  }
}

// C(MxN) = A(MxK) @ B(NxK)^T + bias, row-major. grid=(M/64, N/64).
__global__ __launch_bounds__(256) void gemm_nt64_bias(const float* __restrict__ A,
                                                      const float* __restrict__ B,
                                                      const float* __restrict__ bias,
                                                      float* __restrict__ C,
                                                      int Kdim, int lda, int ldb, int ldc) {
  __shared__ float As[16][68];
  __shared__ float Bs[16][68];
  const int tid = threadIdx.x;
  const int bm = blockIdx.x * 64, bn = blockIdx.y * 64;
  const int lr = tid >> 2, lc = (tid & 3) * 4;
  const int tx = tid & 15, ty = tid >> 4;
  const float* Ap = A + (size_t)(bm + lr) * lda + lc;
  const float* Bp = B + (size_t)(bn + lr) * ldb + lc;
  float acc[4][4] = {};
  for (int k0 = 0; k0 < Kdim; k0 += 16) {
    float4 av = *(const float4*)(Ap + k0);
    float4 bv = *(const float4*)(Bp + k0);
    __syncthreads();
    As[lc + 0][lr] = av.x; As[lc + 1][lr] = av.y; As[lc + 2][lr] = av.z; As[lc + 3][lr] = av.w;
    Bs[lc + 0][lr] = bv.x; Bs[lc + 1][lr] = bv.y; Bs[lc + 2][lr] = bv.z; Bs[lc + 3][lr] = bv.w;
    __syncthreads();
#pragma unroll
    for (int kk = 0; kk < 16; ++kk) {
      float a[4], b[4];
      *(float4*)a = *(const float4*)&As[kk][ty * 4];
      *(float4*)b = *(const float4*)&Bs[kk][tx * 4];
#pragma unroll
      for (int i = 0; i < 4; ++i)
#pragma unroll
        for (int j = 0; j < 4; ++j) acc[i][j] += a[i] * b[j];
    }
  }
#pragma unroll
  for (int i = 0; i < 4; ++i) {
    int row = bm + ty * 4 + i;
    float4 o;
    o.x = acc[i][0] + bias[bn + tx * 4 + 0];
    o.y = acc[i][1] + bias[bn + tx * 4 + 1];
    o.z = acc[i][2] + bias[bn + tx * 4 + 2];
    o.w = acc[i][3] + bias[bn + tx * 4 + 3];
    *(float4*)(C + (size_t)row * ldc + bn + tx * 4) = o;
  }
}

// ===================== MFMA bf16-split GEMMs (3-pass hi/lo) =====================
// A tile in LDS [128 rows][64 bf16] x (hi,lo) = 32 KB, XOR-swizzled
// (byte ^= (row&7)<<4). B fragments loaded DIRECTLY from global (L2-resident,
// 2 MB arrays) -- per-lane 16B loads give the exact MFMA B register layout.
// Epilogue: 2 x 64-row rounds through the (dead) 32 KB A buffer, float4 stores.

// S(4096x4096) = (Ah+Al)(Bh+Bl)^T * scale. grid (32,32).
__global__ __launch_bounds__(256) void scores_mfma(const u16* __restrict__ Ahg,
                                                   const u16* __restrict__ Alg,
                                                   const u16* __restrict__ Bhg,
                                                   const u16* __restrict__ Blg,
                                                   float* __restrict__ C, float scale) {
  __shared__ char smem[32768];
  char* pAh = smem;
  char* pAl = smem + 16384;
  const int tid = threadIdx.x;
  const int bm = blockIdx.x * 128, bn = blockIdx.y * 128;
  const int w = tid >> 6, l = tid & 63;
  const int wr = (w >> 1) * 64, wc = (w & 1) * 64;
  const int srow = tid >> 3, scol = (tid & 7) * 8;
  const int lb = l & 15, lke = (l >> 4) * 8;   // lane row-in-frag, k elem offset
  // per-j B lane pointers (row = bn + wc + j*16 + lb)
  const u16* bh0 = Bhg + (size_t)(bn + wc + 0  + lb) * D_ + lke;
  const u16* bh1 = Bhg + (size_t)(bn + wc + 16 + lb) * D_ + lke;
  const u16* bh2 = Bhg + (size_t)(bn + wc + 32 + lb) * D_ + lke;
  const u16* bh3 = Bhg + (size_t)(bn + wc + 48 + lb) * D_ + lke;
  const size_t dlo = (size_t)(Blg - Bhg);
  f32x4 acc[4][4];
#pragma unroll
  for (int i = 0; i < 4; ++i)
#pragma unroll
    for (int j = 0; j < 4; ++j) { acc[i][j][0] = 0.f; acc[i][j][1] = 0.f; acc[i][j][2] = 0.f; acc[i][j][3] = 0.f; }

  for (int c = 0; c < 4; ++c) {
    const int k0 = c * 64;
    uint4 ah[4], al[4];
#pragma unroll
    for (int ii = 0; ii < 4; ++ii) {
      int r = srow + ii * 32;
      ah[ii] = *(const uint4*)(Ahg + (size_t)(bm + r) * D_ + k0 + scol);
      al[ii] = *(const uint4*)(Alg + (size_t)(bm + r) * D_ + k0 + scol);
    }
    __syncthreads();
#pragma unroll
    for (int ii = 0; ii < 4; ++ii) {
      int r = srow + ii * 32;
      int off = r * 128 + ((scol * 2) ^ ((r & 7) << 4));
      *(uint4*)(pAh + off) = ah[ii];
      *(uint4*)(pAl + off) = al[ii];
    }
    __syncthreads();
#pragma unroll
    for (int kk = 0; kk < 2; ++kk) {
      const int kb = kk * 64 + ((l >> 4) << 4);
      const int ge = k0 + kk * 32;               // global k element offset
      bf16x8 fbh[4], fbl[4];
      fbh[0] = *(const bf16x8*)(bh0 + ge); fbl[0] = *(const bf16x8*)(bh0 + dlo + ge);
      fbh[1] = *(const bf16x8*)(bh1 + ge); fbl[1] = *(const bf16x8*)(bh1 + dlo + ge);
      fbh[2] = *(const bf16x8*)(bh2 + ge); fbl[2] = *(const bf16x8*)(bh2 + dlo + ge);
      fbh[3] = *(const bf16x8*)(bh3 + ge); fbl[3] = *(const bf16x8*)(bh3 + dlo + ge);
#pragma unroll
      for (int i = 0; i < 4; ++i) {
        int ra = wr + i * 16 + lb;
        int oa = ra * 128 + (kb ^ ((ra & 7) << 4));
        bf16x8 fah = *(const bf16x8*)(pAh + oa);
        bf16x8 fal = *(const bf16x8*)(pAl + oa);
#pragma unroll
        for (int j = 0; j < 4; ++j) {
          acc[i][j] = __builtin_amdgcn_mfma_f32_16x16x32_bf16(fah, fbh[j], acc[i][j], 0, 0, 0);
          acc[i][j] = __builtin_amdgcn_mfma_f32_16x16x32_bf16(fah, fbl[j], acc[i][j], 0, 0, 0);
          acc[i][j] = __builtin_amdgcn_mfma_f32_16x16x32_bf16(fal, fbh[j], acc[i][j], 0, 0, 0);
        }
      }
    }
  }
  // epilogue: two 64-row rounds through 32 KB LDS (64 x 128 f32)
  float* Cs = (float*)smem;
  const int cr = (l >> 4) * 4, cc = l & 15;
#pragma unroll
  for (int p = 0; p < 2; ++p) {
    __syncthreads();
    if ((w >> 1) == p) {
#pragma unroll
      for (int i = 0; i < 4; ++i)
#pragma unroll
        for (int r = 0; r < 4; ++r) {
          int rl = i * 16 + cr + r;
          int sw = ((rl >> 2) & 3) << 4;
#pragma unroll
          for (int j = 0; j < 4; ++j) {
            int cl = wc + j * 16 + cc;
            Cs[rl * 128 + (cl ^ sw)] = acc[i][j][r] * scale;
          }
        }
    }
    __syncthreads();
#pragma unroll
    for (int ii = 0; ii < 8; ++ii) {
      int rl = ii * 8 + (tid >> 5);
      int c4 = (tid & 31) * 4;
      float4 v = *(float4*)&Cs[rl * 128 + (c4 ^ (((rl >> 2) & 3) << 4))];
      *(float4*)(C + (size_t)(bm + p * 64 + rl) * N_ + bn + c4) = v;
    }
  }
}

// Zpart[kz] += (w_k/rowZ[m]) * exp(S-rowmax) @ X ; A staged from S with exp+split,
// B fragments direct from XhT/XlT [256][4096]. grid (32, 2, SPLITK).
__global__ __launch_bounds__(256) void zkern_mfma(const float* __restrict__ S,
                                                  const float* __restrict__ rowmax,
                                                  const float* __restrict__ rowZ,
                                                  const u16* __restrict__ BhT,
                                                  const u16* __restrict__ BlT,
                                                  float* __restrict__ Zpart,
                                                  const float* __restrict__ scal,
                                                  int kidx, int kchunk) {
  __shared__ char smem[32768];
  char* pAh = smem;
  char* pAl = smem + 16384;
  const int tid = threadIdx.x;
  const int bm = blockIdx.x * 128, bn = blockIdx.y * 128;
  const int kz = blockIdx.z;
  const int w = tid >> 6, l = tid & 63;
  const int wr = (w >> 1) * 64, wc = (w & 1) * 64;
  const int arow = tid >> 4, acol = (tid & 15) * 4;
  const int lb = l & 15, lke = (l >> 4) * 8;
  const u16* bh0 = BhT + (size_t)(bn + wc + 0  + lb) * N_ + lke;
  const u16* bh1 = BhT + (size_t)(bn + wc + 16 + lb) * N_ + lke;
  const u16* bh2 = BhT + (size_t)(bn + wc + 32 + lb) * N_ + lke;
  const u16* bh3 = BhT + (size_t)(bn + wc + 48 + lb) * N_ + lke;
  const size_t dlo = (size_t)(BlT - BhT);
  float rm[8];
#pragma unroll
  for (int ii = 0; ii < 8; ++ii) rm[ii] = rowmax[bm + arow + ii * 16];
  f32x4 acc[4][4];
#pragma unroll
  for (int i = 0; i < 4; ++i)
#pragma unroll
    for (int j = 0; j < 4; ++j) { acc[i][j][0] = 0.f; acc[i][j][1] = 0.f; acc[i][j][2] = 0.f; acc[i][j][3] = 0.f; }

  const int nchunk = kchunk >> 6;
  for (int c = 0; c < nchunk; ++c) {
    const int k0 = kz * kchunk + c * 64;
    uint2 eh[8], el[8];
#pragma unroll
    for (int ii = 0; ii < 8; ++ii) {
      int r = arow + ii * 16;
      float4 s = *(const float4*)(S + (size_t)(bm + r) * N_ + k0 + acol);
      float e0 = expf(s.x - rm[ii]), e1 = expf(s.y - rm[ii]);
      float e2 = expf(s.z - rm[ii]), e3 = expf(s.w - rm[ii]);
      u16 h0 = bf16_rne(e0), h1 = bf16_rne(e1), h2 = bf16_rne(e2), h3 = bf16_rne(e3);
      u16 l0 = bf16_rne(e0 - __uint_as_float((u32)h0 << 16));
      u16 l1 = bf16_rne(e1 - __uint_as_float((u32)h1 << 16));
      u16 l2 = bf16_rne(e2 - __uint_as_float((u32)h2 << 16));
      u16 l3 = bf16_rne(e3 - __uint_as_float((u32)h3 << 16));
      eh[ii] = make_uint2((u32)h0 | ((u32)h1 << 16), (u32)h2 | ((u32)h3 << 16));
      el[ii] = make_uint2((u32)l0 | ((u32)l1 << 16), (u32)l2 | ((u32)l3 << 16));
    }
    __syncthreads();
#pragma unroll
    for (int ii = 0; ii < 8; ++ii) {
      int r = arow + ii * 16;
      int off = r * 128 + ((acol * 2) ^ ((r & 7) << 4));
      *(uint2*)(pAh + off) = eh[ii];
      *(uint2*)(pAl + off) = el[ii];
    }
    __syncthreads();
#pragma unroll
    for (int kk = 0; kk < 2; ++kk) {
      const int kb = kk * 64 + ((l >> 4) << 4);
      const int ge = k0 + kk * 32;
      bf16x8 fbh[4], fbl[4];
      fbh[0] = *(const bf16x8*)(bh0 + ge); fbl[0] = *(const bf16x8*)(bh0 + dlo + ge);
      fbh[1] = *(const bf16x8*)(bh1 + ge); fbl[1] = *(const bf16x8*)(bh1 + dlo + ge);
      fbh[2] = *(const bf16x8*)(bh2 + ge); fbl[2] = *(const bf16x8*)(bh2 + dlo + ge);
      fbh[3] = *(const bf16x8*)(bh3 + ge); fbl[3] = *(const bf16x8*)(bh3 + dlo + ge);
#pragma unroll
      for (int i = 0; i < 4; ++i) {
        int ra = wr + i * 16 + lb;
        int oa = ra * 128 + (kb ^ ((ra & 7) << 4));
        bf16x8 fah = *(const bf16x8*)(pAh + oa);
        bf16x8 fal = *(const bf16x8*)(pAl + oa);
#pragma unroll
        for (int j = 0; j < 4; ++j) {
          acc[i][j] = __builtin_amdgcn_mfma_f32_16x16x32_bf16(fah, fbh[j], acc[i][j], 0, 0, 0);
          acc[i][j] = __builtin_amdgcn_mfma_f32_16x16x32_bf16(fah, fbl[j], acc[i][j], 0, 0, 0);
          acc[i][j] = __builtin_amdgcn_mfma_f32_16x16x32_bf16(fal, fbh[j], acc[i][j], 0, 0, 0);
        }
      }
    }
  }
  // epilogue: LDS transpose rounds + coalesced float4 RMW of Zpart
  const float wk = scal[kidx];
  float* Zp = Zpart + (size_t)kz * N_ * D_;
  float* Cs = (float*)smem;
  const int cr = (l >> 4) * 4, cc = l & 15;
#pragma unroll
  for (int p = 0; p < 2; ++p) {
    __syncthreads();
    if ((w >> 1) == p) {
#pragma unroll
      for (int i = 0; i < 4; ++i)
#pragma unroll
        for (int r = 0; r < 4; ++r) {
          int rl = i * 16 + cr + r;
          int sw = ((rl >> 2) & 3) << 4;
#pragma unroll
          for (int j = 0; j < 4; ++j) {
            int cl = wc + j * 16 + cc;
            Cs[rl * 128 + (cl ^ sw)] = acc[i][j][r];
          }
        }
    }
    __syncthreads();
#pragma unroll
    for (int ii = 0; ii < 8; ++ii) {
      int rl = ii * 8 + (tid >> 5);
      int c4 = (tid & 31) * 4;
      int row = bm + p * 64 + rl;
      float sc = wk / rowZ[row];
      float4 v = *(float4*)&Cs[rl * 128 + (c4 ^ (((rl >> 2) & 3) << 4))];
      float* zb = Zp + (size_t)row * D_ + bn + c4;
      float4 z = *(float4*)zb;
      z.x += sc * v.x; z.y += sc * v.y; z.z += sc * v.z; z.w += sc * v.w;
      *(float4*)zb = z;
    }
  }
}

// ======================= per-row stats + histogram top-16 =======================
__global__ __launch_bounds__(256) void rowstats_topk(const float* __restrict__ S,
                                                     float* __restrict__ rowmax,
                                                     float* __restrict__ rowZ,
                                                     float* __restrict__ tkv,
                                                     int* __restrict__ tki) {
  const int row = blockIdx.x, tid = threadIdx.x;
  const int wid = tid >> 6, lane = tid & 63;
  __shared__ int hist[1024];
  __shared__ int P[256];
  __shared__ float cval[256];
  __shared__ int cgi[256];
  __shared__ int ccnt;
  __shared__ int binlo_s;
  __shared__ float rv[4];
  __shared__ float stk[TK_];
  __shared__ int itk[TK_];
  __shared__ float tv16[TK_];
  __shared__ float mzs[3];

  hist[tid] = 0; hist[tid + 256] = 0; hist[tid + 512] = 0; hist[tid + 768] = 0;
  if (tid == 0) ccnt = 0;

  const float4* Sp = (const float4*)(S + (size_t)row * N_);
  float r[16];
  float lmax = -3.4e38f;
#pragma unroll
  for (int it = 0; it < 4; ++it) {
    float4 v = Sp[tid + it * 256];
    r[it * 4 + 0] = v.x; r[it * 4 + 1] = v.y; r[it * 4 + 2] = v.z; r[it * 4 + 3] = v.w;
    lmax = fmaxf(lmax, fmaxf(fmaxf(v.x, v.y), fmaxf(v.z, v.w)));
  }
#pragma unroll
  for (int off = 32; off; off >>= 1) lmax = fmaxf(lmax, __shfl_xor(lmax, off));
  if (lane == 0) rv[wid] = lmax;
  __syncthreads();
  if (tid == 0) mzs[0] = fmaxf(fmaxf(rv[0], rv[1]), fmaxf(rv[2], rv[3]));
  __syncthreads();
  const float M = mzs[0];
  float ls = 0.f;
#pragma unroll
  for (int j = 0; j < 16; ++j) ls += expf(r[j] - M);
#pragma unroll
  for (int off = 32; off; off >>= 1) ls += __shfl_xor(ls, off);
  if (lane == 0) rv[wid] = ls;
  __syncthreads();
  if (tid == 0) {
    float z = rv[0] + rv[1] + rv[2] + rv[3];
    mzs[1] = z; rowmax[row] = M; rowZ[row] = z;
  }
  __syncthreads();
  const float Z = mzs[1];

#pragma unroll
  for (int j = 0; j < 16; ++j) {
    u32 u = __float_as_uint(r[j]);
    u32 key = (u >> 31) ? ~u : (u | 0x80000000u);
    atomicAdd(&hist[key >> 22], 1);
  }
  __syncthreads();
  const int b0 = tid * 4;
  const int h0 = hist[b0], h1 = hist[b0 + 1], h2 = hist[b0 + 2], h3 = hist[b0 + 3];
  P[tid] = h0 + h1 + h2 + h3;
  __syncthreads();
  for (int o = 1; o < 256; o <<= 1) {
    int v = P[tid] + ((tid + o < 256) ? P[tid + o] : 0);
    __syncthreads();
    P[tid] = v;
    __syncthreads();
  }
  {
    int above = (tid < 255) ? P[tid + 1] : 0;
    int s3 = above + h3, s2 = s3 + h2, s1 = s2 + h1, s0 = s1 + h0;
    if (s3 >= TK_ && above < TK_) binlo_s = b0 + 3;
    else if (s2 >= TK_ && s3 < TK_) binlo_s = b0 + 2;
    else if (s1 >= TK_ && s2 < TK_) binlo_s = b0 + 1;
    else if (s0 >= TK_ && s1 < TK_) binlo_s = b0;
  }
  __syncthreads();
  const u32 kmin = (u32)binlo_s << 22;
#pragma unroll
  for (int j = 0; j < 16; ++j) {
    u32 u = __float_as_uint(r[j]);
    u32 key = (u >> 31) ? ~u : (u | 0x80000000u);
    if (key >= kmin) {
      int p = atomicAdd(&ccnt, 1);
      if (p < 256) {
        cval[p] = r[j];
        cgi[p] = 4 * tid + ((j >> 2) << 10) + (j & 3);
      }
    }
  }
  __syncthreads();
  const int nc = min(ccnt, 256);
  for (int t = 0; t < TK_; ++t) {
    if (tid < 64) {
      float bv = -3.4e38f; int bg = 0x7fffffff, bp = -1;
      for (int p = tid; p < nc; p += 64) {
        float v = cval[p]; int g = cgi[p];
        if (v > bv || (v == bv && g < bg)) { bv = v; bg = g; bp = p; }
      }
#pragma unroll
      for (int off = 32; off; off >>= 1) {
        float ov = __shfl_xor(bv, off);
        int og = __shfl_xor(bg, off);
        int op = __shfl_xor(bp, off);
        if (ov > bv || (ov == bv && og < bg)) { bv = ov; bg = og; bp = op; }
      }
      if (tid == 0) { stk[t] = bv; itk[t] = bg; cval[bp] = -3.4e38f; }
    }
    __syncthreads();
  }
  if (tid < TK_) tv16[tid] = expf(stk[tid] - M) / Z;
  __syncthreads();
  if (tid == 0) { float s = 0.f; for (int q = 0; q < TK_; ++q) s += tv16[q]; mzs[2] = s + 1e-9f; }
  __syncthreads();
  if (tid < TK_) {
    tkv[(size_t)row * TK_ + tid] = tv16[tid] / mzs[2];
    tki[(size_t)row * TK_ + tid] = itk[tid];
  }
}

// ======================= hypergraph build =======================
__global__ void edge_scan(const float* __restrict__ tkv, const int* __restrict__ tki,
                          float* __restrict__ DvAcc, int* __restrict__ cnt,
                          float* __restrict__ invDe) {
  int e = blockIdx.x * 256 + threadIdx.x;
  float s = 0.f;
#pragma unroll
  for (int q = 0; q < TK_; ++q) s += tkv[(size_t)e * TK_ + q];
  invDe[e] = 1.0f / (s + 1e-9f);
#pragma unroll
  for (int q = 0; q < TK_; ++q) {
    int m = tki[(size_t)e * TK_ + q];
    atomicAdd(&DvAcc[m], tkv[(size_t)e * TK_ + q]);
    atomicAdd(&cnt[m], 1);
  }
}

__global__ __launch_bounds__(1024) void scan_offsets(const int* __restrict__ cnt,
                                                     int* __restrict__ off,
                                                     int* __restrict__ cur) {
  __shared__ int part[1024];
  const int t = threadIdx.x;
  const int b = t * 4;
  int c0 = cnt[b], c1 = cnt[b + 1], c2 = cnt[b + 2], c3 = cnt[b + 3];
  part[t] = c0 + c1 + c2 + c3;
  __syncthreads();
  for (int o = 1; o < 1024; o <<= 1) {
    int v = part[t] + ((t >= o) ? part[t - o] : 0);
    __syncthreads();
    part[t] = v;
    __syncthreads();
  }
  int ex = (t == 0) ? 0 : part[t - 1];
  off[b] = ex; off[b + 1] = ex + c0; off[b + 2] = ex + c0 + c1; off[b + 3] = ex + c0 + c1 + c2;
  cur[b] = off[b]; cur[b + 1] = off[b + 1]; cur[b + 2] = off[b + 2]; cur[b + 3] = off[b + 3];
  if (t == 1023) off[N_] = part[1023];
}

__global__ void edge_fill(const float* __restrict__ tkv, const int* __restrict__ tki,
                          int* __restrict__ cur, int* __restrict__ ince,
                          float* __restrict__ incv) {
  int e = blockIdx.x * 256 + threadIdx.x;
#pragma unroll
  for (int q = 0; q < TK_; ++q) {
    int m = tki[(size_t)e * TK_ + q];
    int pos = atomicAdd(&cur[m], 1);
    ince[pos] = e;
    incv[pos] = tkv[(size_t)e * TK_ + q];
  }
}

// ======================= power iteration (multi-kernel, unnormalized) ==========
__global__ void pi_init(const float* __restrict__ v0, const float* __restrict__ Dvis,
                        float* __restrict__ v, float* __restrict__ u) {
  int i = blockIdx.x * 256 + threadIdx.x;
  float x = v0[i];
  v[i] = x; u[i] = Dvis[i] * x;
}

__global__ void pi_ye(const float* __restrict__ u, const float* __restrict__ tkv,
                      const int* __restrict__ tki, const float* __restrict__ invDe,
                      float* __restrict__ ye) {
  int e = blockIdx.x * 256 + threadIdx.x;
  const float* tv = tkv + (size_t)e * TK_;
  const int* ti = tki + (size_t)e * TK_;
  float a = 0.f;
#pragma unroll
  for (int q = 0; q < TK_; ++q) a += tv[q] * u[ti[q]];
  ye[e] = a * invDe[e];
}

__global__ void pi_step(const float* __restrict__ v, const float* __restrict__ ye,
                        const int* __restrict__ off, const int* __restrict__ ince,
                        const float* __restrict__ incv, const float* __restrict__ Dvis,
                        float* __restrict__ vn, float* __restrict__ un) {
  int m = blockIdx.x * 256 + threadIdx.x;
  float z = 0.f;
  int j0 = off[m], j1 = off[m + 1];
  for (int j = j0; j < j1; ++j) z += incv[j] * ye[ince[j]];
  float wv = v[m] - Dvis[m] * z;
  vn[m] = wv; un[m] = Dvis[m] * wv;
}

__global__ __launch_bounds__(256) void pi_final(const float* __restrict__ v,
                                                const float* __restrict__ ye,
                                                const int* __restrict__ off,
                                                const int* __restrict__ ince,
                                                const float* __restrict__ incv,
                                                const float* __restrict__ Dvis,
                                                float* __restrict__ partial) {
  __shared__ float r1[256], r2[256];
  int m = blockIdx.x * 256 + threadIdx.x;
  float z = 0.f;
  int j0 = off[m], j1 = off[m + 1];
  for (int j = j0; j < j1; ++j) z += incv[j] * ye[ince[j]];
  float wv = v[m] - Dvis[m] * z;
  r1[threadIdx.x] = v[m] * wv;
  r2[threadIdx.x] = v[m] * v[m];
  __syncthreads();
  for (int s = 128; s; s >>= 1) {
    if (threadIdx.x < s) { r1[threadIdx.x] += r1[threadIdx.x + s]; r2[threadIdx.x] += r2[threadIdx.x + s]; }
    __syncthreads();
  }
  if (threadIdx.x == 0) { partial[blockIdx.x * 2] = r1[0]; partial[blockIdx.x * 2 + 1] = r2[0]; }
}

__global__ void pi_lam(const float* __restrict__ partial, float* __restrict__ scal) {
  if (threadIdx.x == 0) {
    float s1 = 0.f, s2 = 0.f;
    for (int b = 0; b < N_ / 256; ++b) { s1 += partial[2 * b]; s2 += partial[2 * b + 1]; }
    scal[5] = fmaxf(s1 / s2, 1e-3f);
  }
}

// ======================= Chebyshev sparse applies =======================
__global__ __launch_bounds__(256) void ye_mat(const float* __restrict__ U,
                                              const float* __restrict__ tkv,
                                              const int* __restrict__ tki,
                                              const float* __restrict__ invDe,
                                              float* __restrict__ Ye) {
  const int e = blockIdx.x, d = threadIdx.x;
  __shared__ float sv[TK_];
  __shared__ int si[TK_];
  if (d < TK_) { sv[d] = tkv[(size_t)e * TK_ + d]; si[d] = tki[(size_t)e * TK_ + d]; }
  __syncthreads();
  float a = 0.f;
#pragma unroll
  for (int q = 0; q < TK_; ++q) a += sv[q] * U[(size_t)si[q] * D_ + d];
  Ye[(size_t)e * D_ + d] = a * invDe[e];
}

__global__ __launch_bounds__(256) void bgather_combine(const float* __restrict__ Ye,
                                                       const int* __restrict__ off,
                                                       const int* __restrict__ ince,
                                                       const float* __restrict__ incv,
                                                       const float* __restrict__ Dvis,
                                                       const float* __restrict__ Mx,
                                                       const float* __restrict__ G,
                                                       const float* __restrict__ scal,
                                                       float* __restrict__ out, int mode) {
  const int m = blockIdx.x, d = threadIdx.x;
  const int j0 = off[m], j1 = off[m + 1];
  float z = 0.f;
  for (int j = j0; j < j1; ++j) z += incv[j] * Ye[(size_t)ince[j] * D_ + d];
  const float lam = scal[5];
  const float c = 2.0f / lam;
  const size_t idx = (size_t)m * D_ + d;
  const float zz = Dvis[m] * z;
  float r;
  if (mode == 1) r = (c - 1.0f) * Mx[idx] - c * zz;
  else           r = (2.0f * c - 2.0f) * Mx[idx] - 2.0f * c * zz - G[idx];
  out[idx] = r;
}

__global__ void mix_kernel(const float* __restrict__ X, const float* __restrict__ T1,
                           const float* __restrict__ T2, const float* __restrict__ theta,
                           const float* __restrict__ Zpart, int splitk,
                           const float* __restrict__ scal, float* __restrict__ Zmix) {
  const int i = blockIdx.x * 256 + threadIdx.x;
  const int d = i & (D_ - 1);
  float cheb = X[i] * theta[d] + T1[i] * theta[D_ + d] + T2[i] * theta[2 * D_ + d];
  float zs = cheb > 0.f ? cheb : expm1f(cheb);
  float zk = 0.f;
  for (int s = 0; s < splitk; ++s) zk += Zpart[(size_t)s * N_ * D_ + i];
  const float rho = scal[4];
  Zmix[i] = rho * zs + (1.0f - rho) * zk;
}

// ============================= launcher =============================

extern "C" void kernel_launch(void* const* d_in, const int* in_sizes, int n_in,
                              void* d_out, int out_size, void* d_ws, size_t ws_size,
                              hipStream_t stream) {
  const float* X       = (const float*)d_in[0];
  const float* L_k     = (const float*)d_in[1];
  const float* alpha   = (const float*)d_in[2];
  const float* theta   = (const float*)d_in[3];
  const float* rho_raw = (const float*)d_in[4];
  const float* proj_w  = (const float*)d_in[5];
  const float* proj_b  = (const float*)d_in[6];
  const float* v0      = (const float*)d_in[7];
  float* out = (float*)d_out;

  char* w = (char*)d_ws;
  size_t o = 0;
  auto alloc = [&](size_t bytes) -> char* {
    char* p = w + o; o += (bytes + 255) & ~(size_t)255; return p;
  };
  float* S     = (float*)alloc((size_t)N_ * N_ * 4);
  u16*   Xh    = (u16*)  alloc((size_t)N_ * D_ * 2);
  u16*   Xl    = (u16*)  alloc((size_t)N_ * D_ * 2);
  u16*   XhT   = (u16*)  alloc((size_t)D_ * N_ * 2);
  u16*   XlT   = (u16*)  alloc((size_t)D_ * N_ * 2);
  u16*   XLh   = (u16*)  alloc((size_t)N_ * D_ * 2);
  u16*   XLl   = (u16*)  alloc((size_t)N_ * D_ * 2);
  float* rowmax= (float*)alloc(N_ * 4);
  float* rowZ  = (float*)alloc(N_ * 4);
  float* tkv   = (float*)alloc((size_t)NENT_ * 4);
  int*   tki   = (int*)  alloc((size_t)NENT_ * 4);
  float* invDe = (float*)alloc(E_ * 4);
  float* DvAcc = (float*)alloc(N_ * 4);
  float* Dvis  = (float*)alloc(N_ * 4);
  int*   cnt   = (int*)  alloc(N_ * 4);
  int*   off   = (int*)  alloc((N_ + 1) * 4);
  int*   cur   = (int*)  alloc(N_ * 4);
  int*   ince  = (int*)  alloc((size_t)NENT_ * 4);
  float* incv  = (float*)alloc((size_t)NENT_ * 4);
  float* va    = (float*)alloc(N_ * 4);
  float* ua    = (float*)alloc(N_ * 4);
  float* vbuf  = (float*)alloc(N_ * 4);
  float* ubuf  = (float*)alloc(N_ * 4);
  float* yev   = (float*)alloc(E_ * 4);
  float* part  = (float*)alloc((N_ / 256) * 2 * 4);
  float* scal  = (float*)alloc(256);
  int SPLITK = 8;
  while (SPLITK > 1 && o + (size_t)SPLITK * N_ * D_ * 4 > ws_size) SPLITK >>= 1;
  float* Zpart = (float*)alloc((size_t)SPLITK * N_ * D_ * 4);
  const int kchunk = N_ / SPLITK;
  // phase-2 temporaries alias into S (dead after the k-loop)
  float* U    = S;
  float* Ye   = S + (size_t)N_ * D_;
  float* T1   = Ye + (size_t)E_ * D_;
  float* T2   = T1 + (size_t)N_ * D_;
  float* Zmix = T2 + (size_t)N_ * D_;

  scalars_kernel<<<1, 64, 0, stream>>>(alpha, rho_raw, scal);
  hipMemsetAsync(Zpart, 0, (size_t)SPLITK * N_ * D_ * 4, stream);
  hipMemsetAsync(DvAcc, 0, N_ * 4, stream);
  hipMemsetAsync(cnt, 0, N_ * 4, stream);

  // one-time bf16 splits of X (row-major and transposed)
  cvt_split4<<<(N_ * D_ / 4) / 256, 256, 0, stream>>>(X, Xh, Xl);
  transpose_split<<<dim3(D_ / 32, N_ / 32), 256, 0, stream>>>(X, XhT, XlT);

  for (int k = 0; k < K_; ++k) {
    gemm_nn64_split<<<dim3(N_ / 64, D_ / 64), 256, 0, stream>>>(
        X, L_k + (size_t)k * D_ * D_, XLh, XLl, D_, D_, D_, D_);
    scores_mfma<<<dim3(N_ / 128, N_ / 128), 256, 0, stream>>>(
        XLh, XLl, Xh, Xl, S, 1.0f / 16.0f);  // 1/sqrt(256)
    rowstats_topk<<<N_, 256, 0, stream>>>(
        S, rowmax, rowZ, tkv + (size_t)k * N_ * TK_, tki + (size_t)k * N_ * TK_);
    zkern_mfma<<<dim3(N_ / 128, D_ / 128, SPLITK), 256, 0, stream>>>(
        S, rowmax, rowZ, XhT, XlT, Zpart, scal, k, kchunk);
  }

  edge_scan<<<E_ / 256, 256, 0, stream>>>(tkv, tki, DvAcc, cnt, invDe);
  dvis_kernel<<<N_ / 256, 256, 0, stream>>>(DvAcc, Dvis);
  scan_offsets<<<1, 1024, 0, stream>>>(cnt, off, cur);
  edge_fill<<<E_ / 256, 256, 0, stream>>>(tkv, tki, cur, ince, incv);

  pi_init<<<N_ / 256, 256, 0, stream>>>(v0, Dvis, va, ua);
  float* vc = va; float* uc = ua; float* vn = vbuf; float* un = ubuf;
  for (int it = 0; it < 5; ++it) {
    pi_ye<<<E_ / 256, 256, 0, stream>>>(uc, tkv, tki, invDe, yev);
    pi_step<<<N_ / 256, 256, 0, stream>>>(vc, yev, off, ince, incv, Dvis, vn, un);
    float* tv = vc; vc = vn; vn = tv;
    float* tu = uc; uc = un; un = tu;
  }
  pi_ye<<<E_ / 256, 256, 0, stream>>>(uc, tkv, tki, invDe, yev);
  pi_final<<<N_ / 256, 256, 0, stream>>>(vc, yev, off, ince, incv, Dvis, part);
  pi_lam<<<1, 64, 0, stream>>>(part, scal);

  // T1 = Lt @ X
  ew_scale<<<N_ * D_ / 256, 256, 0, stream>>>(X, Dvis, U);
  ye_mat<<<E_, 256, 0, stream>>>(U, tkv, tki, invDe, Ye);
  bgather_combine<<<N_, 256, 0, stream>>>(Ye, off, ince, incv, Dvis, X, X, scal, T1, 1);
  // T2 = 2*Lt @ T1 - X
  ew_scale<<<N_ * D_ / 256, 256, 0, stream>>>(T1, Dvis, U);
  ye_mat<<<E_, 256, 0, stream>>>(U, tkv, tki, invDe, Ye);
  bgather_combine<<<N_, 256, 0, stream>>>(Ye, off, ince, incv, Dvis, T1, X, scal, T2, 2);

  mix_kernel<<<N_ * D_ / 256, 256, 0, stream>>>(X, T1, T2, theta, Zpart, SPLITK, scal, Zmix);

  gemm_nt64_bias<<<dim3(N_ / 64, D_ / 64), 256, 0, stream>>>(
      Zmix, proj_w, proj_b, out, D_, D_, D_, D_);
}

// Round 6
// 1276.124 us; speedup vs baseline: 4.3436x; 1.1353x over previous
//
#include <hip/hip_runtime.h>
#include <math.h>

#define N_ 4096
#define D_ 256
#define K_ 4
#define TK_ 16
#define E_ (K_ * N_)          // 16384 hyperedges
#define NENT_ (E_ * TK_)      // 262144 incidence entries

typedef unsigned short u16;
typedef unsigned int u32;
typedef __attribute__((ext_vector_type(8))) short bf16x8;
typedef __attribute__((ext_vector_type(4))) float f32x4;

__device__ __forceinline__ u16 bf16_rne(float x) {
  u32 u = __float_as_uint(x);
  u32 r = u + 0x7FFFu + ((u >> 16) & 1u);
  return (u16)(r >> 16);
}

// ============================= small kernels =============================

__global__ void scalars_kernel(const float* __restrict__ alpha,
                               const float* __restrict__ rho_raw,
                               float* __restrict__ scal) {
  if (threadIdx.x == 0) {
    float m = alpha[0];
    for (int k = 1; k < K_; ++k) m = fmaxf(m, alpha[k]);
    float e[K_]; float s = 0.f;
    for (int k = 0; k < K_; ++k) { e[k] = expf(alpha[k] - m); s += e[k]; }
    for (int k = 0; k < K_; ++k) scal[k] = e[k] / s;   // w_k
    scal[4] = 1.0f / (1.0f + expf(-rho_raw[0]));       // rho
  }
}

__global__ void dvis_kernel(const float* __restrict__ DvAcc, float* __restrict__ Dvis) {
  int i = blockIdx.x * 256 + threadIdx.x;
  Dvis[i] = 1.0f / sqrtf(DvAcc[i] + 1e-9f);
}

__global__ void ew_scale(const float* __restrict__ M, const float* __restrict__ Dvis,
                         float* __restrict__ U) {
  int i = blockIdx.x * 256 + threadIdx.x;
  U[i] = Dvis[i >> 8] * M[i];
}

// fp32 -> (hi, lo) bf16 split, 4 elems/thread (used for X row-major)
__global__ void cvt_split4(const float* __restrict__ in, u16* __restrict__ hi,
                           u16* __restrict__ lo) {
  int i = (blockIdx.x * 256 + threadIdx.x) * 4;
  float4 v = *(const float4*)(in + i);
  u16 h0 = bf16_rne(v.x), h1 = bf16_rne(v.y), h2 = bf16_rne(v.z), h3 = bf16_rne(v.w);
  float f0 = __uint_as_float((u32)h0 << 16), f1 = __uint_as_float((u32)h1 << 16);
  float f2 = __uint_as_float((u32)h2 << 16), f3 = __uint_as_float((u32)h3 << 16);
  u16 l0 = bf16_rne(v.x - f0), l1 = bf16_rne(v.y - f1);
  u16 l2 = bf16_rne(v.z - f2), l3 = bf16_rne(v.w - f3);
  *(uint2*)(hi + i) = make_uint2((u32)h0 | ((u32)h1 << 16), (u32)h2 | ((u32)h3 << 16));
  *(uint2*)(lo + i) = make_uint2((u32)l0 | ((u32)l1 << 16), (u32)l2 | ((u32)l3 << 16));
}

// X [N][D] fp32 -> XhT/XlT [D][N] bf16 (transposed split). grid (D/32, N/32), 256 thr.
__global__ __launch_bounds__(256) void transpose_split(const float* __restrict__ X,
                                                       u16* __restrict__ ht,
                                                       u16* __restrict__ lt) {
  __shared__ float tile[32][33];
  const int tx = threadIdx.x & 31, ty = threadIdx.x >> 5;  // 32x8
  const int d0 = blockIdx.x * 32, n0 = blockIdx.y * 32;
#pragma unroll
  for (int q = 0; q < 4; ++q)
    tile[ty + q * 8][tx] = X[(size_t)(n0 + ty + q * 8) * D_ + d0 + tx];
  __syncthreads();
#pragma unroll
  for (int q = 0; q < 4; ++q) {
    int dd = ty + q * 8;
    float v = tile[tx][dd];               // = X[n0+tx][d0+dd]
    u16 h = bf16_rne(v);
    float hf = __uint_as_float((u32)h << 16);
    u16 l = bf16_rne(v - hf);
    ht[(size_t)(d0 + dd) * N_ + n0 + tx] = h;
    lt[(size_t)(d0 + dd) * N_ + n0 + tx] = l;
  }
}

// ============================= 64-tile fp32 GEMMs =============================
// XL = X @ L_k, epilogue writes bf16 hi/lo split directly. grid=(N/64, D/64).
__global__ __launch_bounds__(256) void gemm_nn64_split(const float* __restrict__ A,
                                                       const float* __restrict__ B,
                                                       u16* __restrict__ Ch,
                                                       u16* __restrict__ Cl,
                                                       int Kdim, int lda, int ldb, int ldc) {
  __shared__ float As[16][68];
  __shared__ float Bs[16][68];
  const int tid = threadIdx.x;
  const int bm = blockIdx.x * 64, bn = blockIdx.y * 64;
  const int lrA = tid >> 2, lcA = (tid & 3) * 4;
  const int rrB = tid >> 4, ccB = (tid & 15) * 4;
  const int tx = tid & 15, ty = tid >> 4;
  const float* Ap = A + (size_t)(bm + lrA) * lda + lcA;
  const float* Bp = B + (size_t)rrB * ldb + bn + ccB;
  float acc[4][4] = {};
  for (int k0 = 0; k0 < Kdim; k0 += 16) {
    float4 av = *(const float4*)(Ap + k0);
    float4 bv = *(const float4*)(Bp + (size_t)k0 * ldb);
    __syncthreads();
    As[lcA + 0][lrA] = av.x; As[lcA + 1][lrA] = av.y;
    As[lcA + 2][lrA] = av.z; As[lcA + 3][lrA] = av.w;
    *(float4*)&Bs[rrB][ccB] = bv;
    __syncthreads();
#pragma unroll
    for (int kk = 0; kk < 16; ++kk) {
      float a[4], b[4];
      *(float4*)a = *(const float4*)&As[kk][ty * 4];
      *(float4*)b = *(const float4*)&Bs[kk][tx * 4];
#pragma unroll
      for (int i = 0; i < 4; ++i)
#pragma unroll
        for (int j = 0; j < 4; ++j) acc[i][j] += a[i] * b[j];
    }
  }
#pragma unroll
  for (int i = 0; i < 4; ++i) {
    int row = bm + ty * 4 + i;
    u16 h[4], lo[4];
#pragma unroll
    for (int j = 0; j < 4; ++j) {
      h[j] = bf16_rne(acc[i][j]);
      lo[j] = bf16_rne(acc[i][j] - __uint_as_float((u32)h[j] << 16));
    }
    size_t base = (size_t)row * ldc + bn + tx * 4;
    *(uint2*)(Ch + base) = make_uint2((u32)h[0] | ((u32)h[1] << 16), (u32)h[2] | ((u32)h[3] << 16));
    *(uint2*)(Cl + base) = make_uint2((u32)lo[0] | ((u32)lo[1] << 16), (u32)lo[2] | ((u32)lo[3] << 16));
  }
}

// C(MxN) = A(MxK) @ B(NxK)^T + bias, row-major. grid=(M/64, N/64).
__global__ __launch_bounds__(256) void gemm_nt64_bias(const float* __restrict__ A,
                                                      const float* __restrict__ B,
                                                      const float* __restrict__ bias,
                                                      float* __restrict__ C,
                                                      int Kdim, int lda, int ldb, int ldc) {
  __shared__ float As[16][68];
  __shared__ float Bs[16][68];
  const int tid = threadIdx.x;
  const int bm = blockIdx.x * 64, bn = blockIdx.y * 64;
  const int lr = tid >> 2, lc = (tid & 3) * 4;
  const int tx = tid & 15, ty = tid >> 4;
  const float* Ap = A + (size_t)(bm + lr) * lda + lc;
  const float* Bp = B + (size_t)(bn + lr) * ldb + lc;
  float acc[4][4] = {};
  for (int k0 = 0; k0 < Kdim; k0 += 16) {
    float4 av = *(const float4*)(Ap + k0);
    float4 bv = *(const float4*)(Bp + k0);
    __syncthreads();
    As[lc + 0][lr] = av.x; As[lc + 1][lr] = av.y; As[lc + 2][lr] = av.z; As[lc + 3][lr] = av.w;
    Bs[lc + 0][lr] = bv.x; Bs[lc + 1][lr] = bv.y; Bs[lc + 2][lr] = bv.z; Bs[lc + 3][lr] = bv.w;
    __syncthreads();
#pragma unroll
    for (int kk = 0; kk < 16; ++kk) {
      float a[4], b[4];
      *(float4*)a = *(const float4*)&As[kk][ty * 4];
      *(float4*)b = *(const float4*)&Bs[kk][tx * 4];
#pragma unroll
      for (int i = 0; i < 4; ++i)
#pragma unroll
        for (int j = 0; j < 4; ++j) acc[i][j] += a[i] * b[j];
    }
  }
#pragma unroll
  for (int i = 0; i < 4; ++i) {
    int row = bm + ty * 4 + i;
    float4 o;
    o.x = acc[i][0] + bias[bn + tx * 4 + 0];
    o.y = acc[i][1] + bias[bn + tx * 4 + 1];
    o.z = acc[i][2] + bias[bn + tx * 4 + 2];
    o.w = acc[i][3] + bias[bn + tx * 4 + 3];
    *(float4*)(C + (size_t)row * ldc + bn + tx * 4) = o;
  }
}

// ===================== MFMA bf16-split GEMMs (3-pass hi/lo) =====================
// Double-buffered A tile in LDS (2 x {hi,lo} x [128][64] bf16 = 64 KB), XOR-swizzled
// (byte ^= (row&7)<<4). One barrier per K-chunk: prefetch chunk c+1 global loads
// BEFORE the MFMA phase on chunk c (latency hides under 96 MFMAs), exp/split+LDS
// write of c+1 after. B fragments load directly from global (L2-resident).

// S(4096x4096) = (Ah+Al)(Bh+Bl)^T * scale. grid (32,32).
__global__ __launch_bounds__(256) void scores_mfma(const u16* __restrict__ Ahg,
                                                   const u16* __restrict__ Alg,
                                                   const u16* __restrict__ Bhg,
                                                   const u16* __restrict__ Blg,
                                                   float* __restrict__ C, float scale) {
  __shared__ char smem[65536];
  const int tid = threadIdx.x;
  const int bm = blockIdx.x * 128, bn = blockIdx.y * 128;
  const int w = tid >> 6, l = tid & 63;
  const int wr = (w >> 1) * 64, wc = (w & 1) * 64;
  const int srow = tid >> 3, scol = (tid & 7) * 8;
  const int lb = l & 15, lke = (l >> 4) * 8;   // lane row-in-frag, k elem offset
  const u16* bh0 = Bhg + (size_t)(bn + wc + 0  + lb) * D_ + lke;
  const u16* bh1 = Bhg + (size_t)(bn + wc + 16 + lb) * D_ + lke;
  const u16* bh2 = Bhg + (size_t)(bn + wc + 32 + lb) * D_ + lke;
  const u16* bh3 = Bhg + (size_t)(bn + wc + 48 + lb) * D_ + lke;
  const size_t dlo = (size_t)(Blg - Bhg);
  const int aoff[4] = {
    (srow + 0)  * 128 + ((scol * 2) ^ (((srow + 0)  & 7) << 4)),
    (srow + 32) * 128 + ((scol * 2) ^ (((srow + 32) & 7) << 4)),
    (srow + 64) * 128 + ((scol * 2) ^ (((srow + 64) & 7) << 4)),
    (srow + 96) * 128 + ((scol * 2) ^ (((srow + 96) & 7) << 4)) };
  f32x4 acc[4][4];
#pragma unroll
  for (int i = 0; i < 4; ++i)
#pragma unroll
    for (int j = 0; j < 4; ++j) { acc[i][j][0] = 0.f; acc[i][j][1] = 0.f; acc[i][j][2] = 0.f; acc[i][j][3] = 0.f; }

  // prologue: chunk 0 -> buf0
  uint4 ah[4], al[4];
#pragma unroll
  for (int ii = 0; ii < 4; ++ii) {
    int r = srow + ii * 32;
    ah[ii] = *(const uint4*)(Ahg + (size_t)(bm + r) * D_ + scol);
    al[ii] = *(const uint4*)(Alg + (size_t)(bm + r) * D_ + scol);
  }
  {
    char* bAh = smem; char* bAl = smem + 16384;
#pragma unroll
    for (int ii = 0; ii < 4; ++ii) {
      *(uint4*)(bAh + aoff[ii]) = ah[ii];
      *(uint4*)(bAl + aoff[ii]) = al[ii];
    }
  }
  __syncthreads();

  for (int c = 0; c < 4; ++c) {
    char* bAh = smem + ((c & 1) << 15);
    char* bAl = bAh + 16384;
    const bool hn = (c < 3);
    if (hn) {
      const int kn = (c + 1) * 64;
#pragma unroll
      for (int ii = 0; ii < 4; ++ii) {
        int r = srow + ii * 32;
        ah[ii] = *(const uint4*)(Ahg + (size_t)(bm + r) * D_ + kn + scol);
        al[ii] = *(const uint4*)(Alg + (size_t)(bm + r) * D_ + kn + scol);
      }
    }
#pragma unroll
    for (int kk = 0; kk < 2; ++kk) {
      const int kb = kk * 64 + ((l >> 4) << 4);
      const int ge = c * 64 + kk * 32;
      bf16x8 fbh[4], fbl[4];
      fbh[0] = *(const bf16x8*)(bh0 + ge); fbl[0] = *(const bf16x8*)(bh0 + dlo + ge);
      fbh[1] = *(const bf16x8*)(bh1 + ge); fbl[1] = *(const bf16x8*)(bh1 + dlo + ge);
      fbh[2] = *(const bf16x8*)(bh2 + ge); fbl[2] = *(const bf16x8*)(bh2 + dlo + ge);
      fbh[3] = *(const bf16x8*)(bh3 + ge); fbl[3] = *(const bf16x8*)(bh3 + dlo + ge);
#pragma unroll
      for (int i = 0; i < 4; ++i) {
        int ra = wr + i * 16 + lb;
        int oa = ra * 128 + (kb ^ ((ra & 7) << 4));
        bf16x8 fah = *(const bf16x8*)(bAh + oa);
        bf16x8 fal = *(const bf16x8*)(bAl + oa);
#pragma unroll
        for (int j = 0; j < 4; ++j) {
          acc[i][j] = __builtin_amdgcn_mfma_f32_16x16x32_bf16(fah, fbh[j], acc[i][j], 0, 0, 0);
          acc[i][j] = __builtin_amdgcn_mfma_f32_16x16x32_bf16(fah, fbl[j], acc[i][j], 0, 0, 0);
          acc[i][j] = __builtin_amdgcn_mfma_f32_16x16x32_bf16(fal, fbh[j], acc[i][j], 0, 0, 0);
        }
      }
    }
    if (hn) {
      char* nAh = smem + (((c + 1) & 1) << 15);
      char* nAl = nAh + 16384;
#pragma unroll
      for (int ii = 0; ii < 4; ++ii) {
        *(uint4*)(nAh + aoff[ii]) = ah[ii];
        *(uint4*)(nAl + aoff[ii]) = al[ii];
      }
    }
    __syncthreads();
  }
  // epilogue: two 64-row rounds through LDS (64 x 128 f32), coalesced stores
  float* Cs = (float*)smem;
  const int cr = (l >> 4) * 4, cc = l & 15;
#pragma unroll
  for (int p = 0; p < 2; ++p) {
    __syncthreads();
    if ((w >> 1) == p) {
#pragma unroll
      for (int i = 0; i < 4; ++i)
#pragma unroll
        for (int r = 0; r < 4; ++r) {
          int rl = i * 16 + cr + r;
          int sw = ((rl >> 2) & 3) << 4;
#pragma unroll
          for (int j = 0; j < 4; ++j) {
            int cl = wc + j * 16 + cc;
            Cs[rl * 128 + (cl ^ sw)] = acc[i][j][r] * scale;
          }
        }
    }
    __syncthreads();
#pragma unroll
    for (int ii = 0; ii < 8; ++ii) {
      int rl = ii * 8 + (tid >> 5);
      int c4 = (tid & 31) * 4;
      float4 v = *(float4*)&Cs[rl * 128 + (c4 ^ (((rl >> 2) & 3) << 4))];
      *(float4*)(C + (size_t)(bm + p * 64 + rl) * N_ + bn + c4) = v;
    }
  }
}

// Zpart[kz] += (w_k/rowZ[m]) * exp(S-rowmax) @ X ; A staged from S with exp+split,
// B fragments direct from XhT/XlT [256][4096]. grid (32, 2, SPLITK).
__global__ __launch_bounds__(256) void zkern_mfma(const float* __restrict__ S,
                                                  const float* __restrict__ rowmax,
                                                  const float* __restrict__ rowZ,
                                                  const u16* __restrict__ BhT,
                                                  const u16* __restrict__ BlT,
                                                  float* __restrict__ Zpart,
                                                  const float* __restrict__ scal,
                                                  int kidx, int kchunk) {
  __shared__ char smem[65536];
  const int tid = threadIdx.x;
  const int bm = blockIdx.x * 128, bn = blockIdx.y * 128;
  const int kz = blockIdx.z;
  const int w = tid >> 6, l = tid & 63;
  const int wr = (w >> 1) * 64, wc = (w & 1) * 64;
  const int arow = tid >> 4, acol = (tid & 15) * 4;
  const int lb = l & 15, lke = (l >> 4) * 8;
  const u16* bh0 = BhT + (size_t)(bn + wc + 0  + lb) * N_ + lke;
  const u16* bh1 = BhT + (size_t)(bn + wc + 16 + lb) * N_ + lke;
  const u16* bh2 = BhT + (size_t)(bn + wc + 32 + lb) * N_ + lke;
  const u16* bh3 = BhT + (size_t)(bn + wc + 48 + lb) * N_ + lke;
  const size_t dlo = (size_t)(BlT - BhT);
  float rm[8];
  int aoff[8];
#pragma unroll
  for (int ii = 0; ii < 8; ++ii) {
    int r = arow + ii * 16;
    rm[ii] = rowmax[bm + r];
    aoff[ii] = r * 128 + ((acol * 2) ^ ((r & 7) << 4));
  }
  f32x4 acc[4][4];
#pragma unroll
  for (int i = 0; i < 4; ++i)
#pragma unroll
    for (int j = 0; j < 4; ++j) { acc[i][j][0] = 0.f; acc[i][j][1] = 0.f; acc[i][j][2] = 0.f; acc[i][j][3] = 0.f; }

  const int nchunk = kchunk >> 6;
  const int kbase = kz * kchunk;

  // helper lambdas would obscure; inline prologue: chunk 0
  float4 sv[8];
#pragma unroll
  for (int ii = 0; ii < 8; ++ii)
    sv[ii] = *(const float4*)(S + (size_t)(bm + arow + ii * 16) * N_ + kbase + acol);
  {
    char* bAh = smem; char* bAl = smem + 16384;
#pragma unroll
    for (int ii = 0; ii < 8; ++ii) {
      float e0 = expf(sv[ii].x - rm[ii]), e1 = expf(sv[ii].y - rm[ii]);
      float e2 = expf(sv[ii].z - rm[ii]), e3 = expf(sv[ii].w - rm[ii]);
      u16 h0 = bf16_rne(e0), h1 = bf16_rne(e1), h2 = bf16_rne(e2), h3 = bf16_rne(e3);
      u16 l0 = bf16_rne(e0 - __uint_as_float((u32)h0 << 16));
      u16 l1 = bf16_rne(e1 - __uint_as_float((u32)h1 << 16));
      u16 l2 = bf16_rne(e2 - __uint_as_float((u32)h2 << 16));
      u16 l3 = bf16_rne(e3 - __uint_as_float((u32)h3 << 16));
      *(uint2*)(bAh + aoff[ii]) = make_uint2((u32)h0 | ((u32)h1 << 16), (u32)h2 | ((u32)h3 << 16));
      *(uint2*)(bAl + aoff[ii]) = make_uint2((u32)l0 | ((u32)l1 << 16), (u32)l2 | ((u32)l3 << 16));
    }
  }
  __syncthreads();

  for (int c = 0; c < nchunk; ++c) {
    char* bAh = smem + ((c & 1) << 15);
    char* bAl = bAh + 16384;
    const bool hn = (c + 1 < nchunk);
    if (hn) {
      const int kn = kbase + (c + 1) * 64;
#pragma unroll
      for (int ii = 0; ii < 8; ++ii)
        sv[ii] = *(const float4*)(S + (size_t)(bm + arow + ii * 16) * N_ + kn + acol);
    }
#pragma unroll
    for (int kk = 0; kk < 2; ++kk) {
      const int kb = kk * 64 + ((l >> 4) << 4);
      const int ge = kbase + c * 64 + kk * 32;
      bf16x8 fbh[4], fbl[4];
      fbh[0] = *(const bf16x8*)(bh0 + ge); fbl[0] = *(const bf16x8*)(bh0 + dlo + ge);
      fbh[1] = *(const bf16x8*)(bh1 + ge); fbl[1] = *(const bf16x8*)(bh1 + dlo + ge);
      fbh[2] = *(const bf16x8*)(bh2 + ge); fbl[2] = *(const bf16x8*)(bh2 + dlo + ge);
      fbh[3] = *(const bf16x8*)(bh3 + ge); fbl[3] = *(const bf16x8*)(bh3 + dlo + ge);
#pragma unroll
      for (int i = 0; i < 4; ++i) {
        int ra = wr + i * 16 + lb;
        int oa = ra * 128 + (kb ^ ((ra & 7) << 4));
        bf16x8 fah = *(const bf16x8*)(bAh + oa);
        bf16x8 fal = *(const bf16x8*)(bAl + oa);
#pragma unroll
        for (int j = 0; j < 4; ++j) {
          acc[i][j] = __builtin_amdgcn_mfma_f32_16x16x32_bf16(fah, fbh[j], acc[i][j], 0, 0, 0);
          acc[i][j] = __builtin_amdgcn_mfma_f32_16x16x32_bf16(fah, fbl[j], acc[i][j], 0, 0, 0);
          acc[i][j] = __builtin_amdgcn_mfma_f32_16x16x32_bf16(fal, fbh[j], acc[i][j], 0, 0, 0);
        }
      }
    }
    if (hn) {
      char* nAh = smem + (((c + 1) & 1) << 15);
      char* nAl = nAh + 16384;
#pragma unroll
      for (int ii = 0; ii < 8; ++ii) {
        float e0 = expf(sv[ii].x - rm[ii]), e1 = expf(sv[ii].y - rm[ii]);
        float e2 = expf(sv[ii].z - rm[ii]), e3 = expf(sv[ii].w - rm[ii]);
        u16 h0 = bf16_rne(e0), h1 = bf16_rne(e1), h2 = bf16_rne(e2), h3 = bf16_rne(e3);
        u16 l0 = bf16_rne(e0 - __uint_as_float((u32)h0 << 16));
        u16 l1 = bf16_rne(e1 - __uint_as_float((u32)h1 << 16));
        u16 l2 = bf16_rne(e2 - __uint_as_float((u32)h2 << 16));
        u16 l3 = bf16_rne(e3 - __uint_as_float((u32)h3 << 16));
        *(uint2*)(nAh + aoff[ii]) = make_uint2((u32)h0 | ((u32)h1 << 16), (u32)h2 | ((u32)h3 << 16));
        *(uint2*)(nAl + aoff[ii]) = make_uint2((u32)l0 | ((u32)l1 << 16), (u32)l2 | ((u32)l3 << 16));
      }
    }
    __syncthreads();
  }
  // epilogue: LDS transpose rounds + coalesced float4 RMW of Zpart
  const float wk = scal[kidx];
  float* Zp = Zpart + (size_t)kz * N_ * D_;
  float* Cs = (float*)smem;
  const int cr = (l >> 4) * 4, cc = l & 15;
#pragma unroll
  for (int p = 0; p < 2; ++p) {
    __syncthreads();
    if ((w >> 1) == p) {
#pragma unroll
      for (int i = 0; i < 4; ++i)
#pragma unroll
        for (int r = 0; r < 4; ++r) {
          int rl = i * 16 + cr + r;
          int sw = ((rl >> 2) & 3) << 4;
#pragma unroll
          for (int j = 0; j < 4; ++j) {
            int cl = wc + j * 16 + cc;
            Cs[rl * 128 + (cl ^ sw)] = acc[i][j][r];
          }
        }
    }
    __syncthreads();
#pragma unroll
    for (int ii = 0; ii < 8; ++ii) {
      int rl = ii * 8 + (tid >> 5);
      int c4 = (tid & 31) * 4;
      int row = bm + p * 64 + rl;
      float sc = wk / rowZ[row];
      float4 v = *(float4*)&Cs[rl * 128 + (c4 ^ (((rl >> 2) & 3) << 4))];
      float* zb = Zp + (size_t)row * D_ + bn + c4;
      float4 z = *(float4*)zb;
      z.x += sc * v.x; z.y += sc * v.y; z.z += sc * v.z; z.w += sc * v.w;
      *(float4*)zb = z;
    }
  }
}

// ======================= per-row stats + histogram top-16 =======================
__global__ __launch_bounds__(256) void rowstats_topk(const float* __restrict__ S,
                                                     float* __restrict__ rowmax,
                                                     float* __restrict__ rowZ,
                                                     float* __restrict__ tkv,
                                                     int* __restrict__ tki) {
  const int row = blockIdx.x, tid = threadIdx.x;
  const int wid = tid >> 6, lane = tid & 63;
  __shared__ int hist[1024];
  __shared__ int P[256];
  __shared__ float cval[256];
  __shared__ int cgi[256];
  __shared__ int ccnt;
  __shared__ int binlo_s;
  __shared__ float rv[4];
  __shared__ float stk[TK_];
  __shared__ int itk[TK_];
  __shared__ float tv16[TK_];
  __shared__ float mzs[3];

  hist[tid] = 0; hist[tid + 256] = 0; hist[tid + 512] = 0; hist[tid + 768] = 0;
  if (tid == 0) ccnt = 0;

  const float4* Sp = (const float4*)(S + (size_t)row * N_);
  float r[16];
  float lmax = -3.4e38f;
#pragma unroll
  for (int it = 0; it < 4; ++it) {
    float4 v = Sp[tid + it * 256];
    r[it * 4 + 0] = v.x; r[it * 4 + 1] = v.y; r[it * 4 + 2] = v.z; r[it * 4 + 3] = v.w;
    lmax = fmaxf(lmax, fmaxf(fmaxf(v.x, v.y), fmaxf(v.z, v.w)));
  }
#pragma unroll
  for (int off = 32; off; off >>= 1) lmax = fmaxf(lmax, __shfl_xor(lmax, off));
  if (lane == 0) rv[wid] = lmax;
  __syncthreads();
  if (tid == 0) mzs[0] = fmaxf(fmaxf(rv[0], rv[1]), fmaxf(rv[2], rv[3]));
  __syncthreads();
  const float M = mzs[0];
  float ls = 0.f;
#pragma unroll
  for (int j = 0; j < 16; ++j) ls += expf(r[j] - M);
#pragma unroll
  for (int off = 32; off; off >>= 1) ls += __shfl_xor(ls, off);
  if (lane == 0) rv[wid] = ls;
  __syncthreads();
  if (tid == 0) {
    float z = rv[0] + rv[1] + rv[2] + rv[3];
    mzs[1] = z; rowmax[row] = M; rowZ[row] = z;
  }
  __syncthreads();
  const float Z = mzs[1];

#pragma unroll
  for (int j = 0; j < 16; ++j) {
    u32 u = __float_as_uint(r[j]);
    u32 key = (u >> 31) ? ~u : (u | 0x80000000u);
    atomicAdd(&hist[key >> 22], 1);
  }
  __syncthreads();
  const int b0 = tid * 4;
  const int h0 = hist[b0], h1 = hist[b0 + 1], h2 = hist[b0 + 2], h3 = hist[b0 + 3];
  P[tid] = h0 + h1 + h2 + h3;
  __syncthreads();
  for (int o = 1; o < 256; o <<= 1) {
    int v = P[tid] + ((tid + o < 256) ? P[tid + o] : 0);
    __syncthreads();
    P[tid] = v;
    __syncthreads();
  }
  {
    int above = (tid < 255) ? P[tid + 1] : 0;
    int s3 = above + h3, s2 = s3 + h2, s1 = s2 + h1, s0 = s1 + h0;
    if (s3 >= TK_ && above < TK_) binlo_s = b0 + 3;
    else if (s2 >= TK_ && s3 < TK_) binlo_s = b0 + 2;
    else if (s1 >= TK_ && s2 < TK_) binlo_s = b0 + 1;
    else if (s0 >= TK_ && s1 < TK_) binlo_s = b0;
  }
  __syncthreads();
  const u32 kmin = (u32)binlo_s << 22;
#pragma unroll
  for (int j = 0; j < 16; ++j) {
    u32 u = __float_as_uint(r[j]);
    u32 key = (u >> 31) ? ~u : (u | 0x80000000u);
    if (key >= kmin) {
      int p = atomicAdd(&ccnt, 1);
      if (p < 256) {
        cval[p] = r[j];
        cgi[p] = 4 * tid + ((j >> 2) << 10) + (j & 3);
      }
    }
  }
  __syncthreads();
  const int nc = min(ccnt, 256);
  for (int t = 0; t < TK_; ++t) {
    if (tid < 64) {
      float bv = -3.4e38f; int bg = 0x7fffffff, bp = -1;
      for (int p = tid; p < nc; p += 64) {
        float v = cval[p]; int g = cgi[p];
        if (v > bv || (v == bv && g < bg)) { bv = v; bg = g; bp = p; }
      }
#pragma unroll
      for (int off = 32; off; off >>= 1) {
        float ov = __shfl_xor(bv, off);
        int og = __shfl_xor(bg, off);
        int op = __shfl_xor(bp, off);
        if (ov > bv || (ov == bv && og < bg)) { bv = ov; bg = og; bp = op; }
      }
      if (tid == 0) { stk[t] = bv; itk[t] = bg; cval[bp] = -3.4e38f; }
    }
    __syncthreads();
  }
  if (tid < TK_) tv16[tid] = expf(stk[tid] - M) / Z;
  __syncthreads();
  if (tid == 0) { float s = 0.f; for (int q = 0; q < TK_; ++q) s += tv16[q]; mzs[2] = s + 1e-9f; }
  __syncthreads();
  if (tid < TK_) {
    tkv[(size_t)row * TK_ + tid] = tv16[tid] / mzs[2];
    tki[(size_t)row * TK_ + tid] = itk[tid];
  }
}

// ======================= hypergraph build =======================
__global__ void edge_scan(const float* __restrict__ tkv, const int* __restrict__ tki,
                          float* __restrict__ DvAcc, int* __restrict__ cnt,
                          float* __restrict__ invDe) {
  int e = blockIdx.x * 256 + threadIdx.x;
  float s = 0.f;
#pragma unroll
  for (int q = 0; q < TK_; ++q) s += tkv[(size_t)e * TK_ + q];
  invDe[e] = 1.0f / (s + 1e-9f);
#pragma unroll
  for (int q = 0; q < TK_; ++q) {
    int m = tki[(size_t)e * TK_ + q];
    atomicAdd(&DvAcc[m], tkv[(size_t)e * TK_ + q]);
    atomicAdd(&cnt[m], 1);
  }
}

__global__ __launch_bounds__(1024) void scan_offsets(const int* __restrict__ cnt,
                                                     int* __restrict__ off,
                                                     int* __restrict__ cur) {
  __shared__ int part[1024];
  const int t = threadIdx.x;
  const int b = t * 4;
  int c0 = cnt[b], c1 = cnt[b + 1], c2 = cnt[b + 2], c3 = cnt[b + 3];
  part[t] = c0 + c1 + c2 + c3;
  __syncthreads();
  for (int o = 1; o < 1024; o <<= 1) {
    int v = part[t] + ((t >= o) ? part[t - o] : 0);
    __syncthreads();
    part[t] = v;
    __syncthreads();
  }
  int ex = (t == 0) ? 0 : part[t - 1];
  off[b] = ex; off[b + 1] = ex + c0; off[b + 2] = ex + c0 + c1; off[b + 3] = ex + c0 + c1 + c2;
  cur[b] = off[b]; cur[b + 1] = off[b + 1]; cur[b + 2] = off[b + 2]; cur[b + 3] = off[b + 3];
  if (t == 1023) off[N_] = part[1023];
}

__global__ void edge_fill(const float* __restrict__ tkv, const int* __restrict__ tki,
                          int* __restrict__ cur, int* __restrict__ ince,
                          float* __restrict__ incv) {
  int e = blockIdx.x * 256 + threadIdx.x;
#pragma unroll
  for (int q = 0; q < TK_; ++q) {
    int m = tki[(size_t)e * TK_ + q];
    int pos = atomicAdd(&cur[m], 1);
    ince[pos] = e;
    incv[pos] = tkv[(size_t)e * TK_ + q];
  }
}

// ======================= power iteration (multi-kernel, unnormalized) ==========
__global__ void pi_init(const float* __restrict__ v0, const float* __restrict__ Dvis,
                        float* __restrict__ v, float* __restrict__ u) {
  int i = blockIdx.x * 256 + threadIdx.x;
  float x = v0[i];
  v[i] = x; u[i] = Dvis[i] * x;
}

__global__ void pi_ye(const float* __restrict__ u, const float* __restrict__ tkv,
                      const int* __restrict__ tki, const float* __restrict__ invDe,
                      float* __restrict__ ye) {
  int e = blockIdx.x * 256 + threadIdx.x;
  const float* tv = tkv + (size_t)e * TK_;
  const int* ti = tki + (size_t)e * TK_;
  float a = 0.f;
#pragma unroll
  for (int q = 0; q < TK_; ++q) a += tv[q] * u[ti[q]];
  ye[e] = a * invDe[e];
}

__global__ void pi_step(const float* __restrict__ v, const float* __restrict__ ye,
                        const int* __restrict__ off, const int* __restrict__ ince,
                        const float* __restrict__ incv, const float* __restrict__ Dvis,
                        float* __restrict__ vn, float* __restrict__ un) {
  int m = blockIdx.x * 256 + threadIdx.x;
  float z = 0.f;
  int j0 = off[m], j1 = off[m + 1];
  for (int j = j0; j < j1; ++j) z += incv[j] * ye[ince[j]];
  float wv = v[m] - Dvis[m] * z;
  vn[m] = wv; un[m] = Dvis[m] * wv;
}

__global__ __launch_bounds__(256) void pi_final(const float* __restrict__ v,
                                                const float* __restrict__ ye,
                                                const int* __restrict__ off,
                                                const int* __restrict__ ince,
                                                const float* __restrict__ incv,
                                                const float* __restrict__ Dvis,
                                                float* __restrict__ partial) {
  __shared__ float r1[256], r2[256];
  int m = blockIdx.x * 256 + threadIdx.x;
  float z = 0.f;
  int j0 = off[m], j1 = off[m + 1];
  for (int j = j0; j < j1; ++j) z += incv[j] * ye[ince[j]];
  float wv = v[m] - Dvis[m] * z;
  r1[threadIdx.x] = v[m] * wv;
  r2[threadIdx.x] = v[m] * v[m];
  __syncthreads();
  for (int s = 128; s; s >>= 1) {
    if (threadIdx.x < s) { r1[threadIdx.x] += r1[threadIdx.x + s]; r2[threadIdx.x] += r2[threadIdx.x + s]; }
    __syncthreads();
  }
  if (threadIdx.x == 0) { partial[blockIdx.x * 2] = r1[0]; partial[blockIdx.x * 2 + 1] = r2[0]; }
}

__global__ void pi_lam(const float* __restrict__ partial, float* __restrict__ scal) {
  if (threadIdx.x == 0) {
    float s1 = 0.f, s2 = 0.f;
    for (int b = 0; b < N_ / 256; ++b) { s1 += partial[2 * b]; s2 += partial[2 * b + 1]; }
    scal[5] = fmaxf(s1 / s2, 1e-3f);
  }
}

// ======================= Chebyshev sparse applies =======================
__global__ __launch_bounds__(256) void ye_mat(const float* __restrict__ U,
                                              const float* __restrict__ tkv,
                                              const int* __restrict__ tki,
                                              const float* __restrict__ invDe,
                                              float* __restrict__ Ye) {
  const int e = blockIdx.x, d = threadIdx.x;
  __shared__ float sv[TK_];
  __shared__ int si[TK_];
  if (d < TK_) { sv[d] = tkv[(size_t)e * TK_ + d]; si[d] = tki[(size_t)e * TK_ + d]; }
  __syncthreads();
  float a = 0.f;
#pragma unroll
  for (int q = 0; q < TK_; ++q) a += sv[q] * U[(size_t)si[q] * D_ + d];
  Ye[(size_t)e * D_ + d] = a * invDe[e];
}

__global__ __launch_bounds__(256) void bgather_combine(const float* __restrict__ Ye,
                                                       const int* __restrict__ off,
                                                       const int* __restrict__ ince,
                                                       const float* __restrict__ incv,
                                                       const float* __restrict__ Dvis,
                                                       const float* __restrict__ Mx,
                                                       const float* __restrict__ G,
                                                       const float* __restrict__ scal,
                                                       float* __restrict__ out, int mode) {
  const int m = blockIdx.x, d = threadIdx.x;
  const int j0 = off[m], j1 = off[m + 1];
  float z = 0.f;
  for (int j = j0; j < j1; ++j) z += incv[j] * Ye[(size_t)ince[j] * D_ + d];
  const float lam = scal[5];
  const float c = 2.0f / lam;
  const size_t idx = (size_t)m * D_ + d;
  const float zz = Dvis[m] * z;
  float r;
  if (mode == 1) r = (c - 1.0f) * Mx[idx] - c * zz;
  else           r = (2.0f * c - 2.0f) * Mx[idx] - 2.0f * c * zz - G[idx];
  out[idx] = r;
}

__global__ void mix_kernel(const float* __restrict__ X, const float* __restrict__ T1,
                           const float* __restrict__ T2, const float* __restrict__ theta,
                           const float* __restrict__ Zpart, int splitk,
                           const float* __restrict__ scal, float* __restrict__ Zmix) {
  const int i = blockIdx.x * 256 + threadIdx.x;
  const int d = i & (D_ - 1);
  float cheb = X[i] * theta[d] + T1[i] * theta[D_ + d] + T2[i] * theta[2 * D_ + d];
  float zs = cheb > 0.f ? cheb : expm1f(cheb);
  float zk = 0.f;
  for (int s = 0; s < splitk; ++s) zk += Zpart[(size_t)s * N_ * D_ + i];
  const float rho = scal[4];
  Zmix[i] = rho * zs + (1.0f - rho) * zk;
}

// ============================= launcher =============================

extern "C" void kernel_launch(void* const* d_in, const int* in_sizes, int n_in,
                              void* d_out, int out_size, void* d_ws, size_t ws_size,
                              hipStream_t stream) {
  const float* X       = (const float*)d_in[0];
  const float* L_k     = (const float*)d_in[1];
  const float* alpha   = (const float*)d_in[2];
  const float* theta   = (const float*)d_in[3];
  const float* rho_raw = (const float*)d_in[4];
  const float* proj_w  = (const float*)d_in[5];
  const float* proj_b  = (const float*)d_in[6];
  const float* v0      = (const float*)d_in[7];
  float* out = (float*)d_out;

  char* w = (char*)d_ws;
  size_t o = 0;
  auto alloc = [&](size_t bytes) -> char* {
    char* p = w + o; o += (bytes + 255) & ~(size_t)255; return p;
  };
  float* S     = (float*)alloc((size_t)N_ * N_ * 4);
  u16*   Xh    = (u16*)  alloc((size_t)N_ * D_ * 2);
  u16*   Xl    = (u16*)  alloc((size_t)N_ * D_ * 2);
  u16*   XhT   = (u16*)  alloc((size_t)D_ * N_ * 2);
  u16*   XlT   = (u16*)  alloc((size_t)D_ * N_ * 2);
  u16*   XLh   = (u16*)  alloc((size_t)N_ * D_ * 2);
  u16*   XLl   = (u16*)  alloc((size_t)N_ * D_ * 2);
  float* rowmax= (float*)alloc(N_ * 4);
  float* rowZ  = (float*)alloc(N_ * 4);
  float* tkv   = (float*)alloc((size_t)NENT_ * 4);
  int*   tki   = (int*)  alloc((size_t)NENT_ * 4);
  float* invDe = (float*)alloc(E_ * 4);
  float* DvAcc = (float*)alloc(N_ * 4);
  float* Dvis  = (float*)alloc(N_ * 4);
  int*   cnt   = (int*)  alloc(N_ * 4);
  int*   off   = (int*)  alloc((N_ + 1) * 4);
  int*   cur   = (int*)  alloc(N_ * 4);
  int*   ince  = (int*)  alloc((size_t)NENT_ * 4);
  float* incv  = (float*)alloc((size_t)NENT_ * 4);
  float* va    = (float*)alloc(N_ * 4);
  float* ua    = (float*)alloc(N_ * 4);
  float* vbuf  = (float*)alloc(N_ * 4);
  float* ubuf  = (float*)alloc(N_ * 4);
  float* yev   = (float*)alloc(E_ * 4);
  float* part  = (float*)alloc((N_ / 256) * 2 * 4);
  float* scal  = (float*)alloc(256);
  int SPLITK = 8;
  while (SPLITK > 1 && o + (size_t)SPLITK * N_ * D_ * 4 > ws_size) SPLITK >>= 1;
  float* Zpart = (float*)alloc((size_t)SPLITK * N_ * D_ * 4);
  const int kchunk = N_ / SPLITK;
  // phase-2 temporaries alias into S (dead after the k-loop)
  float* U    = S;
  float* Ye   = S + (size_t)N_ * D_;
  float* T1   = Ye + (size_t)E_ * D_;
  float* T2   = T1 + (size_t)N_ * D_;
  float* Zmix = T2 + (size_t)N_ * D_;

  scalars_kernel<<<1, 64, 0, stream>>>(alpha, rho_raw, scal);
  hipMemsetAsync(Zpart, 0, (size_t)SPLITK * N_ * D_ * 4, stream);
  hipMemsetAsync(DvAcc, 0, N_ * 4, stream);
  hipMemsetAsync(cnt, 0, N_ * 4, stream);

  // one-time bf16 splits of X (row-major and transposed)
  cvt_split4<<<(N_ * D_ / 4) / 256, 256, 0, stream>>>(X, Xh, Xl);
  transpose_split<<<dim3(D_ / 32, N_ / 32), 256, 0, stream>>>(X, XhT, XlT);

  for (int k = 0; k < K_; ++k) {
    gemm_nn64_split<<<dim3(N_ / 64, D_ / 64), 256, 0, stream>>>(
        X, L_k + (size_t)k * D_ * D_, XLh, XLl, D_, D_, D_, D_);
    scores_mfma<<<dim3(N_ / 128, N_ / 128), 256, 0, stream>>>(
        XLh, XLl, Xh, Xl, S, 1.0f / 16.0f);  // 1/sqrt(256)
    rowstats_topk<<<N_, 256, 0, stream>>>(
        S, rowmax, rowZ, tkv + (size_t)k * N_ * TK_, tki + (size_t)k * N_ * TK_);
    zkern_mfma<<<dim3(N_ / 128, D_ / 128, SPLITK), 256, 0, stream>>>(
        S, rowmax, rowZ, XhT, XlT, Zpart, scal, k, kchunk);
  }

  edge_scan<<<E_ / 256, 256, 0, stream>>>(tkv, tki, DvAcc, cnt, invDe);
  dvis_kernel<<<N_ / 256, 256, 0, stream>>>(DvAcc, Dvis);
  scan_offsets<<<1, 1024, 0, stream>>>(cnt, off, cur);
  edge_fill<<<E_ / 256, 256, 0, stream>>>(tkv, tki, cur, ince, incv);

  pi_init<<<N_ / 256, 256, 0, stream>>>(v0, Dvis, va, ua);
  float* vc = va; float* uc = ua; float* vn = vbuf; float* un = ubuf;
  for (int it = 0; it < 5; ++it) {
    pi_ye<<<E_ / 256, 256, 0, stream>>>(uc, tkv, tki, invDe, yev);
    pi_step<<<N_ / 256, 256, 0, stream>>>(vc, yev, off, ince, incv, Dvis, vn, un);
    float* tv = vc; vc = vn; vn = tv;
    float* tu = uc; uc = un; un = tu;
  }
  pi_ye<<<E_ / 256, 256, 0, stream>>>(uc, tkv, tki, invDe, yev);
  pi_final<<<N_ / 256, 256, 0, stream>>>(vc, yev, off, ince, incv, Dvis, part);
  pi_lam<<<1, 64, 0, stream>>>(part, scal);

  // T1 = Lt @ X
  ew_scale<<<N_ * D_ / 256, 256, 0, stream>>>(X, Dvis, U);
  ye_mat<<<E_, 256, 0, stream>>>(U, tkv, tki, invDe, Ye);
  bgather_combine<<<N_, 256, 0, stream>>>(Ye, off, ince, incv, Dvis, X, X, scal, T1, 1);
  // T2 = 2*Lt @ T1 - X
  ew_scale<<<N_ * D_ / 256, 256, 0, stream>>>(T1, Dvis, U);
  ye_mat<<<E_, 256, 0, stream>>>(U, tkv, tki, invDe, Ye);
  bgather_combine<<<N_, 256, 0, stream>>>(Ye, off, ince, incv, Dvis, T1, X, scal, T2, 2);

  mix_kernel<<<N_ * D_ / 256, 256, 0, stream>>>(X, T1, T2, theta, Zpart, SPLITK, scal, Zmix);

  gemm_nt64_bias<<<dim3(N_ / 64, D_ / 64), 256, 0, stream>>>(
      Zmix, proj_w, proj_b, out, D_, D_, D_, D_);
}

// Round 7
// 1190.799 us; speedup vs baseline: 4.6548x; 1.0717x over previous
//
#include <hip/hip_runtime.h>
#include <math.h>

#define N_ 4096
#define D_ 256
#define K_ 4
#define TK_ 16
#define E_ (K_ * N_)          // 16384 hyperedges
#define NENT_ (E_ * TK_)      // 262144 incidence entries

typedef unsigned short u16;
typedef unsigned int u32;
typedef __attribute__((ext_vector_type(8))) short bf16x8;
typedef __attribute__((ext_vector_type(4))) float f32x4;

__device__ __forceinline__ u16 bf16_rne(float x) {
  u32 u = __float_as_uint(x);
  u32 r = u + 0x7FFFu + ((u >> 16) & 1u);
  return (u16)(r >> 16);
}

// ============================= small kernels =============================

__global__ void scalars_kernel(const float* __restrict__ alpha,
                               const float* __restrict__ rho_raw,
                               float* __restrict__ scal) {
  if (threadIdx.x == 0) {
    float m = alpha[0];
    for (int k = 1; k < K_; ++k) m = fmaxf(m, alpha[k]);
    float e[K_]; float s = 0.f;
    for (int k = 0; k < K_; ++k) { e[k] = expf(alpha[k] - m); s += e[k]; }
    for (int k = 0; k < K_; ++k) scal[k] = e[k] / s;   // w_k
    scal[4] = 1.0f / (1.0f + expf(-rho_raw[0]));       // rho
  }
}

__global__ void dvis_kernel(const float* __restrict__ DvAcc, float* __restrict__ Dvis) {
  int i = blockIdx.x * 256 + threadIdx.x;
  Dvis[i] = 1.0f / sqrtf(DvAcc[i] + 1e-9f);
}

// per-entry weight with right-side Dvis folded in: tkvd = tkv * Dvis[tki]
__global__ void make_tkvd(const float* __restrict__ tkv, const int* __restrict__ tki,
                          const float* __restrict__ Dvis, float* __restrict__ tkvd) {
  int i = blockIdx.x * 256 + threadIdx.x;
  tkvd[i] = tkv[i] * Dvis[tki[i]];
}

// fp32 -> (hi, lo) bf16 split, 4 elems/thread (used for X row-major)
__global__ void cvt_split4(const float* __restrict__ in, u16* __restrict__ hi,
                           u16* __restrict__ lo) {
  int i = (blockIdx.x * 256 + threadIdx.x) * 4;
  float4 v = *(const float4*)(in + i);
  u16 h0 = bf16_rne(v.x), h1 = bf16_rne(v.y), h2 = bf16_rne(v.z), h3 = bf16_rne(v.w);
  float f0 = __uint_as_float((u32)h0 << 16), f1 = __uint_as_float((u32)h1 << 16);
  float f2 = __uint_as_float((u32)h2 << 16), f3 = __uint_as_float((u32)h3 << 16);
  u16 l0 = bf16_rne(v.x - f0), l1 = bf16_rne(v.y - f1);
  u16 l2 = bf16_rne(v.z - f2), l3 = bf16_rne(v.w - f3);
  *(uint2*)(hi + i) = make_uint2((u32)h0 | ((u32)h1 << 16), (u32)h2 | ((u32)h3 << 16));
  *(uint2*)(lo + i) = make_uint2((u32)l0 | ((u32)l1 << 16), (u32)l2 | ((u32)l3 << 16));
}

// X [N][D] fp32 -> XhT/XlT [D][N] bf16 (transposed split). grid (D/32, N/32), 256 thr.
__global__ __launch_bounds__(256) void transpose_split(const float* __restrict__ X,
                                                       u16* __restrict__ ht,
                                                       u16* __restrict__ lt) {
  __shared__ float tile[32][33];
  const int tx = threadIdx.x & 31, ty = threadIdx.x >> 5;  // 32x8
  const int d0 = blockIdx.x * 32, n0 = blockIdx.y * 32;
#pragma unroll
  for (int q = 0; q < 4; ++q)
    tile[ty + q * 8][tx] = X[(size_t)(n0 + ty + q * 8) * D_ + d0 + tx];
  __syncthreads();
#pragma unroll
  for (int q = 0; q < 4; ++q) {
    int dd = ty + q * 8;
    float v = tile[tx][dd];               // = X[n0+tx][d0+dd]
    u16 h = bf16_rne(v);
    float hf = __uint_as_float((u32)h << 16);
    u16 l = bf16_rne(v - hf);
    ht[(size_t)(d0 + dd) * N_ + n0 + tx] = h;
    lt[(size_t)(d0 + dd) * N_ + n0 + tx] = l;
  }
}

// ============================= 64-tile fp32 GEMMs =============================
// XL = X @ L_k, epilogue writes bf16 hi/lo split directly. grid=(N/64, D/64).
__global__ __launch_bounds__(256) void gemm_nn64_split(const float* __restrict__ A,
                                                       const float* __restrict__ B,
                                                       u16* __restrict__ Ch,
                                                       u16* __restrict__ Cl,
                                                       int Kdim, int lda, int ldb, int ldc) {
  __shared__ float As[16][68];
  __shared__ float Bs[16][68];
  const int tid = threadIdx.x;
  const int bm = blockIdx.x * 64, bn = blockIdx.y * 64;
  const int lrA = tid >> 2, lcA = (tid & 3) * 4;
  const int rrB = tid >> 4, ccB = (tid & 15) * 4;
  const int tx = tid & 15, ty = tid >> 4;
  const float* Ap = A + (size_t)(bm + lrA) * lda + lcA;
  const float* Bp = B + (size_t)rrB * ldb + bn + ccB;
  float acc[4][4] = {};
  for (int k0 = 0; k0 < Kdim; k0 += 16) {
    float4 av = *(const float4*)(Ap + k0);
    float4 bv = *(const float4*)(Bp + (size_t)k0 * ldb);
    __syncthreads();
    As[lcA + 0][lrA] = av.x; As[lcA + 1][lrA] = av.y;
    As[lcA + 2][lrA] = av.z; As[lcA + 3][lrA] = av.w;
    *(float4*)&Bs[rrB][ccB] = bv;
    __syncthreads();
#pragma unroll
    for (int kk = 0; kk < 16; ++kk) {
      float a[4], b[4];
      *(float4*)a = *(const float4*)&As[kk][ty * 4];
      *(float4*)b = *(const float4*)&Bs[kk][tx * 4];
#pragma unroll
      for (int i = 0; i < 4; ++i)
#pragma unroll
        for (int j = 0; j < 4; ++j) acc[i][j] += a[i] * b[j];
    }
  }
#pragma unroll
  for (int i = 0; i < 4; ++i) {
    int row = bm + ty * 4 + i;
    u16 h[4], lo[4];
#pragma unroll
    for (int j = 0; j < 4; ++j) {
      h[j] = bf16_rne(acc[i][j]);
      lo[j] = bf16_rne(acc[i][j] - __uint_as_float((u32)h[j] << 16));
    }
    size_t base = (size_t)row * ldc + bn + tx * 4;
    *(uint2*)(Ch + base) = make_uint2((u32)h[0] | ((u32)h[1] << 16), (u32)h[2] | ((u32)h[3] << 16));
    *(uint2*)(Cl + base) = make_uint2((u32)lo[0] | ((u32)lo[1] << 16), (u32)lo[2] | ((u32)lo[3] << 16));
  }
}

// C(MxN) = A(MxK) @ B(NxK)^T + bias, row-major. grid=(M/64, N/64).
__global__ __launch_bounds__(256) void gemm_nt64_bias(const float* __restrict__ A,
                                                      const float* __restrict__ B,
                                                      const float* __restrict__ bias,
                                                      float* __restrict__ C,
                                                      int Kdim, int lda, int ldb, int ldc) {
  __shared__ float As[16][68];
  __shared__ float Bs[16][68];
  const int tid = threadIdx.x;
  const int bm = blockIdx.x * 64, bn = blockIdx.y * 64;
  const int lr = tid >> 2, lc = (tid & 3) * 4;
  const int tx = tid & 15, ty = tid >> 4;
  const float* Ap = A + (size_t)(bm + lr) * lda + lc;
  const float* Bp = B + (size_t)(bn + lr) * ldb + lc;
  float acc[4][4] = {};
  for (int k0 = 0; k0 < Kdim; k0 += 16) {
    float4 av = *(const float4*)(Ap + k0);
    float4 bv = *(const float4*)(Bp + k0);
    __syncthreads();
    As[lc + 0][lr] = av.x; As[lc + 1][lr] = av.y; As[lc + 2][lr] = av.z; As[lc + 3][lr] = av.w;
    Bs[lc + 0][lr] = bv.x; Bs[lc + 1][lr] = bv.y; Bs[lc + 2][lr] = bv.z; Bs[lc + 3][lr] = bv.w;
    __syncthreads();
#pragma unroll
    for (int kk = 0; kk < 16; ++kk) {
      float a[4], b[4];
      *(float4*)a = *(const float4*)&As[kk][ty * 4];
      *(float4*)b = *(const float4*)&Bs[kk][tx * 4];
#pragma unroll
      for (int i = 0; i < 4; ++i)
#pragma unroll
        for (int j = 0; j < 4; ++j) acc[i][j] += a[i] * b[j];
    }
  }
#pragma unroll
  for (int i = 0; i < 4; ++i) {
    int row = bm + ty * 4 + i;
    float4 o;
    o.x = acc[i][0] + bias[bn + tx * 4 + 0];
    o.y = acc[i][1] + bias[bn + tx * 4 + 1];
    o.z = acc[i][2] + bias[bn + tx * 4 + 2];
    o.w = acc[i][3] + bias[bn + tx * 4 + 3];
    *(float4*)(C + (size_t)row * ldc + bn + tx * 4) = o;
  }
}

// ===================== MFMA bf16-split GEMMs =====================
// Double-buffered A tile in LDS, XOR-swizzled (byte ^= (row&7)<<4). One barrier
// per K-chunk: prefetch chunk c+1 global loads BEFORE the MFMA phase on chunk c,
// LDS write of c+1 after. B fragments load directly from global (L2-resident).

// S = (Ah+Al)(Bh+Bl)^T * scale, 3-pass (full precision for top-k). grid (32,32).
__global__ __launch_bounds__(256) void scores_mfma(const u16* __restrict__ Ahg,
                                                   const u16* __restrict__ Alg,
                                                   const u16* __restrict__ Bhg,
                                                   const u16* __restrict__ Blg,
                                                   float* __restrict__ C, float scale) {
  __shared__ char smem[65536];
  const int tid = threadIdx.x;
  const int bm = blockIdx.x * 128, bn = blockIdx.y * 128;
  const int w = tid >> 6, l = tid & 63;
  const int wr = (w >> 1) * 64, wc = (w & 1) * 64;
  const int srow = tid >> 3, scol = (tid & 7) * 8;
  const int lb = l & 15, lke = (l >> 4) * 8;   // lane row-in-frag, k elem offset
  const u16* bh0 = Bhg + (size_t)(bn + wc + 0  + lb) * D_ + lke;
  const u16* bh1 = Bhg + (size_t)(bn + wc + 16 + lb) * D_ + lke;
  const u16* bh2 = Bhg + (size_t)(bn + wc + 32 + lb) * D_ + lke;
  const u16* bh3 = Bhg + (size_t)(bn + wc + 48 + lb) * D_ + lke;
  const size_t dlo = (size_t)(Blg - Bhg);
  const int aoff[4] = {
    (srow + 0)  * 128 + ((scol * 2) ^ (((srow + 0)  & 7) << 4)),
    (srow + 32) * 128 + ((scol * 2) ^ (((srow + 32) & 7) << 4)),
    (srow + 64) * 128 + ((scol * 2) ^ (((srow + 64) & 7) << 4)),
    (srow + 96) * 128 + ((scol * 2) ^ (((srow + 96) & 7) << 4)) };
  f32x4 acc[4][4];
#pragma unroll
  for (int i = 0; i < 4; ++i)
#pragma unroll
    for (int j = 0; j < 4; ++j) { acc[i][j][0] = 0.f; acc[i][j][1] = 0.f; acc[i][j][2] = 0.f; acc[i][j][3] = 0.f; }

  // prologue: chunk 0 -> buf0
  uint4 ah[4], al[4];
#pragma unroll
  for (int ii = 0; ii < 4; ++ii) {
    int r = srow + ii * 32;
    ah[ii] = *(const uint4*)(Ahg + (size_t)(bm + r) * D_ + scol);
    al[ii] = *(const uint4*)(Alg + (size_t)(bm + r) * D_ + scol);
  }
  {
    char* bAh = smem; char* bAl = smem + 16384;
#pragma unroll
    for (int ii = 0; ii < 4; ++ii) {
      *(uint4*)(bAh + aoff[ii]) = ah[ii];
      *(uint4*)(bAl + aoff[ii]) = al[ii];
    }
  }
  __syncthreads();

  for (int c = 0; c < 4; ++c) {
    char* bAh = smem + ((c & 1) << 15);
    char* bAl = bAh + 16384;
    const bool hn = (c < 3);
    if (hn) {
      const int kn = (c + 1) * 64;
#pragma unroll
      for (int ii = 0; ii < 4; ++ii) {
        int r = srow + ii * 32;
        ah[ii] = *(const uint4*)(Ahg + (size_t)(bm + r) * D_ + kn + scol);
        al[ii] = *(const uint4*)(Alg + (size_t)(bm + r) * D_ + kn + scol);
      }
    }
#pragma unroll
    for (int kk = 0; kk < 2; ++kk) {
      const int kb = kk * 64 + ((l >> 4) << 4);
      const int ge = c * 64 + kk * 32;
      bf16x8 fbh[4], fbl[4];
      fbh[0] = *(const bf16x8*)(bh0 + ge); fbl[0] = *(const bf16x8*)(bh0 + dlo + ge);
      fbh[1] = *(const bf16x8*)(bh1 + ge); fbl[1] = *(const bf16x8*)(bh1 + dlo + ge);
      fbh[2] = *(const bf16x8*)(bh2 + ge); fbl[2] = *(const bf16x8*)(bh2 + dlo + ge);
      fbh[3] = *(const bf16x8*)(bh3 + ge); fbl[3] = *(const bf16x8*)(bh3 + dlo + ge);
#pragma unroll
      for (int i = 0; i < 4; ++i) {
        int ra = wr + i * 16 + lb;
        int oa = ra * 128 + (kb ^ ((ra & 7) << 4));
        bf16x8 fah = *(const bf16x8*)(bAh + oa);
        bf16x8 fal = *(const bf16x8*)(bAl + oa);
#pragma unroll
        for (int j = 0; j < 4; ++j) {
          acc[i][j] = __builtin_amdgcn_mfma_f32_16x16x32_bf16(fah, fbh[j], acc[i][j], 0, 0, 0);
          acc[i][j] = __builtin_amdgcn_mfma_f32_16x16x32_bf16(fah, fbl[j], acc[i][j], 0, 0, 0);
          acc[i][j] = __builtin_amdgcn_mfma_f32_16x16x32_bf16(fal, fbh[j], acc[i][j], 0, 0, 0);
        }
      }
    }
    if (hn) {
      char* nAh = smem + (((c + 1) & 1) << 15);
      char* nAl = nAh + 16384;
#pragma unroll
      for (int ii = 0; ii < 4; ++ii) {
        *(uint4*)(nAh + aoff[ii]) = ah[ii];
        *(uint4*)(nAl + aoff[ii]) = al[ii];
      }
    }
    __syncthreads();
  }
  // epilogue: two 64-row rounds through LDS (64 x 128 f32), coalesced stores
  float* Cs = (float*)smem;
  const int cr = (l >> 4) * 4, cc = l & 15;
#pragma unroll
  for (int p = 0; p < 2; ++p) {
    __syncthreads();
    if ((w >> 1) == p) {
#pragma unroll
      for (int i = 0; i < 4; ++i)
#pragma unroll
        for (int r = 0; r < 4; ++r) {
          int rl = i * 16 + cr + r;
          int sw = ((rl >> 2) & 3) << 4;
#pragma unroll
          for (int j = 0; j < 4; ++j) {
            int cl = wc + j * 16 + cc;
            Cs[rl * 128 + (cl ^ sw)] = acc[i][j][r] * scale;
          }
        }
    }
    __syncthreads();
#pragma unroll
    for (int ii = 0; ii < 8; ++ii) {
      int rl = ii * 8 + (tid >> 5);
      int c4 = (tid & 31) * 4;
      float4 v = *(float4*)&Cs[rl * 128 + (c4 ^ (((rl >> 2) & 3) << 4))];
      *(float4*)(C + (size_t)(bm + p * 64 + rl) * N_ + bn + c4) = v;
    }
  }
}

// Zpart[kz] += (w_k/rowZ[m]) * exp(S-rowmax) @ X ; 2-PASS: A = bf16(exp(S-rm))
// hi only (softmax here is flat -> ~1e-4 error), B keeps hi/lo. grid (32,2,SPLITK).
__global__ __launch_bounds__(256) void zkern_mfma(const float* __restrict__ S,
                                                  const float* __restrict__ rowmax,
                                                  const float* __restrict__ rowZ,
                                                  const u16* __restrict__ BhT,
                                                  const u16* __restrict__ BlT,
                                                  float* __restrict__ Zpart,
                                                  const float* __restrict__ scal,
                                                  int kidx, int kchunk) {
  __shared__ char smem[32768];
  const int tid = threadIdx.x;
  const int bm = blockIdx.x * 128, bn = blockIdx.y * 128;
  const int kz = blockIdx.z;
  const int w = tid >> 6, l = tid & 63;
  const int wr = (w >> 1) * 64, wc = (w & 1) * 64;
  const int arow = tid >> 4, acol = (tid & 15) * 4;
  const int lb = l & 15, lke = (l >> 4) * 8;
  const u16* bh0 = BhT + (size_t)(bn + wc + 0  + lb) * N_ + lke;
  const u16* bh1 = BhT + (size_t)(bn + wc + 16 + lb) * N_ + lke;
  const u16* bh2 = BhT + (size_t)(bn + wc + 32 + lb) * N_ + lke;
  const u16* bh3 = BhT + (size_t)(bn + wc + 48 + lb) * N_ + lke;
  const size_t dlo = (size_t)(BlT - BhT);
  float rm[8];
  int aoff[8];
#pragma unroll
  for (int ii = 0; ii < 8; ++ii) {
    int r = arow + ii * 16;
    rm[ii] = rowmax[bm + r];
    aoff[ii] = r * 128 + ((acol * 2) ^ ((r & 7) << 4));
  }
  f32x4 acc[4][4];
#pragma unroll
  for (int i = 0; i < 4; ++i)
#pragma unroll
    for (int j = 0; j < 4; ++j) { acc[i][j][0] = 0.f; acc[i][j][1] = 0.f; acc[i][j][2] = 0.f; acc[i][j][3] = 0.f; }

  const int nchunk = kchunk >> 6;
  const int kbase = kz * kchunk;

  float4 sv[8];
#pragma unroll
  for (int ii = 0; ii < 8; ++ii)
    sv[ii] = *(const float4*)(S + (size_t)(bm + arow + ii * 16) * N_ + kbase + acol);
  {
    char* bAh = smem;
#pragma unroll
    for (int ii = 0; ii < 8; ++ii) {
      float e0 = expf(sv[ii].x - rm[ii]), e1 = expf(sv[ii].y - rm[ii]);
      float e2 = expf(sv[ii].z - rm[ii]), e3 = expf(sv[ii].w - rm[ii]);
      u16 h0 = bf16_rne(e0), h1 = bf16_rne(e1), h2 = bf16_rne(e2), h3 = bf16_rne(e3);
      *(uint2*)(bAh + aoff[ii]) = make_uint2((u32)h0 | ((u32)h1 << 16), (u32)h2 | ((u32)h3 << 16));
    }
  }
  __syncthreads();

  for (int c = 0; c < nchunk; ++c) {
    char* bAh = smem + ((c & 1) << 14);
    const bool hn = (c + 1 < nchunk);
    if (hn) {
      const int kn = kbase + (c + 1) * 64;
#pragma unroll
      for (int ii = 0; ii < 8; ++ii)
        sv[ii] = *(const float4*)(S + (size_t)(bm + arow + ii * 16) * N_ + kn + acol);
    }
#pragma unroll
    for (int kk = 0; kk < 2; ++kk) {
      const int kb = kk * 64 + ((l >> 4) << 4);
      const int ge = kbase + c * 64 + kk * 32;
      bf16x8 fbh[4], fbl[4];
      fbh[0] = *(const bf16x8*)(bh0 + ge); fbl[0] = *(const bf16x8*)(bh0 + dlo + ge);
      fbh[1] = *(const bf16x8*)(bh1 + ge); fbl[1] = *(const bf16x8*)(bh1 + dlo + ge);
      fbh[2] = *(const bf16x8*)(bh2 + ge); fbl[2] = *(const bf16x8*)(bh2 + dlo + ge);
      fbh[3] = *(const bf16x8*)(bh3 + ge); fbl[3] = *(const bf16x8*)(bh3 + dlo + ge);
#pragma unroll
      for (int i = 0; i < 4; ++i) {
        int ra = wr + i * 16 + lb;
        int oa = ra * 128 + (kb ^ ((ra & 7) << 4));
        bf16x8 fah = *(const bf16x8*)(bAh + oa);
#pragma unroll
        for (int j = 0; j < 4; ++j) {
          acc[i][j] = __builtin_amdgcn_mfma_f32_16x16x32_bf16(fah, fbh[j], acc[i][j], 0, 0, 0);
          acc[i][j] = __builtin_amdgcn_mfma_f32_16x16x32_bf16(fah, fbl[j], acc[i][j], 0, 0, 0);
        }
      }
    }
    if (hn) {
      char* nAh = smem + (((c + 1) & 1) << 14);
#pragma unroll
      for (int ii = 0; ii < 8; ++ii) {
        float e0 = expf(sv[ii].x - rm[ii]), e1 = expf(sv[ii].y - rm[ii]);
        float e2 = expf(sv[ii].z - rm[ii]), e3 = expf(sv[ii].w - rm[ii]);
        u16 h0 = bf16_rne(e0), h1 = bf16_rne(e1), h2 = bf16_rne(e2), h3 = bf16_rne(e3);
        *(uint2*)(nAh + aoff[ii]) = make_uint2((u32)h0 | ((u32)h1 << 16), (u32)h2 | ((u32)h3 << 16));
      }
    }
    __syncthreads();
  }
  // epilogue: LDS transpose rounds + coalesced float4 RMW of Zpart
  const float wk = scal[kidx];
  float* Zp = Zpart + (size_t)kz * N_ * D_;
  float* Cs = (float*)smem;
  const int cr = (l >> 4) * 4, cc = l & 15;
#pragma unroll
  for (int p = 0; p < 2; ++p) {
    __syncthreads();
    if ((w >> 1) == p) {
#pragma unroll
      for (int i = 0; i < 4; ++i)
#pragma unroll
        for (int r = 0; r < 4; ++r) {
          int rl = i * 16 + cr + r;
          int sw = ((rl >> 2) & 3) << 4;
#pragma unroll
          for (int j = 0; j < 4; ++j) {
            int cl = wc + j * 16 + cc;
            Cs[rl * 128 + (cl ^ sw)] = acc[i][j][r];
          }
        }
    }
    __syncthreads();
#pragma unroll
    for (int ii = 0; ii < 8; ++ii) {
      int rl = ii * 8 + (tid >> 5);
      int c4 = (tid & 31) * 4;
      int row = bm + p * 64 + rl;
      float sc = wk / rowZ[row];
      float4 v = *(float4*)&Cs[rl * 128 + (c4 ^ (((rl >> 2) & 3) << 4))];
      float* zb = Zp + (size_t)row * D_ + bn + c4;
      float4 z = *(float4*)zb;
      z.x += sc * v.x; z.y += sc * v.y; z.z += sc * v.z; z.w += sc * v.w;
      *(float4*)zb = z;
    }
  }
}

// ======================= per-row stats + histogram top-16 =======================
__global__ __launch_bounds__(256) void rowstats_topk(const float* __restrict__ S,
                                                     float* __restrict__ rowmax,
                                                     float* __restrict__ rowZ,
                                                     float* __restrict__ tkv,
                                                     int* __restrict__ tki) {
  const int row = blockIdx.x, tid = threadIdx.x;
  const int wid = tid >> 6, lane = tid & 63;
  __shared__ int hist[1024];
  __shared__ int P[256];
  __shared__ float cval[256];
  __shared__ int cgi[256];
  __shared__ int ccnt;
  __shared__ int binlo_s;
  __shared__ float rv[4];
  __shared__ float stk[TK_];
  __shared__ int itk[TK_];
  __shared__ float tv16[TK_];
  __shared__ float mzs[3];

  hist[tid] = 0; hist[tid + 256] = 0; hist[tid + 512] = 0; hist[tid + 768] = 0;
  if (tid == 0) ccnt = 0;

  const float4* Sp = (const float4*)(S + (size_t)row * N_);
  float r[16];
  float lmax = -3.4e38f;
#pragma unroll
  for (int it = 0; it < 4; ++it) {
    float4 v = Sp[tid + it * 256];
    r[it * 4 + 0] = v.x; r[it * 4 + 1] = v.y; r[it * 4 + 2] = v.z; r[it * 4 + 3] = v.w;
    lmax = fmaxf(lmax, fmaxf(fmaxf(v.x, v.y), fmaxf(v.z, v.w)));
  }
#pragma unroll
  for (int off = 32; off; off >>= 1) lmax = fmaxf(lmax, __shfl_xor(lmax, off));
  if (lane == 0) rv[wid] = lmax;
  __syncthreads();
  if (tid == 0) mzs[0] = fmaxf(fmaxf(rv[0], rv[1]), fmaxf(rv[2], rv[3]));
  __syncthreads();
  const float M = mzs[0];
  float ls = 0.f;
#pragma unroll
  for (int j = 0; j < 16; ++j) ls += expf(r[j] - M);
#pragma unroll
  for (int off = 32; off; off >>= 1) ls += __shfl_xor(ls, off);
  if (lane == 0) rv[wid] = ls;
  __syncthreads();
  if (tid == 0) {
    float z = rv[0] + rv[1] + rv[2] + rv[3];
    mzs[1] = z; rowmax[row] = M; rowZ[row] = z;
  }
  __syncthreads();
  const float Z = mzs[1];

#pragma unroll
  for (int j = 0; j < 16; ++j) {
    u32 u = __float_as_uint(r[j]);
    u32 key = (u >> 31) ? ~u : (u | 0x80000000u);
    atomicAdd(&hist[key >> 22], 1);
  }
  __syncthreads();
  const int b0 = tid * 4;
  const int h0 = hist[b0], h1 = hist[b0 + 1], h2 = hist[b0 + 2], h3 = hist[b0 + 3];
  P[tid] = h0 + h1 + h2 + h3;
  __syncthreads();
  for (int o = 1; o < 256; o <<= 1) {
    int v = P[tid] + ((tid + o < 256) ? P[tid + o] : 0);
    __syncthreads();
    P[tid] = v;
    __syncthreads();
  }
  {
    int above = (tid < 255) ? P[tid + 1] : 0;
    int s3 = above + h3, s2 = s3 + h2, s1 = s2 + h1, s0 = s1 + h0;
    if (s3 >= TK_ && above < TK_) binlo_s = b0 + 3;
    else if (s2 >= TK_ && s3 < TK_) binlo_s = b0 + 2;
    else if (s1 >= TK_ && s2 < TK_) binlo_s = b0 + 1;
    else if (s0 >= TK_ && s1 < TK_) binlo_s = b0;
  }
  __syncthreads();
  const u32 kmin = (u32)binlo_s << 22;
#pragma unroll
  for (int j = 0; j < 16; ++j) {
    u32 u = __float_as_uint(r[j]);
    u32 key = (u >> 31) ? ~u : (u | 0x80000000u);
    if (key >= kmin) {
      int p = atomicAdd(&ccnt, 1);
      if (p < 256) {
        cval[p] = r[j];
        cgi[p] = 4 * tid + ((j >> 2) << 10) + (j & 3);
      }
    }
  }
  __syncthreads();
  const int nc = min(ccnt, 256);
  for (int t = 0; t < TK_; ++t) {
    if (tid < 64) {
      float bv = -3.4e38f; int bg = 0x7fffffff, bp = -1;
      for (int p = tid; p < nc; p += 64) {
        float v = cval[p]; int g = cgi[p];
        if (v > bv || (v == bv && g < bg)) { bv = v; bg = g; bp = p; }
      }
#pragma unroll
      for (int off = 32; off; off >>= 1) {
        float ov = __shfl_xor(bv, off);
        int og = __shfl_xor(bg, off);
        int op = __shfl_xor(bp, off);
        if (ov > bv || (ov == bv && og < bg)) { bv = ov; bg = og; bp = op; }
      }
      if (tid == 0) { stk[t] = bv; itk[t] = bg; cval[bp] = -3.4e38f; }
    }
    __syncthreads();
  }
  if (tid < TK_) tv16[tid] = expf(stk[tid] - M) / Z;
  __syncthreads();
  if (tid == 0) { float s = 0.f; for (int q = 0; q < TK_; ++q) s += tv16[q]; mzs[2] = s + 1e-9f; }
  __syncthreads();
  if (tid < TK_) {
    tkv[(size_t)row * TK_ + tid] = tv16[tid] / mzs[2];
    tki[(size_t)row * TK_ + tid] = itk[tid];
  }
}

// ======================= hypergraph build =======================
__global__ void edge_scan(const float* __restrict__ tkv, const int* __restrict__ tki,
                          float* __restrict__ DvAcc, int* __restrict__ cnt,
                          float* __restrict__ invDe) {
  int e = blockIdx.x * 256 + threadIdx.x;
  float s = 0.f;
#pragma unroll
  for (int q = 0; q < TK_; ++q) s += tkv[(size_t)e * TK_ + q];
  invDe[e] = 1.0f / (s + 1e-9f);
#pragma unroll
  for (int q = 0; q < TK_; ++q) {
    int m = tki[(size_t)e * TK_ + q];
    atomicAdd(&DvAcc[m], tkv[(size_t)e * TK_ + q]);
    atomicAdd(&cnt[m], 1);
  }
}

__global__ __launch_bounds__(1024) void scan_offsets(const int* __restrict__ cnt,
                                                     int* __restrict__ off,
                                                     int* __restrict__ cur) {
  __shared__ int part[1024];
  const int t = threadIdx.x;
  const int b = t * 4;
  int c0 = cnt[b], c1 = cnt[b + 1], c2 = cnt[b + 2], c3 = cnt[b + 3];
  part[t] = c0 + c1 + c2 + c3;
  __syncthreads();
  for (int o = 1; o < 1024; o <<= 1) {
    int v = part[t] + ((t >= o) ? part[t - o] : 0);
    __syncthreads();
    part[t] = v;
    __syncthreads();
  }
  int ex = (t == 0) ? 0 : part[t - 1];
  off[b] = ex; off[b + 1] = ex + c0; off[b + 2] = ex + c0 + c1; off[b + 3] = ex + c0 + c1 + c2;
  cur[b] = off[b]; cur[b + 1] = off[b + 1]; cur[b + 2] = off[b + 2]; cur[b + 3] = off[b + 3];
  if (t == 1023) off[N_] = part[1023];
}

__global__ void edge_fill(const float* __restrict__ tkv, const int* __restrict__ tki,
                          int* __restrict__ cur, int* __restrict__ ince,
                          float* __restrict__ incv) {
  int e = blockIdx.x * 256 + threadIdx.x;
#pragma unroll
  for (int q = 0; q < TK_; ++q) {
    int m = tki[(size_t)e * TK_ + q];
    int pos = atomicAdd(&cur[m], 1);
    ince[pos] = e;
    incv[pos] = tkv[(size_t)e * TK_ + q];
  }
}

// ======================= power iteration (multi-kernel, unnormalized) ==========
// ye[e] = invDe[e] * sum_q tkvd[e,q] * v[tki[e,q]]   (right Dvis folded in tkvd)
__global__ void pi_ye(const float* __restrict__ v, const float* __restrict__ tkvd,
                      const int* __restrict__ tki, const float* __restrict__ invDe,
                      float* __restrict__ ye) {
  int e = blockIdx.x * 256 + threadIdx.x;
  const float* tv = tkvd + (size_t)e * TK_;
  const int* ti = tki + (size_t)e * TK_;
  float a = 0.f;
#pragma unroll
  for (int q = 0; q < TK_; ++q) a += tv[q] * v[ti[q]];
  ye[e] = a * invDe[e];
}

__global__ void pi_step(const float* __restrict__ v, const float* __restrict__ ye,
                        const int* __restrict__ off, const int* __restrict__ ince,
                        const float* __restrict__ incv, const float* __restrict__ Dvis,
                        float* __restrict__ vn) {
  int m = blockIdx.x * 256 + threadIdx.x;
  float z = 0.f;
  int j0 = off[m], j1 = off[m + 1];
  for (int j = j0; j < j1; ++j) z += incv[j] * ye[ince[j]];
  vn[m] = v[m] - Dvis[m] * z;
}

__global__ __launch_bounds__(256) void pi_final(const float* __restrict__ v,
                                                const float* __restrict__ ye,
                                                const int* __restrict__ off,
                                                const int* __restrict__ ince,
                                                const float* __restrict__ incv,
                                                const float* __restrict__ Dvis,
                                                float* __restrict__ partial) {
  __shared__ float r1[256], r2[256];
  int m = blockIdx.x * 256 + threadIdx.x;
  float z = 0.f;
  int j0 = off[m], j1 = off[m + 1];
  for (int j = j0; j < j1; ++j) z += incv[j] * ye[ince[j]];
  float wv = v[m] - Dvis[m] * z;
  r1[threadIdx.x] = v[m] * wv;
  r2[threadIdx.x] = v[m] * v[m];
  __syncthreads();
  for (int s = 128; s; s >>= 1) {
    if (threadIdx.x < s) { r1[threadIdx.x] += r1[threadIdx.x + s]; r2[threadIdx.x] += r2[threadIdx.x + s]; }
    __syncthreads();
  }
  if (threadIdx.x == 0) { partial[blockIdx.x * 2] = r1[0]; partial[blockIdx.x * 2 + 1] = r2[0]; }
}

__global__ void pi_lam(const float* __restrict__ partial, float* __restrict__ scal) {
  if (threadIdx.x == 0) {
    float s1 = 0.f, s2 = 0.f;
    for (int b = 0; b < N_ / 256; ++b) { s1 += partial[2 * b]; s2 += partial[2 * b + 1]; }
    scal[5] = fmaxf(s1 / s2, 1e-3f);
  }
}

// ======================= Chebyshev sparse applies =======================
// Ye[e,:] = invDe[e] * sum_q tkvd[e,q] * M[tki[e,q], :]. Wave-per-edge, float4.
// grid E_/4 blocks, 256 thr.
__global__ __launch_bounds__(256) void ye_mat(const float* __restrict__ M,
                                              const float* __restrict__ tkvd,
                                              const int* __restrict__ tki,
                                              const float* __restrict__ invDe,
                                              float* __restrict__ Ye) {
  const int w = threadIdx.x >> 6, l = threadIdx.x & 63;
  const int e = blockIdx.x * 4 + w;
  const float* tv = tkvd + (size_t)e * TK_;
  const int* ti = tki + (size_t)e * TK_;
  float4 a = make_float4(0.f, 0.f, 0.f, 0.f);
#pragma unroll
  for (int q = 0; q < TK_; ++q) {
    float v = tv[q];
    const float4 x = *(const float4*)(M + (size_t)ti[q] * D_ + l * 4);
    a.x += v * x.x; a.y += v * x.y; a.z += v * x.z; a.w += v * x.w;
  }
  const float s = invDe[e];
  float4 o; o.x = a.x * s; o.y = a.y * s; o.z = a.z * s; o.w = a.w * s;
  *(float4*)(Ye + (size_t)e * D_ + l * 4) = o;
}

// z = B Ye per node (wave-per-node float4 gather, 2-way unrolled), combine:
//  mode 1 (T1 = Lt X):      out = (2/lam - 1)*Mx - (2/lam)*Dvis*z
//  mode 2 (T2 = 2 Lt T1-X): out = (4/lam - 2)*Mx - (4/lam)*Dvis*z - G
// grid N_/4 blocks, 256 thr.
__global__ __launch_bounds__(256) void bgather_combine(const float* __restrict__ Ye,
                                                       const int* __restrict__ off,
                                                       const int* __restrict__ ince,
                                                       const float* __restrict__ incv,
                                                       const float* __restrict__ Dvis,
                                                       const float* __restrict__ Mx,
                                                       const float* __restrict__ G,
                                                       const float* __restrict__ scal,
                                                       float* __restrict__ out, int mode) {
  const int w = threadIdx.x >> 6, l = threadIdx.x & 63;
  const int m = blockIdx.x * 4 + w;
  const int j0 = off[m], j1 = off[m + 1];
  float4 z = make_float4(0.f, 0.f, 0.f, 0.f);
  int j = j0;
  for (; j + 2 <= j1; j += 2) {
    float v0 = incv[j];     int e0 = ince[j];
    float v1 = incv[j + 1]; int e1 = ince[j + 1];
    float4 y0 = *(const float4*)(Ye + (size_t)e0 * D_ + l * 4);
    float4 y1 = *(const float4*)(Ye + (size_t)e1 * D_ + l * 4);
    z.x += v0 * y0.x + v1 * y1.x;
    z.y += v0 * y0.y + v1 * y1.y;
    z.z += v0 * y0.z + v1 * y1.z;
    z.w += v0 * y0.w + v1 * y1.w;
  }
  if (j < j1) {
    float v0 = incv[j]; int e0 = ince[j];
    float4 y0 = *(const float4*)(Ye + (size_t)e0 * D_ + l * 4);
    z.x += v0 * y0.x; z.y += v0 * y0.y; z.z += v0 * y0.z; z.w += v0 * y0.w;
  }
  const float lam = scal[5];
  const float c = 2.0f / lam;
  const float dv = Dvis[m];
  const size_t idx = (size_t)m * D_ + l * 4;
  float4 mx = *(const float4*)(Mx + idx);
  float4 o;
  if (mode == 1) {
    o.x = (c - 1.0f) * mx.x - c * dv * z.x;
    o.y = (c - 1.0f) * mx.y - c * dv * z.y;
    o.z = (c - 1.0f) * mx.z - c * dv * z.z;
    o.w = (c - 1.0f) * mx.w - c * dv * z.w;
  } else {
    float4 g = *(const float4*)(G + idx);
    o.x = (2.0f * c - 2.0f) * mx.x - 2.0f * c * dv * z.x - g.x;
    o.y = (2.0f * c - 2.0f) * mx.y - 2.0f * c * dv * z.y - g.y;
    o.z = (2.0f * c - 2.0f) * mx.z - 2.0f * c * dv * z.z - g.z;
    o.w = (2.0f * c - 2.0f) * mx.w - 2.0f * c * dv * z.w - g.w;
  }
  *(float4*)(out + idx) = o;
}

__global__ void mix_kernel(const float* __restrict__ X, const float* __restrict__ T1,
                           const float* __restrict__ T2, const float* __restrict__ theta,
                           const float* __restrict__ Zpart, int splitk,
                           const float* __restrict__ scal, float* __restrict__ Zmix) {
  const int i = blockIdx.x * 256 + threadIdx.x;
  const int d = i & (D_ - 1);
  float cheb = X[i] * theta[d] + T1[i] * theta[D_ + d] + T2[i] * theta[2 * D_ + d];
  float zs = cheb > 0.f ? cheb : expm1f(cheb);
  float zk = 0.f;
  for (int s = 0; s < splitk; ++s) zk += Zpart[(size_t)s * N_ * D_ + i];
  const float rho = scal[4];
  Zmix[i] = rho * zs + (1.0f - rho) * zk;
}

// ============================= launcher =============================

extern "C" void kernel_launch(void* const* d_in, const int* in_sizes, int n_in,
                              void* d_out, int out_size, void* d_ws, size_t ws_size,
                              hipStream_t stream) {
  const float* X       = (const float*)d_in[0];
  const float* L_k     = (const float*)d_in[1];
  const float* alpha   = (const float*)d_in[2];
  const float* theta   = (const float*)d_in[3];
  const float* rho_raw = (const float*)d_in[4];
  const float* proj_w  = (const float*)d_in[5];
  const float* proj_b  = (const float*)d_in[6];
  const float* v0      = (const float*)d_in[7];
  float* out = (float*)d_out;

  char* w = (char*)d_ws;
  size_t o = 0;
  auto alloc = [&](size_t bytes) -> char* {
    char* p = w + o; o += (bytes + 255) & ~(size_t)255; return p;
  };
  float* S     = (float*)alloc((size_t)N_ * N_ * 4);
  u16*   Xh    = (u16*)  alloc((size_t)N_ * D_ * 2);
  u16*   Xl    = (u16*)  alloc((size_t)N_ * D_ * 2);
  u16*   XhT   = (u16*)  alloc((size_t)D_ * N_ * 2);
  u16*   XlT   = (u16*)  alloc((size_t)D_ * N_ * 2);
  u16*   XLh   = (u16*)  alloc((size_t)N_ * D_ * 2);
  u16*   XLl   = (u16*)  alloc((size_t)N_ * D_ * 2);
  float* rowmax= (float*)alloc(N_ * 4);
  float* rowZ  = (float*)alloc(N_ * 4);
  float* tkv   = (float*)alloc((size_t)NENT_ * 4);
  int*   tki   = (int*)  alloc((size_t)NENT_ * 4);
  float* tkvd  = (float*)alloc((size_t)NENT_ * 4);
  float* invDe = (float*)alloc(E_ * 4);
  float* DvAcc = (float*)alloc(N_ * 4);
  float* Dvis  = (float*)alloc(N_ * 4);
  int*   cnt   = (int*)  alloc(N_ * 4);
  int*   off   = (int*)  alloc((N_ + 1) * 4);
  int*   cur   = (int*)  alloc(N_ * 4);
  int*   ince  = (int*)  alloc((size_t)NENT_ * 4);
  float* incv  = (float*)alloc((size_t)NENT_ * 4);
  float* va    = (float*)alloc(N_ * 4);
  float* vbuf  = (float*)alloc(N_ * 4);
  float* yev   = (float*)alloc(E_ * 4);
  float* part  = (float*)alloc((N_ / 256) * 2 * 4);
  float* scal  = (float*)alloc(256);
  int SPLITK = 8;
  while (SPLITK > 1 && o + (size_t)SPLITK * N_ * D_ * 4 > ws_size) SPLITK >>= 1;
  float* Zpart = (float*)alloc((size_t)SPLITK * N_ * D_ * 4);
  const int kchunk = N_ / SPLITK;
  // phase-2 temporaries alias into S (dead after the k-loop)
  float* Ye   = S + (size_t)N_ * D_;
  float* T1   = Ye + (size_t)E_ * D_;
  float* T2   = T1 + (size_t)N_ * D_;
  float* Zmix = T2 + (size_t)N_ * D_;

  scalars_kernel<<<1, 64, 0, stream>>>(alpha, rho_raw, scal);
  hipMemsetAsync(Zpart, 0, (size_t)SPLITK * N_ * D_ * 4, stream);
  hipMemsetAsync(DvAcc, 0, N_ * 4, stream);
  hipMemsetAsync(cnt, 0, N_ * 4, stream);

  // one-time bf16 splits of X (row-major and transposed)
  cvt_split4<<<(N_ * D_ / 4) / 256, 256, 0, stream>>>(X, Xh, Xl);
  transpose_split<<<dim3(D_ / 32, N_ / 32), 256, 0, stream>>>(X, XhT, XlT);

  for (int k = 0; k < K_; ++k) {
    gemm_nn64_split<<<dim3(N_ / 64, D_ / 64), 256, 0, stream>>>(
        X, L_k + (size_t)k * D_ * D_, XLh, XLl, D_, D_, D_, D_);
    scores_mfma<<<dim3(N_ / 128, N_ / 128), 256, 0, stream>>>(
        XLh, XLl, Xh, Xl, S, 1.0f / 16.0f);  // 1/sqrt(256)
    rowstats_topk<<<N_, 256, 0, stream>>>(
        S, rowmax, rowZ, tkv + (size_t)k * N_ * TK_, tki + (size_t)k * N_ * TK_);
    zkern_mfma<<<dim3(N_ / 128, D_ / 128, SPLITK), 256, 0, stream>>>(
        S, rowmax, rowZ, XhT, XlT, Zpart, scal, k, kchunk);
  }

  edge_scan<<<E_ / 256, 256, 0, stream>>>(tkv, tki, DvAcc, cnt, invDe);
  dvis_kernel<<<N_ / 256, 256, 0, stream>>>(DvAcc, Dvis);
  make_tkvd<<<NENT_ / 256, 256, 0, stream>>>(tkv, tki, Dvis, tkvd);
  scan_offsets<<<1, 1024, 0, stream>>>(cnt, off, cur);
  edge_fill<<<E_ / 256, 256, 0, stream>>>(tkv, tki, cur, ince, incv);

  // power iteration: 5 unnormalized matvecs + Rayleigh quotient
  const float* vc = v0;
  float* vn = va;
  for (int it = 0; it < 5; ++it) {
    pi_ye<<<E_ / 256, 256, 0, stream>>>(vc, tkvd, tki, invDe, yev);
    pi_step<<<N_ / 256, 256, 0, stream>>>(vc, yev, off, ince, incv, Dvis, vn);
    vc = vn;
    vn = (vc == va) ? vbuf : va;
  }
  pi_ye<<<E_ / 256, 256, 0, stream>>>(vc, tkvd, tki, invDe, yev);
  pi_final<<<N_ / 256, 256, 0, stream>>>(vc, yev, off, ince, incv, Dvis, part);
  pi_lam<<<1, 64, 0, stream>>>(part, scal);

  // T1 = Lt @ X
  ye_mat<<<E_ / 4, 256, 0, stream>>>(X, tkvd, tki, invDe, Ye);
  bgather_combine<<<N_ / 4, 256, 0, stream>>>(Ye, off, ince, incv, Dvis, X, X, scal, T1, 1);
  // T2 = 2*Lt @ T1 - X
  ye_mat<<<E_ / 4, 256, 0, stream>>>(T1, tkvd, tki, invDe, Ye);
  bgather_combine<<<N_ / 4, 256, 0, stream>>>(Ye, off, ince, incv, Dvis, T1, X, scal, T2, 2);

  mix_kernel<<<N_ * D_ / 256, 256, 0, stream>>>(X, T1, T2, theta, Zpart, SPLITK, scal, Zmix);

  gemm_nt64_bias<<<dim3(N_ / 64, D_ / 64), 256, 0, stream>>>(
      Zmix, proj_w, proj_b, out, D_, D_, D_, D_);
}